// Round 7
// baseline (385.518 us; speedup 1.0000x reference)
//
#include <hip/hip_runtime.h>
#include <stdint.h>

// ---------------- constants ----------------
#define NPOS 2500      // 50*50
#define NANCH 22500    // NPOS*9
#define NPRE 6000
#define NW 94          // ceil(6000/64)
#define XPAD 2704      // 52*52 padded plane
#define CMAX 32        // restricted NMS chunk budget (2048 candidates)
#define KFAST 2048     // common-path sort depth (= CMAX*64)
#define HPART 2560000  // floats per split-K partial (2*2500*512)

// async global->LDS DMA (gfx950). dst is wave-uniform base + lane*size.
__device__ __forceinline__ void gl_lds4(const float* g, float* l) {
  __builtin_amdgcn_global_load_lds((const __attribute__((address_space(1))) void*)g,
                                   (__attribute__((address_space(3))) void*)l, 4, 0, 0);
}
__device__ __forceinline__ void gl_lds16(const float* g, float* l) {
  __builtin_amdgcn_global_load_lds((const __attribute__((address_space(1))) void*)g,
                                   (__attribute__((address_space(3))) void*)l, 16, 0, 0);
}

// ---------------- fused prep: weight transpose + x pad + head-weight transpose ----------------
__global__ __launch_bounds__(256) void prep(const float* __restrict__ w,
                                            float* __restrict__ wt,
                                            const float* __restrict__ x,
                                            float* __restrict__ xp,
                                            const float* __restrict__ objw,
                                            const float* __restrict__ locw,
                                            float* __restrict__ wt54b) {
  __shared__ float tile[32][33];
  int bid = blockIdx.x;
  int tid = threadIdx.x;
  if (bid < 1152) {
    // ---- role A: conv weight transpose ----
    int k0 = (bid % 72) * 32;   // k' = ic*9 + tap
    int o0 = (bid / 72) * 32;
    int tx = tid & 31;
    int ty = tid >> 5;  // 0..7
#pragma unroll
    for (int i = 0; i < 4; ++i) {
      int oc = o0 + ty + i * 8;
      int kp = k0 + tx;
      tile[ty + i * 8][tx] = w[(size_t)oc * 2304 + kp];
    }
    __syncthreads();
#pragma unroll
    for (int i = 0; i < 4; ++i) {
      int kp = k0 + ty + i * 8;
      int ic = kp / 9, tap = kp % 9;
      wt[((size_t)tap * 256 + ic) * 512 + (o0 + tx)] = tile[tx][ty + i * 8];
    }
  } else if (bid < 6560) {
    // ---- role B: zero-pad x ----
    int t = (bid - 1152) * 256 + tid;
    if (t < 2 * 256 * XPAD) {
      int c = t / XPAD;        // b*256 + ic
      int r = t % XPAD;
      int yy = r / 52, xx = r % 52;
      float v = 0.f;
      if (yy >= 1 && yy <= 50 && xx >= 1 && xx <= 50)
        v = x[(size_t)c * NPOS + (yy - 1) * 50 + (xx - 1)];
      xp[t] = v;
    }
  } else {
    // ---- role C: head-weight transpose to [k/4][oc][4] ----
    int t = (bid - 6560) * 256 + tid;
    if (t < 54 * 512) {
      int oc = t / 512, k = t % 512;
      float v = (oc < 18) ? objw[(size_t)oc * 512 + k] : locw[(size_t)(oc - 18) * 512 + k];
      wt54b[((size_t)(k >> 2) * 64 + oc) * 4 + (k & 3)] = v;
    }
  }
}

// ---------------- conv1 split-K=4, dbuf + RAW barriers + counted vmcnt (R22) ----------------
// R21 post-mortem: __syncthreads() ALWAYS emits s_waitcnt vmcnt(0) before
// s_barrier -> the barrier after compute(c) drained stage(c+1)'s just-issued
// DMAs; prefetch annihilated (182us ~ R20's 174.5). R22 applies the verified
// T3+T4 recipe: raw __builtin_amdgcn_s_barrier() + counted s_waitcnt
// vmcnt(10) -> stage(c+1)'s 10 DMAs stay in flight ACROSS the barrier and
// complete under compute(c)'s ~2048 VALU cycles. Per chunk each wave issues
// exactly 10 VMEM (8 gl_lds4 + 2 gl_lds16; FIFO retirement per m135).
// RAW: vmcnt(10)+barrier certifies all waves' stage(c) landed. WAR: trailing
// barrier before next overwrite. Only vmcnt(0) is the last chunk.
// Accumulation order (tap asc, ic asc, kk asc) bit-identical to R20/R21.
__global__ __launch_bounds__(256) void conv1_gemm_split(const float* __restrict__ xp,
                                                        const float* __restrict__ wt,
                                                        float* __restrict__ hpart) {
  __shared__ __align__(16) float As[2][16][128];
  __shared__ __align__(16) float Bs[2][16][128];
  int b = blockIdx.z;
  int m0 = blockIdx.x * 128;
  int oc0 = (blockIdx.y & 3) * 128;
  int kh = blockIdx.y >> 2;        // 0..3: this block's 64-ic slice
  int tid = threadIdx.x;
  int lane = tid & 63;
  int wv = tid >> 6;   // wave 0..3
  int tm = tid >> 4;   // 0..15
  int tn = tid & 15;   // 0..15
  float acc[8][8] = {};

  int p0r = m0 + lane;
  int p0c = p0r < NPOS ? p0r : (NPOS - 1);
  int p1r = m0 + 64 + lane;
  int p1c = p1r < NPOS ? p1r : (NPOS - 1);
  const float* gA0 = xp + (size_t)b * 256 * XPAD + (p0c / 50) * 52 + (p0c % 50) + 53;
  const float* gA1 = xp + (size_t)b * 256 * XPAD + (p1c / 50) * 52 + (p1c % 50) + 53;
  int brow = lane >> 5, bcol4 = (lane & 31) * 4;

  // chunk c = tap*4 + q; covers ic [kh*64 + q*16, +16). 10 VMEM instrs/wave.
  auto stage = [&](int c, int buf) {
    int tap = c >> 2, q = c & 3;
    int koff = (tap / 3 - 1) * 52 + (tap % 3 - 1);
    int ic0 = kh * 64 + q * 16;
#pragma unroll
    for (int j = 0; j < 4; ++j) {
      int kk = wv * 4 + j;
      gl_lds4(gA0 + (size_t)(ic0 + kk) * XPAD + koff, &As[buf][kk][0]);
      gl_lds4(gA1 + (size_t)(ic0 + kk) * XPAD + koff, &As[buf][kk][64]);
    }
#pragma unroll
    for (int q2 = 0; q2 < 2; ++q2) {
      int r0 = wv * 4 + q2 * 2;  // gl_lds16 covers rows r0, r0+1 (1KB)
      gl_lds16(wt + ((size_t)tap * 256 + ic0 + r0 + brow) * 512 + oc0 + bcol4,
               &Bs[buf][r0][0]);
    }
  };

  stage(0, 0);  // prologue: 10 outstanding
  for (int c = 0; c < 36; ++c) {
    int cur = c & 1;
    if (c < 35) {
      stage(c + 1, cur ^ 1);  // prefetch; outstanding: stage(c)+stage(c+1)
      // wait my stage(c) landed (FIFO); stage(c+1)'s 10 stay in flight
      asm volatile("s_waitcnt vmcnt(10)" ::: "memory");
    } else {
      asm volatile("s_waitcnt vmcnt(0)" ::: "memory");
    }
    __builtin_amdgcn_s_barrier();        // RAW publish: all waves' stage(c) landed
    __builtin_amdgcn_sched_barrier(0);   // pin: no ds_read hoisted above barrier
#pragma unroll 4
    for (int kk = 0; kk < 16; ++kk) {
      float4 a0 = *(const float4*)&As[cur][kk][tm * 4];
      float4 a1 = *(const float4*)&As[cur][kk][64 + tm * 4];
      float4 b0 = *(const float4*)&Bs[cur][kk][tn * 4];
      float4 b1 = *(const float4*)&Bs[cur][kk][64 + tn * 4];
      float am[8] = {a0.x, a0.y, a0.z, a0.w, a1.x, a1.y, a1.z, a1.w};
      float bn[8] = {b0.x, b0.y, b0.z, b0.w, b1.x, b1.y, b1.z, b1.w};
#pragma unroll
      for (int i = 0; i < 8; ++i)
#pragma unroll
        for (int j = 0; j < 8; ++j) acc[i][j] = fmaf(am[i], bn[j], acc[i][j]);
    }
    __builtin_amdgcn_sched_barrier(0);   // pin: reads complete before WAR publish
    __builtin_amdgcn_s_barrier();        // WAR: buf[cur] free for stage(c+2)
  }

  // epilogue: plain coalesced float4 stores of this split's partial
  float* hp = hpart + (size_t)kh * HPART;
#pragma unroll
  for (int i = 0; i < 8; ++i) {
    int row = m0 + ((i & 4) ? 64 : 0) + tm * 4 + (i & 3);
    if (row < NPOS) {
      float* hrow = &hp[((size_t)b * NPOS + row) * 512 + oc0];
      float4 v0 = make_float4(acc[i][0], acc[i][1], acc[i][2], acc[i][3]);
      float4 v1 = make_float4(acc[i][4], acc[i][5], acc[i][6], acc[i][7]);
      *(float4*)&hrow[tn * 4] = v0;
      *(float4*)&hrow[64 + tn * 4] = v1;
    }
  }
}

// ---------------- conv1 mono (EXACT R7, known-good 202us): ws fallback ----------------
__global__ __launch_bounds__(256) void conv1_gemm_mono(const float* __restrict__ xp,
                                                       const float* __restrict__ wt,
                                                       const float* __restrict__ bias,
                                                       float* __restrict__ h) {
  __shared__ __align__(16) float As[32][64];
  __shared__ __align__(16) float Bs[32][64];
  int b = blockIdx.z;
  int m0 = blockIdx.x * 64;
  int oc0 = blockIdx.y * 64;
  int tid = threadIdx.x;
  int lane = tid & 63;
  int wv = tid >> 6;
  int tn = tid & 15, tm = tid >> 4;
  float acc[4][4] = {};

  int p = m0 + lane;
  int pc = p < NPOS ? p : (NPOS - 1);
  int py = pc / 50, px = pc % 50;
  const float* gA0 = xp + (size_t)b * 256 * XPAD + py * 52 + px + 53;
  int brow = lane >> 4, bcol4 = (lane & 15) * 4;

  for (int tap = 0; tap < 9; ++tap) {
    int ky = tap / 3 - 1, kx = tap % 3 - 1;
    int koff = ky * 52 + kx;
    for (int icc = 0; icc < 8; ++icc) {
      int ic0 = icc * 32;
      __syncthreads();
#pragma unroll
      for (int j = 0; j < 8; ++j) {
        int kk = wv * 8 + j;
        gl_lds4(gA0 + (size_t)(ic0 + kk) * XPAD + koff, &As[kk][0]);
      }
#pragma unroll
      for (int q = 0; q < 2; ++q) {
        int r0 = wv * 8 + q * 4;
        gl_lds16(wt + ((size_t)tap * 256 + ic0 + r0 + brow) * 512 + oc0 + bcol4,
                 &Bs[r0][0]);
      }
      __syncthreads();
#pragma unroll
      for (int kk = 0; kk < 32; ++kk) {
        float4 av = *(const float4*)&As[kk][tm * 4];
        float4 bv = *(const float4*)&Bs[kk][tn * 4];
        float am[4] = {av.x, av.y, av.z, av.w};
        float bn[4] = {bv.x, bv.y, bv.z, bv.w};
#pragma unroll
        for (int i = 0; i < 4; ++i)
#pragma unroll
          for (int j = 0; j < 4; ++j) acc[i][j] = fmaf(am[i], bn[j], acc[i][j]);
      }
    }
  }
#pragma unroll
  for (int i = 0; i < 4; ++i) {
    int pp = m0 + tm * 4 + i;
    if (pp < NPOS) {
      float4 v;
      float* vp = (float*)&v;
#pragma unroll
      for (int j = 0; j < 4; ++j) {
        int oc = oc0 + tn * 4 + j;
        vp[j] = fmaxf(acc[i][j] + bias[oc], 0.f);
      }
      *(float4*)&h[((size_t)b * NPOS + pp) * 512 + oc0 + tn * 4] = v;
    }
  }
}

// ---------------- heads (split variant): sums 4 partials + bias + relu on load ----------------
template <bool SPLIT>
__global__ __launch_bounds__(64) void heads_t(const float* __restrict__ h,
                                              const float* __restrict__ convb,
                                              const float* __restrict__ wt54b,
                                              const float* __restrict__ objb,
                                              const float* __restrict__ locb,
                                              const float* __restrict__ anch,
                                              const int* __restrict__ imgh,
                                              const int* __restrict__ imgw,
                                              float* __restrict__ scores,
                                              float4* __restrict__ boxes) {
  __shared__ float hv[4 * 512];
  __shared__ float outs[4][64];
  int blk = blockIdx.x;             // 0..1249
  int b = blk / 625;
  int p0 = (blk % 625) * 4;         // 4 consecutive positions
  int lane = threadIdx.x;
  const float4* h4 = (const float4*)h;
  size_t base = ((size_t)b * NPOS + p0) * 128;  // float4 units
  float4* hv4 = (float4*)hv;
  if (SPLIT) {
    const float4* cb4 = (const float4*)convb;
#pragma unroll
    for (int q = 0; q < 8; ++q) {
      int f = lane + 64 * q;
      float4 s0 = h4[base + f];
      float4 s1 = h4[(HPART / 4) + base + f];
      float4 s2 = h4[2 * (HPART / 4) + base + f];
      float4 s3 = h4[3 * (HPART / 4) + base + f];
      float4 bb = cb4[f & 127];
      float4 r;
      r.x = fmaxf(((s0.x + s1.x) + s2.x) + s3.x + bb.x, 0.f);
      r.y = fmaxf(((s0.y + s1.y) + s2.y) + s3.y + bb.y, 0.f);
      r.z = fmaxf(((s0.z + s1.z) + s2.z) + s3.z + bb.z, 0.f);
      r.w = fmaxf(((s0.w + s1.w) + s2.w) + s3.w + bb.w, 0.f);
      hv4[f] = r;
    }
  } else {
#pragma unroll
    for (int q = 0; q < 8; ++q) {
      int f = lane + 64 * q;
      hv4[f] = h4[base + f];
    }
  }
  __syncthreads();
  if (lane < 54) {
    float bias0 = (lane < 18) ? objb[lane] : locb[lane - 18];
    float a0 = bias0, a1 = bias0, a2 = bias0, a3 = bias0;
    const float4* w4 = (const float4*)wt54b;
#pragma unroll 4
    for (int k = 0; k < 128; ++k) {
      float4 wv = w4[k * 64 + lane];
      float4 h0 = hv4[k], h1 = hv4[128 + k], h2 = hv4[256 + k], h3 = hv4[384 + k];
      a0 = fmaf(wv.x, h0.x, a0); a0 = fmaf(wv.y, h0.y, a0);
      a0 = fmaf(wv.z, h0.z, a0); a0 = fmaf(wv.w, h0.w, a0);
      a1 = fmaf(wv.x, h1.x, a1); a1 = fmaf(wv.y, h1.y, a1);
      a1 = fmaf(wv.z, h1.z, a1); a1 = fmaf(wv.w, h1.w, a1);
      a2 = fmaf(wv.x, h2.x, a2); a2 = fmaf(wv.y, h2.y, a2);
      a2 = fmaf(wv.z, h2.z, a2); a2 = fmaf(wv.w, h2.w, a2);
      a3 = fmaf(wv.x, h3.x, a3); a3 = fmaf(wv.y, h3.y, a3);
      a3 = fmaf(wv.z, h3.z, a3); a3 = fmaf(wv.w, h3.w, a3);
    }
    outs[0][lane] = a0; outs[1][lane] = a1; outs[2][lane] = a2; outs[3][lane] = a3;
  }
  __syncthreads();
  if (lane < 36) {
    int pi = lane / 9, a = lane % 9;
    int p = p0 + pi;
    float l0 = outs[pi][2 * a], l1 = outs[pi][2 * a + 1];
    float mx = fmaxf(l0, l1);
    float e0 = expf(l0 - mx);
    float e1 = expf(l1 - mx);
    float s = e1 / (e0 + e1);
    float d0 = outs[pi][18 + 4 * a + 0];
    float d1 = outs[pi][18 + 4 * a + 1];
    float d2 = outs[pi][18 + 4 * a + 2];
    float d3 = outs[pi][18 + 4 * a + 3];
    int ai = p * 9 + a;
    float4 A = ((const float4*)anch)[ai];
    float aw = A.z - A.x, ah = A.w - A.y;
    float acx = A.x + 0.5f * aw, acy = A.y + 0.5f * ah;
    float cx = acx + d0 * aw, cy = acy + d1 * ah;
    float w = aw * expf(d2), hh = ah * expf(d3);
    float W = (float)imgw[0], H = (float)imgh[0];
    float x1 = fminf(fmaxf(cx - 0.5f * w, 0.f), W);
    float y1 = fminf(fmaxf(cy - 0.5f * hh, 0.f), H);
    float x2 = fminf(fmaxf(cx + 0.5f * w, 0.f), W);
    float y2 = fminf(fmaxf(cy + 0.5f * hh, 0.f), H);
    bool valid = (x2 - x1 >= 16.f) && (y2 - y1 >= 16.f);
    scores[(size_t)b * NANCH + ai] = valid ? s : -1.f;
    boxes[(size_t)b * NANCH + ai] = make_float4(x1, y1, x2, y2);
  }
}

// ---------------- top-K select + stable radix sort (one block per batch) ----------------
__device__ inline unsigned int mono_of(float f) {
  unsigned int u = __float_as_uint(f);
  return (u & 0x80000000u) ? ~u : (u | 0x80000000u);
}

// strict suffix sum over 1024 per-thread values (2 barriers)
__device__ __forceinline__ unsigned int suffix_strict(unsigned int v,
                                                      unsigned int* partw,
                                                      int tid, int lane, int wv) {
  unsigned int inc = v;
#pragma unroll
  for (int d = 1; d < 64; d <<= 1) {
    unsigned int u = __shfl_down(inc, d, 64);
    if (lane + d < 64) inc += u;
  }
  if (lane == 0) partw[wv] = inc;  // wave total
  __syncthreads();
  if (tid < 16) {
    unsigned int tot = partw[tid];
    unsigned int inc2 = tot;
#pragma unroll
    for (int d = 1; d < 16; d <<= 1) {
      unsigned int u = __shfl_down(inc2, d, 64);
      if (tid + d < 16) inc2 += u;
    }
    partw[tid] = inc2 - tot;  // strict suffix of later waves
  }
  __syncthreads();
  return partw[wv] + (inc - v);
}

template <int KSEL, int SLOTK, int TBLSZ, bool GATED>
__global__ __launch_bounds__(1024) void topk_sort_t(const float* __restrict__ scores,
                                                    const float4* __restrict__ boxes,
                                                    float* __restrict__ sscore,
                                                    float4* __restrict__ sbox,
                                                    const unsigned int* __restrict__ state) {
  int b = blockIdx.x;
  if (GATED && state[b * 192 + 189]) return;  // common path: NMS already done
  const float* sc = scores + (size_t)b * NANCH;
  __shared__ unsigned int hist[4096];
  __shared__ unsigned int part[1024];
  __shared__ unsigned short pidA[SLOTK * 64];
  __shared__ unsigned short pidB[SLOTK * 64];
  __shared__ unsigned short table[TBLSZ];   // 64 digits x SLOTK slots (padded)
  __shared__ int res[8];
  int tid = threadIdx.x;
  int lane = tid & 63;
  int wv = tid >> 6;

  // ---------- phase 1: top-12-bit histogram ----------
  for (int i = tid; i < 4096; i += 1024) hist[i] = 0;
  __syncthreads();
  for (int i = tid; i < NANCH; i += 1024) atomicAdd(&hist[mono_of(sc[i]) >> 20], 1u);
  __syncthreads();
  {
    unsigned int h0 = hist[4 * tid], h1 = hist[4 * tid + 1];
    unsigned int h2 = hist[4 * tid + 2], h3 = hist[4 * tid + 3];
    unsigned int c = suffix_strict(h0 + h1 + h2 + h3, part, tid, lane, wv);
    const unsigned int need = KSEL;
    if (c < need && c + h3 >= need) { res[0] = 4 * tid + 3; res[1] = (int)c; }
    c += h3;
    if (c < need && c + h2 >= need) { res[0] = 4 * tid + 2; res[1] = (int)c; }
    c += h2;
    if (c < need && c + h1 >= need) { res[0] = 4 * tid + 1; res[1] = (int)c; }
    c += h1;
    if (c < need && c + h0 >= need) { res[0] = 4 * tid + 0; res[1] = (int)c; }
  }
  __syncthreads();
  int t1 = res[0], a1 = res[1];
  __syncthreads();

  // ---------- phase 2: middle-12 bits within bin t1 ----------
  for (int i = tid; i < 4096; i += 1024) hist[i] = 0;
  __syncthreads();
  for (int i = tid; i < NANCH; i += 1024) {
    unsigned int m = mono_of(sc[i]);
    if ((int)(m >> 20) == t1) atomicAdd(&hist[(m >> 8) & 0xFFF], 1u);
  }
  __syncthreads();
  {
    unsigned int h0 = hist[4 * tid], h1 = hist[4 * tid + 1];
    unsigned int h2 = hist[4 * tid + 2], h3 = hist[4 * tid + 3];
    unsigned int c = suffix_strict(h0 + h1 + h2 + h3, part, tid, lane, wv);
    const unsigned int need = (unsigned)(KSEL - a1);
    if (c < need && c + h3 >= need) { res[2] = 4 * tid + 3; res[3] = (int)c; }
    c += h3;
    if (c < need && c + h2 >= need) { res[2] = 4 * tid + 2; res[3] = (int)c; }
    c += h2;
    if (c < need && c + h1 >= need) { res[2] = 4 * tid + 1; res[3] = (int)c; }
    c += h1;
    if (c < need && c + h0 >= need) { res[2] = 4 * tid + 0; res[3] = (int)c; }
  }
  __syncthreads();
  int t2 = res[2], a2 = res[3];
  __syncthreads();

  // ---------- phase 3: low-8 bits within (t1,t2) ----------
  for (int i = tid; i < 256; i += 1024) hist[i] = 0;
  __syncthreads();
  unsigned int top24 = ((unsigned int)t1 << 12) | (unsigned int)t2;
  for (int i = tid; i < NANCH; i += 1024) {
    unsigned int m = mono_of(sc[i]);
    if ((m >> 8) == top24) atomicAdd(&hist[m & 0xFF], 1u);
  }
  __syncthreads();
  {
    unsigned int hb = (tid < 256) ? hist[tid] : 0;
    unsigned int c = suffix_strict(hb, part, tid, lane, wv);
    if (tid < 256) {
      const unsigned int need = (unsigned)(KSEL - a1 - a2);
      if (c < need && c + hb >= need) {
        res[4] = tid;
        res[6] = (int)(need - c);                         // ties_needed
        res[7] = (hb == need - c) ? NANCH : -1;           // idx_cut or TBD
      }
    }
  }
  __syncthreads();
  int t3 = res[4];
  unsigned int T = (top24 << 8) | (unsigned int)t3;
  int ties_needed = res[6];
  int idx_cut = res[7];
  __syncthreads();

  // ---------- phase 4 (rare): tie resolution by smallest index ----------
  if (idx_cut < 0) {
    for (int i = tid; i < 704; i += 1024) hist[i] = 0;
    __syncthreads();
    for (int i = tid; i < NANCH; i += 1024)
      if (mono_of(sc[i]) == T) atomicAdd(&hist[i >> 5], 1u);
    __syncthreads();
    if (tid == 0) {
      int c = 0, cut = NANCH;
      for (int bin = 0; bin < 704; ++bin) {
        int hc = (int)hist[bin];
        if (c + hc >= ties_needed) {
          int c2 = c;
          for (int idx = bin * 32; idx < bin * 32 + 32; ++idx) {
            if (idx < NANCH && mono_of(sc[idx]) == T) {
              ++c2;
              if (c2 == ties_needed) { cut = idx; break; }
            }
          }
          break;
        }
        c += hc;
      }
      res[7] = cut;
    }
    __syncthreads();
    idx_cut = res[7];
    __syncthreads();
  }

  // ---------- phase 5: deterministic idx-order compact (blocked ranges + scan) ----------
  int base0 = tid * 22;  // 1024*22 = 22528 >= NANCH
  unsigned int selm = 0;
  int cnt = 0;
  for (int k = 0; k < 22; ++k) {
    int i = base0 + k;
    if (i < NANCH) {
      unsigned int m = mono_of(sc[i]);
      if (m > T || (m == T && i <= idx_cut)) { selm |= 1u << k; ++cnt; }
    }
  }
  {
    int inc = cnt;
#pragma unroll
    for (int d = 1; d < 64; d <<= 1) {
      int u = __shfl_up(inc, d, 64);
      if (lane >= d) inc += u;
    }
    if (lane == 63) part[wv] = (unsigned int)inc;
    __syncthreads();
    if (tid < 16) {
      int v = (int)part[tid];
      int inc2 = v;
#pragma unroll
      for (int d = 1; d < 16; d <<= 1) {
        int u = __shfl_up(inc2, d, 16);
        if (tid >= d) inc2 += u;
      }
      part[tid] = (unsigned int)(inc2 - v);  // exclusive wave base
    }
    __syncthreads();
    int pos = (int)part[wv] + (inc - cnt);
    for (int k = 0; k < 22; ++k)
      if ((selm >> k) & 1u) pidA[pos++] = (unsigned short)(base0 + k);
  }
  __syncthreads();

  // ---------- phase 6: 6-pass 6-bit stable LSD radix, key = ~mono (asc) ----------
  unsigned short* src = pidA;
  unsigned short* dst = pidB;
  constexpr int KITER = (SLOTK + 15) / 16;
  constexpr int VPT = TBLSZ / 1024;
  for (int pass = 0; pass < 6; ++pass) {
    int shift = pass * 6;
    for (int i = tid; i < TBLSZ; i += 1024) table[i] = 0;
    __syncthreads();
    int dig[KITER], irk[KITER], pidr[KITER];
#pragma unroll
    for (int k = 0; k < KITER; ++k) {
      dig[k] = 0; irk[k] = 0; pidr[k] = 0;
      int s = wv + 16 * k;          // wave-uniform
      if (s < SLOTK) {
        int e = s * 64 + lane;
        bool act = e < KSEL;
        int pid = act ? (int)src[e] : 0;
        unsigned int key = act ? ~mono_of(sc[pid]) : 0u;
        int d = (int)((key >> shift) & 63u);
        uint64_t peers = __ballot(act);
#pragma unroll
        for (int bb = 0; bb < 6; ++bb) {
          uint64_t bl = __ballot(((d >> bb) & 1) != 0);
          peers &= ((d >> bb) & 1) ? bl : ~bl;
        }
        if (act) {
          dig[k] = d;
          pidr[k] = pid;
          irk[k] = (int)__popcll(peers & ((1ull << lane) - 1ull));
          int leader = __ffsll((long long)peers) - 1;
          if (lane == leader)
            table[d * SLOTK + s] = (unsigned short)__popcll(peers);
        }
      }
    }
    __syncthreads();
    // exclusive scan over table[0..TBLSZ) (digit-major, slot-minor)
    {
      int tb = tid * VPT;
      int v[VPT];
      int lsum = 0;
#pragma unroll
      for (int q = 0; q < VPT; ++q) { v[q] = table[tb + q]; lsum += v[q]; }
      int inc = lsum;
#pragma unroll
      for (int d = 1; d < 64; d <<= 1) {
        int u = __shfl_up(inc, d, 64);
        if (lane >= d) inc += u;
      }
      if (lane == 63) part[wv] = (unsigned int)inc;
      __syncthreads();
      if (tid < 16) {
        int vv = (int)part[tid];
        int inc2 = vv;
#pragma unroll
        for (int d = 1; d < 16; d <<= 1) {
          int u = __shfl_up(inc2, d, 16);
          if (tid >= d) inc2 += u;
        }
        part[tid] = (unsigned int)(inc2 - vv);
      }
      __syncthreads();
      int run = (int)part[wv] + (inc - lsum);
#pragma unroll
      for (int q = 0; q < VPT; ++q) { table[tb + q] = (unsigned short)run; run += v[q]; }
    }
    __syncthreads();
    // scatter (stable): pos = base(digit,slot) + intra-slot rank
#pragma unroll
    for (int k = 0; k < KITER; ++k) {
      int s = wv + 16 * k;
      if (s < SLOTK) {
        int e = s * 64 + lane;
        if (e < KSEL) {
          int pos = (int)table[dig[k] * SLOTK + s] + irk[k];
          dst[pos] = (unsigned short)pidr[k];
        }
      }
    }
    __syncthreads();
    unsigned short* tmp = src; src = dst; dst = tmp;
  }
  // 6 passes -> result back in pidA (== src)

  // ---------- phase 7: gather sorted scores/boxes ----------
  for (int r = tid; r < KSEL; r += 1024) {
    int idx = (int)src[r];
    sscore[(size_t)b * NPRE + r] = sc[idx];
    sbox[(size_t)b * NPRE + r] = boxes[(size_t)b * NANCH + idx];
  }
}

// ---------------- IoU suppression bitmask (shared body) ----------------
__device__ __forceinline__ void iou_tile(const float4* __restrict__ sbox,
                                         uint64_t* __restrict__ M,
                                         int b, int it, int jt, int tid,
                                         float4* bi, float4* bj) {
  if (tid < 64) {
    int i = it * 64 + tid;
    bi[tid] = (i < NPRE) ? sbox[(size_t)b * NPRE + i] : make_float4(0, 0, 0, 0);
  }
  {
    int j = jt * 256 + tid;
    bj[tid] = (j < NPRE) ? sbox[(size_t)b * NPRE + j] : make_float4(0, 0, 0, 0);
  }
  __syncthreads();
  int li = tid & 63, wq = tid >> 6;
  int i = it * 64 + li;
  int w = jt * 4 + wq;
  if (i < NPRE && w < NW) {
    float4 A = bi[li];
    float areaA = (A.z - A.x) * (A.w - A.y);
    uint64_t bits = 0;
#pragma unroll 8
    for (int jj = 0; jj < 64; ++jj) {
      int j = w * 64 + jj;
      float4 Bx = bj[wq * 64 + jj];
      float ix1 = fmaxf(A.x, Bx.x), iy1 = fmaxf(A.y, Bx.y);
      float ix2 = fminf(A.z, Bx.z), iy2 = fminf(A.w, Bx.w);
      float inter = fmaxf(ix2 - ix1, 0.f) * fmaxf(iy2 - iy1, 0.f);
      float areaB = (Bx.z - Bx.x) * (Bx.w - Bx.y);
      float iou = inter / (areaA + areaB - inter);
      if ((j > i) && (j < NPRE) && (iou > 0.7f)) bits |= (1ull << jj);
    }
    M[((size_t)b * NPRE + i) * NW + w] = bits;
  }
}

// common path: rows < CMAX*64 AND columns w < CMAX
__global__ __launch_bounds__(256) void iou_mat(const float4* __restrict__ sbox,
                                               uint64_t* __restrict__ M) {
  __shared__ float4 bi[64];
  __shared__ float4 bj[256];
  iou_tile(sbox, M, blockIdx.z, blockIdx.x, blockIdx.y, threadIdx.x, bi, bj);
}

// fallback complement: (rows >= 2048, all cols) + (rows < 2048, cols >= 32)
__global__ __launch_bounds__(256) void iou_rest(const float4* __restrict__ sbox,
                                                uint64_t* __restrict__ M,
                                                const unsigned int* __restrict__ state) {
  if (state[blockIdx.z * 192 + 189]) return;  // done
  int it = blockIdx.x, jt = blockIdx.y;
  if (it < CMAX && jt < CMAX / 4) return;     // covered by iou_mat
  __shared__ float4 bi[64];
  __shared__ float4 bj[256];
  iou_tile(sbox, M, blockIdx.z, it, jt, threadIdx.x, bi, bj);
}

// ---------------- NMS scan: wave0 serial closure + block-parallel OR + early exit ----------------
__device__ inline uint64_t shfl64(uint64_t v, int src) {
  int lo = __shfl((int)(unsigned int)(v & 0xFFFFFFFFull), src, 64);
  int hi = __shfl((int)(unsigned int)(v >> 32), src, 64);
  return ((uint64_t)(unsigned int)hi << 32) | (unsigned int)lo;
}

// one NMS chunk step; OR restricted to w < wlimit
__device__ __forceinline__ void nms_chunk(const uint64_t* __restrict__ Mb,
                                          const float* __restrict__ sscore,
                                          uint64_t* __restrict__ keep,
                                          int b, int c, int tid, int wlimit,
                                          unsigned int* supLo, unsigned int* supHi,
                                          int* klist, int* knS, int* countS) {
  int ibase = c * 64;
  if (tid < 64) {
    int lane = tid;
    if (lane == 0) *knS = 0;
    uint64_t supc = ((uint64_t)supHi[c] << 32) | supLo[c];
    uint64_t validm = (c == NW - 1) ? ((1ull << (NPRE - (NW - 1) * 64)) - 1ull) : ~0ull;
    int pos = ibase + lane;
    uint64_t myrow = (pos < NPRE) ? Mb[(size_t)pos * NW + c] : 0ull;
    bool sval = (pos < NPRE) && (sscore[(size_t)b * NPRE + pos] >= 0.f);
    uint64_t vb = __ballot(sval);
    uint64_t cur = validm & ~supc;
    uint64_t kept = 0;
    while (cur) {
      int i = __ffsll((long long)cur) - 1;
      kept |= (1ull << i);
      cur &= ~(1ull << i);
      uint64_t row = shfl64(myrow, i);
      cur &= ~row;
    }
    if (kept & (1ull << lane)) {
      int pp = atomicAdd(knS, 1);
      klist[pp] = lane;
    }
    if (lane == 0) {
      keep[b * NW + c] = kept;
      *countS += __popcll(kept & vb);
    }
  }
  __syncthreads();  // [A] klist/knS/count visible; sup[c] consumed
  int kn = *knS;
  for (int t = tid; t < kn * 128; t += 1024) {
    int ii = t >> 7, w = t & 127;
    if (w > c && w < wlimit) {
      uint64_t row = Mb[(size_t)(ibase + klist[ii]) * NW + w];
      unsigned int lo = (unsigned int)row;
      unsigned int hi = (unsigned int)(row >> 32);
      if (lo) atomicOr(&supLo[w], lo);
      if (hi) atomicOr(&supHi[w], hi);
    }
  }
  __syncthreads();  // [B] sup updated before next chunk's closure
}

// phase A: chunks 0..CMAX, OR width limited to CMAX
__global__ __launch_bounds__(1024) void nms_scan(const uint64_t* __restrict__ M,
                                                 const float* __restrict__ sscore,
                                                 uint64_t* __restrict__ keep,
                                                 unsigned int* __restrict__ state) {
  __shared__ unsigned int supLo[NW], supHi[NW];
  __shared__ int klist[64];
  __shared__ int knS;
  __shared__ int countS;
  int b = blockIdx.x;
  int tid = threadIdx.x;
  const uint64_t* Mb = M + (size_t)b * NPRE * NW;

  for (int w = tid; w < NW; w += 1024) {
    supLo[w] = 0;
    supHi[w] = 0;
    keep[b * NW + w] = 0;  // early-exit / fallback leaves untouched chunks zeroed
  }
  if (tid == 0) countS = 0;
  __syncthreads();

  int done = 0;
  for (int c = 0; c < CMAX; ++c) {
    nms_chunk(Mb, sscore, keep, b, c, tid, CMAX, supLo, supHi, klist, &knS, &countS);
    if (countS >= 300) { done = 1; break; }  // uniform: countS read post-barrier
  }
  __syncthreads();
  unsigned int* st = state + b * 192;
  for (int w = tid; w < NW; w += 1024) { st[w] = supLo[w]; st[94 + w] = supHi[w]; }
  if (tid == 0) { st[188] = (unsigned int)countS; st[189] = (unsigned int)done; }
}

// fallback scan + emit, merged. Part 1 (only when !done): reconstruct
// sup[w>=CMAX] exactly by re-ORing kept rows over M's high columns, continue
// chunks CMAX..NW full-width. Part 2: emit top-300 (always).
__global__ __launch_bounds__(1024) void nms_finish(const uint64_t* __restrict__ M,
                                                   const float* __restrict__ sscore,
                                                   uint64_t* __restrict__ keep,
                                                   const unsigned int* __restrict__ state,
                                                   const float4* __restrict__ sbox,
                                                   float* __restrict__ out) {
  __shared__ unsigned int supLo[NW], supHi[NW];
  __shared__ int klist[64];
  __shared__ int knS;
  __shared__ int countS;
  __shared__ int cnt[128];
  __shared__ uint64_t fw[NW];
  int b = blockIdx.x;
  int tid = threadIdx.x;
  const uint64_t* Mb = M + (size_t)b * NPRE * NW;
  const unsigned int* st = state + b * 192;

  if (!st[189]) {  // fallback path (uniform)
    for (int w = tid; w < NW; w += 1024) { supLo[w] = st[w]; supHi[w] = st[94 + w]; }
    if (tid == 0) countS = (int)st[188];
    __syncthreads();
    // reconstruct sup words >= CMAX from kept rows of chunks < CMAX
    for (int c = 0; c < CMAX; ++c) {
      uint64_t kw = keep[b * NW + c];
      if (!kw) continue;  // uniform (all threads read same global)
      int ibase = c * 64;
      const int WREST = NW - CMAX;  // 62
      for (int t = tid; t < 64 * WREST; t += 1024) {
        int j = t / WREST;
        int w = CMAX + (t % WREST);
        if ((kw >> j) & 1ull) {
          uint64_t row = Mb[(size_t)(ibase + j) * NW + w];
          unsigned int lo = (unsigned int)row;
          unsigned int hi = (unsigned int)(row >> 32);
          if (lo) atomicOr(&supLo[w], lo);
          if (hi) atomicOr(&supHi[w], hi);
        }
      }
    }
    __syncthreads();
    for (int c = CMAX; c < NW; ++c) {
      nms_chunk(Mb, sscore, keep, b, c, tid, NW, supLo, supHi, klist, &knS, &countS);
      if (countS >= 300) break;
    }
    __threadfence();  // keep[] writes visible to part 2 reads
    __syncthreads();
  }

  // ---- part 2: emit ----
  for (int i = tid; i < 1200; i += 1024) out[b * 1200 + i] = 0.f;
  for (int i = tid; i < 300; i += 1024) {
    out[2400 + b * 300 + i] = 0.f;
    out[3000 + b * 300 + i] = 0.f;
  }
  uint64_t w = 0;
  if (tid < NW) {
    uint64_t kw = keep[b * NW + tid];
    while (kw) {
      int j = __ffsll((long long)kw) - 1;
      kw &= kw - 1;
      if (sscore[(size_t)b * NPRE + tid * 64 + j] >= 0.f) w |= (1ull << j);
    }
    fw[tid] = w;
  }
  if (tid < 128) cnt[tid] = (tid < NW) ? __popcll(w) : 0;
  __syncthreads();
  for (int off = 1; off < 128; off <<= 1) {
    int v = 0, u = 0;
    if (tid < 128) {
      v = cnt[tid];
      u = (tid >= off) ? cnt[tid - off] : 0;
    }
    __syncthreads();
    if (tid < 128) cnt[tid] = v + u;
    __syncthreads();
  }
  if (tid < NW) {
    int base = cnt[tid] - __popcll(fw[tid]);
    uint64_t ww = fw[tid];
    while (ww) {
      int j = __ffsll((long long)ww) - 1;
      ww &= ww - 1;
      if (base < 300) {
        int p = tid * 64 + j;
        float4 bx = sbox[(size_t)b * NPRE + p];
        float* ob = out + b * 1200 + base * 4;
        ob[0] = bx.x; ob[1] = bx.y; ob[2] = bx.z; ob[3] = bx.w;
        out[2400 + b * 300 + base] = sscore[(size_t)b * NPRE + p];
        out[3000 + b * 300 + base] = 1.0f;
      }
      ++base;
    }
  }
}

// ---------------- launch ----------------
extern "C" void kernel_launch(void* const* d_in, const int* in_sizes, int n_in,
                              void* d_out, int out_size, void* d_ws, size_t ws_size,
                              hipStream_t stream) {
  const float* x       = (const float*)d_in[0];
  const float* conv1_w = (const float*)d_in[1];
  const float* conv1_b = (const float*)d_in[2];
  const float* obj_w   = (const float*)d_in[3];
  const float* obj_b   = (const float*)d_in[4];
  const float* loc_w   = (const float*)d_in[5];
  const float* loc_b   = (const float*)d_in[6];
  const float* anch    = (const float*)d_in[7];
  const int*   img_h   = (const int*)d_in[8];
  const int*   img_w   = (const int*)d_in[9];

  char* base = (char*)d_ws;
  // split layout needs: wt(4.72M) + hpart(40.96M) + tail(7.4M) = 52.36 MB
  const size_t NEED_SPLIT = 52359424;
  bool use_split = (ws_size >= NEED_SPLIT);

  float* wt = (float*)(base + 0);  // 4,718,592
  float* h;                        // split: 4 partials (40,960,000); mono: 10,240,000
  uint64_t* M;                     // aliases h region (9,024,000 fits either way)
  float* scores;
  float4* boxes;
  float* sscore;
  float4* sbox;
  uint64_t* keep;
  float* xp;
  unsigned int* state;
  float* wt54b;

  size_t off = 4718592;
  h = (float*)(base + off);
  M = (uint64_t*)(base + off);
  off += use_split ? 40960000 : 10240000;
  scores = (float*)(base + off); off += 180000;
  boxes  = (float4*)(base + off); off += 720000;
  sscore = (float*)(base + off); off += 48000;
  sbox   = (float4*)(base + off);
  wt54b  = (float*)sbox;  // aliases sbox: prep writes, heads reads, topk ph7 overwrites after
  off += 192000;
  keep   = (uint64_t*)(base + off); off += 1504;
  xp     = (float*)(base + off); off += 5537792;
  state  = (unsigned int*)(base + off);

  hipLaunchKernelGGL(prep, dim3(6668), dim3(256), 0, stream,
                     conv1_w, wt, x, xp, obj_w, loc_w, wt54b);
  if (use_split) {
    // split-K=4: y = oc_tile(0..3) | kh(0..3)<<2; partials to h[kh], no atomics
    hipLaunchKernelGGL(conv1_gemm_split, dim3(20, 16, 2), dim3(256), 0, stream, xp, wt, h);
    hipLaunchKernelGGL((heads_t<true>), dim3(1250), dim3(64), 0, stream, h, conv1_b, wt54b,
                       obj_b, loc_b, anch, img_h, img_w, scores, boxes);
  } else {
    // fallback: exact R7 mono path (known-good)
    hipLaunchKernelGGL(conv1_gemm_mono, dim3(40, 8, 2), dim3(256), 0, stream, xp, wt,
                       conv1_b, h);
    hipLaunchKernelGGL((heads_t<false>), dim3(1250), dim3(64), 0, stream, h, conv1_b, wt54b,
                       obj_b, loc_b, anch, img_h, img_w, scores, boxes);
  }
  // common path: sort only top-2048 (all NMS consumes within CMAX budget)
  hipLaunchKernelGGL((topk_sort_t<KFAST, 32, 2048, false>), dim3(2), dim3(1024), 0, stream,
                     scores, boxes, sscore, sbox, state);
  hipLaunchKernelGGL(iou_mat, dim3(CMAX, CMAX / 4, 2), dim3(256), 0, stream, sbox, M);
  hipLaunchKernelGGL(nms_scan, dim3(2), dim3(1024), 0, stream, M, sscore, keep, state);
  // fallback chain (gated on !done): full 6000 sort -> remaining IoU -> rest-scan+emit
  hipLaunchKernelGGL((topk_sort_t<NPRE, 94, 6144, true>), dim3(2), dim3(1024), 0, stream,
                     scores, boxes, sscore, sbox, state);
  hipLaunchKernelGGL(iou_rest, dim3(NW, 24, 2), dim3(256), 0, stream, sbox, M, state);
  hipLaunchKernelGGL(nms_finish, dim3(2), dim3(1024), 0, stream, M, sscore, keep, state,
                     sbox, (float*)d_out);
}

// Round 8
// 376.937 us; speedup vs baseline: 1.0228x; 1.0228x over previous
//
#include <hip/hip_runtime.h>
#include <stdint.h>

// ---------------- constants ----------------
#define NPOS 2500      // 50*50
#define NANCH 22500    // NPOS*9
#define NPRE 6000
#define NW 94          // ceil(6000/64)
#define XPAD 2704      // 52*52 padded plane
#define CMAX 32        // restricted NMS chunk budget (2048 candidates)
#define KFAST 2048     // common-path sort depth (= CMAX*64)
#define HPART 2560000  // floats per split-K partial (2*2500*512)

// async global->LDS DMA (gfx950). dst is wave-uniform base + lane*size.
__device__ __forceinline__ void gl_lds4(const float* g, float* l) {
  __builtin_amdgcn_global_load_lds((const __attribute__((address_space(1))) void*)g,
                                   (__attribute__((address_space(3))) void*)l, 4, 0, 0);
}
__device__ __forceinline__ void gl_lds16(const float* g, float* l) {
  __builtin_amdgcn_global_load_lds((const __attribute__((address_space(1))) void*)g,
                                   (__attribute__((address_space(3))) void*)l, 16, 0, 0);
}

// ---------------- fused prep: weight transpose + x pad + head-weight transpose ----------------
__global__ __launch_bounds__(256) void prep(const float* __restrict__ w,
                                            float* __restrict__ wt,
                                            const float* __restrict__ x,
                                            float* __restrict__ xp,
                                            const float* __restrict__ objw,
                                            const float* __restrict__ locw,
                                            float* __restrict__ wt54b) {
  __shared__ float tile[32][33];
  int bid = blockIdx.x;
  int tid = threadIdx.x;
  if (bid < 1152) {
    // ---- role A: conv weight transpose ----
    int k0 = (bid % 72) * 32;   // k' = ic*9 + tap
    int o0 = (bid / 72) * 32;
    int tx = tid & 31;
    int ty = tid >> 5;  // 0..7
#pragma unroll
    for (int i = 0; i < 4; ++i) {
      int oc = o0 + ty + i * 8;
      int kp = k0 + tx;
      tile[ty + i * 8][tx] = w[(size_t)oc * 2304 + kp];
    }
    __syncthreads();
#pragma unroll
    for (int i = 0; i < 4; ++i) {
      int kp = k0 + ty + i * 8;
      int ic = kp / 9, tap = kp % 9;
      wt[((size_t)tap * 256 + ic) * 512 + (o0 + tx)] = tile[tx][ty + i * 8];
    }
  } else if (bid < 6560) {
    // ---- role B: zero-pad x ----
    int t = (bid - 1152) * 256 + tid;
    if (t < 2 * 256 * XPAD) {
      int c = t / XPAD;        // b*256 + ic
      int r = t % XPAD;
      int yy = r / 52, xx = r % 52;
      float v = 0.f;
      if (yy >= 1 && yy <= 50 && xx >= 1 && xx <= 50)
        v = x[(size_t)c * NPOS + (yy - 1) * 50 + (xx - 1)];
      xp[t] = v;
    }
  } else {
    // ---- role C: head-weight transpose to [k/4][oc][4] ----
    int t = (bid - 6560) * 256 + tid;
    if (t < 54 * 512) {
      int oc = t / 512, k = t % 512;
      float v = (oc < 18) ? objw[(size_t)oc * 512 + k] : locw[(size_t)(oc - 18) * 512 + k];
      wt54b[((size_t)(k >> 2) * 64 + oc) * 4 + (k & 3)] = v;
    }
  }
}

// ---------------- conv1 split-K=4 (EXACT R20, measured 174.5us). FROZEN. ----------------
// R20=174.5 (2-barrier BK=32); R21 dbuf-BK16=182; R22 counted-vmcnt-BK16=182.
// Regression tracks chunk count (36 vs 18 barrier pairs), not sync style;
// cross-block overlap (2.5 blocks/CU) already hides the DMA drain. Frozen.
__global__ __launch_bounds__(256) void conv1_gemm_split(const float* __restrict__ xp,
                                                        const float* __restrict__ wt,
                                                        float* __restrict__ hpart) {
  __shared__ __align__(16) float As[32][128];
  __shared__ __align__(16) float Bs[32][128];
  int b = blockIdx.z;
  int m0 = blockIdx.x * 128;
  int oc0 = (blockIdx.y & 3) * 128;
  int kh = blockIdx.y >> 2;        // 0..3: icc pair (kh*2, kh*2+1)
  int tid = threadIdx.x;
  int lane = tid & 63;
  int wv = tid >> 6;   // wave 0..3
  int tm = tid >> 4;   // 0..15
  int tn = tid & 15;   // 0..15
  float acc[8][8] = {};

  int p0r = m0 + lane;
  int p0c = p0r < NPOS ? p0r : (NPOS - 1);
  int p1r = m0 + 64 + lane;
  int p1c = p1r < NPOS ? p1r : (NPOS - 1);
  const float* gA0 = xp + (size_t)b * 256 * XPAD + (p0c / 50) * 52 + (p0c % 50) + 53;
  const float* gA1 = xp + (size_t)b * 256 * XPAD + (p1c / 50) * 52 + (p1c % 50) + 53;
  int brow = lane >> 5, bcol4 = (lane & 31) * 4;

  for (int tap = 0; tap < 9; ++tap) {
    int ky = tap / 3 - 1, kx = tap % 3 - 1;
    int koff = ky * 52 + kx;
#pragma unroll
    for (int ii = 0; ii < 2; ++ii) {
      int ic0 = (kh * 2 + ii) * 32;
      __syncthreads();  // LDS consumed by previous chunk's compute
#pragma unroll
      for (int j = 0; j < 8; ++j) {
        int kk = wv * 8 + j;
        gl_lds4(gA0 + (size_t)(ic0 + kk) * XPAD + koff, &As[kk][0]);
        gl_lds4(gA1 + (size_t)(ic0 + kk) * XPAD + koff, &As[kk][64]);
      }
#pragma unroll
      for (int q = 0; q < 4; ++q) {
        int r0 = wv * 8 + q * 2;  // instr covers rows r0, r0+1 (1KB)
        gl_lds16(wt + ((size_t)tap * 256 + ic0 + r0 + brow) * 512 + oc0 + bcol4,
                 &Bs[r0][0]);
      }
      __syncthreads();  // drains vmcnt -> DMAs complete
#pragma unroll 4
      for (int kk = 0; kk < 32; ++kk) {
        float4 a0 = *(const float4*)&As[kk][tm * 4];
        float4 a1 = *(const float4*)&As[kk][64 + tm * 4];
        float4 b0 = *(const float4*)&Bs[kk][tn * 4];
        float4 b1 = *(const float4*)&Bs[kk][64 + tn * 4];
        float am[8] = {a0.x, a0.y, a0.z, a0.w, a1.x, a1.y, a1.z, a1.w};
        float bn[8] = {b0.x, b0.y, b0.z, b0.w, b1.x, b1.y, b1.z, b1.w};
#pragma unroll
        for (int i = 0; i < 8; ++i)
#pragma unroll
          for (int j = 0; j < 8; ++j) acc[i][j] = fmaf(am[i], bn[j], acc[i][j]);
      }
    }
  }
  // epilogue: plain coalesced float4 stores of this split's partial
  float* hp = hpart + (size_t)kh * HPART;
#pragma unroll
  for (int i = 0; i < 8; ++i) {
    int row = m0 + ((i & 4) ? 64 : 0) + tm * 4 + (i & 3);
    if (row < NPOS) {
      float* hrow = &hp[((size_t)b * NPOS + row) * 512 + oc0];
      float4 v0 = make_float4(acc[i][0], acc[i][1], acc[i][2], acc[i][3]);
      float4 v1 = make_float4(acc[i][4], acc[i][5], acc[i][6], acc[i][7]);
      *(float4*)&hrow[tn * 4] = v0;
      *(float4*)&hrow[64 + tn * 4] = v1;
    }
  }
}

// ---------------- conv1 mono (EXACT R7, known-good 202us): ws fallback ----------------
__global__ __launch_bounds__(256) void conv1_gemm_mono(const float* __restrict__ xp,
                                                       const float* __restrict__ wt,
                                                       const float* __restrict__ bias,
                                                       float* __restrict__ h) {
  __shared__ __align__(16) float As[32][64];
  __shared__ __align__(16) float Bs[32][64];
  int b = blockIdx.z;
  int m0 = blockIdx.x * 64;
  int oc0 = blockIdx.y * 64;
  int tid = threadIdx.x;
  int lane = tid & 63;
  int wv = tid >> 6;
  int tn = tid & 15, tm = tid >> 4;
  float acc[4][4] = {};

  int p = m0 + lane;
  int pc = p < NPOS ? p : (NPOS - 1);
  int py = pc / 50, px = pc % 50;
  const float* gA0 = xp + (size_t)b * 256 * XPAD + py * 52 + px + 53;
  int brow = lane >> 4, bcol4 = (lane & 15) * 4;

  for (int tap = 0; tap < 9; ++tap) {
    int ky = tap / 3 - 1, kx = tap % 3 - 1;
    int koff = ky * 52 + kx;
    for (int icc = 0; icc < 8; ++icc) {
      int ic0 = icc * 32;
      __syncthreads();
#pragma unroll
      for (int j = 0; j < 8; ++j) {
        int kk = wv * 8 + j;
        gl_lds4(gA0 + (size_t)(ic0 + kk) * XPAD + koff, &As[kk][0]);
      }
#pragma unroll
      for (int q = 0; q < 2; ++q) {
        int r0 = wv * 8 + q * 4;
        gl_lds16(wt + ((size_t)tap * 256 + ic0 + r0 + brow) * 512 + oc0 + bcol4,
                 &Bs[r0][0]);
      }
      __syncthreads();
#pragma unroll
      for (int kk = 0; kk < 32; ++kk) {
        float4 av = *(const float4*)&As[kk][tm * 4];
        float4 bv = *(const float4*)&Bs[kk][tn * 4];
        float am[4] = {av.x, av.y, av.z, av.w};
        float bn[4] = {bv.x, bv.y, bv.z, bv.w};
#pragma unroll
        for (int i = 0; i < 4; ++i)
#pragma unroll
          for (int j = 0; j < 4; ++j) acc[i][j] = fmaf(am[i], bn[j], acc[i][j]);
      }
    }
  }
#pragma unroll
  for (int i = 0; i < 4; ++i) {
    int pp = m0 + tm * 4 + i;
    if (pp < NPOS) {
      float4 v;
      float* vp = (float*)&v;
#pragma unroll
      for (int j = 0; j < 4; ++j) {
        int oc = oc0 + tn * 4 + j;
        vp[j] = fmaxf(acc[i][j] + bias[oc], 0.f);
      }
      *(float4*)&h[((size_t)b * NPOS + pp) * 512 + oc0 + tn * 4] = v;
    }
  }
}

// ---------------- heads (split variant): sums 4 partials + bias + relu on load ----------------
template <bool SPLIT>
__global__ __launch_bounds__(64) void heads_t(const float* __restrict__ h,
                                              const float* __restrict__ convb,
                                              const float* __restrict__ wt54b,
                                              const float* __restrict__ objb,
                                              const float* __restrict__ locb,
                                              const float* __restrict__ anch,
                                              const int* __restrict__ imgh,
                                              const int* __restrict__ imgw,
                                              float* __restrict__ scores,
                                              float4* __restrict__ boxes) {
  __shared__ float hv[4 * 512];
  __shared__ float outs[4][64];
  int blk = blockIdx.x;             // 0..1249
  int b = blk / 625;
  int p0 = (blk % 625) * 4;         // 4 consecutive positions
  int lane = threadIdx.x;
  const float4* h4 = (const float4*)h;
  size_t base = ((size_t)b * NPOS + p0) * 128;  // float4 units
  float4* hv4 = (float4*)hv;
  if (SPLIT) {
    const float4* cb4 = (const float4*)convb;
#pragma unroll
    for (int q = 0; q < 8; ++q) {
      int f = lane + 64 * q;
      float4 s0 = h4[base + f];
      float4 s1 = h4[(HPART / 4) + base + f];
      float4 s2 = h4[2 * (HPART / 4) + base + f];
      float4 s3 = h4[3 * (HPART / 4) + base + f];
      float4 bb = cb4[f & 127];
      float4 r;
      r.x = fmaxf(((s0.x + s1.x) + s2.x) + s3.x + bb.x, 0.f);
      r.y = fmaxf(((s0.y + s1.y) + s2.y) + s3.y + bb.y, 0.f);
      r.z = fmaxf(((s0.z + s1.z) + s2.z) + s3.z + bb.z, 0.f);
      r.w = fmaxf(((s0.w + s1.w) + s2.w) + s3.w + bb.w, 0.f);
      hv4[f] = r;
    }
  } else {
#pragma unroll
    for (int q = 0; q < 8; ++q) {
      int f = lane + 64 * q;
      hv4[f] = h4[base + f];
    }
  }
  __syncthreads();
  if (lane < 54) {
    float bias0 = (lane < 18) ? objb[lane] : locb[lane - 18];
    float a0 = bias0, a1 = bias0, a2 = bias0, a3 = bias0;
    const float4* w4 = (const float4*)wt54b;
#pragma unroll 4
    for (int k = 0; k < 128; ++k) {
      float4 wv = w4[k * 64 + lane];
      float4 h0 = hv4[k], h1 = hv4[128 + k], h2 = hv4[256 + k], h3 = hv4[384 + k];
      a0 = fmaf(wv.x, h0.x, a0); a0 = fmaf(wv.y, h0.y, a0);
      a0 = fmaf(wv.z, h0.z, a0); a0 = fmaf(wv.w, h0.w, a0);
      a1 = fmaf(wv.x, h1.x, a1); a1 = fmaf(wv.y, h1.y, a1);
      a1 = fmaf(wv.z, h1.z, a1); a1 = fmaf(wv.w, h1.w, a1);
      a2 = fmaf(wv.x, h2.x, a2); a2 = fmaf(wv.y, h2.y, a2);
      a2 = fmaf(wv.z, h2.z, a2); a2 = fmaf(wv.w, h2.w, a2);
      a3 = fmaf(wv.x, h3.x, a3); a3 = fmaf(wv.y, h3.y, a3);
      a3 = fmaf(wv.z, h3.z, a3); a3 = fmaf(wv.w, h3.w, a3);
    }
    outs[0][lane] = a0; outs[1][lane] = a1; outs[2][lane] = a2; outs[3][lane] = a3;
  }
  __syncthreads();
  if (lane < 36) {
    int pi = lane / 9, a = lane % 9;
    int p = p0 + pi;
    float l0 = outs[pi][2 * a], l1 = outs[pi][2 * a + 1];
    float mx = fmaxf(l0, l1);
    float e0 = expf(l0 - mx);
    float e1 = expf(l1 - mx);
    float s = e1 / (e0 + e1);
    float d0 = outs[pi][18 + 4 * a + 0];
    float d1 = outs[pi][18 + 4 * a + 1];
    float d2 = outs[pi][18 + 4 * a + 2];
    float d3 = outs[pi][18 + 4 * a + 3];
    int ai = p * 9 + a;
    float4 A = ((const float4*)anch)[ai];
    float aw = A.z - A.x, ah = A.w - A.y;
    float acx = A.x + 0.5f * aw, acy = A.y + 0.5f * ah;
    float cx = acx + d0 * aw, cy = acy + d1 * ah;
    float w = aw * expf(d2), hh = ah * expf(d3);
    float W = (float)imgw[0], H = (float)imgh[0];
    float x1 = fminf(fmaxf(cx - 0.5f * w, 0.f), W);
    float y1 = fminf(fmaxf(cy - 0.5f * hh, 0.f), H);
    float x2 = fminf(fmaxf(cx + 0.5f * w, 0.f), W);
    float y2 = fminf(fmaxf(cy + 0.5f * hh, 0.f), H);
    bool valid = (x2 - x1 >= 16.f) && (y2 - y1 >= 16.f);
    scores[(size_t)b * NANCH + ai] = valid ? s : -1.f;
    boxes[(size_t)b * NANCH + ai] = make_float4(x1, y1, x2, y2);
  }
}

// ---------------- top-K select + stable radix sort (one block per batch) ----------------
__device__ inline unsigned int mono_of(float f) {
  unsigned int u = __float_as_uint(f);
  return (u & 0x80000000u) ? ~u : (u | 0x80000000u);
}

// strict suffix sum over 1024 per-thread values (2 barriers)
__device__ __forceinline__ unsigned int suffix_strict(unsigned int v,
                                                      unsigned int* partw,
                                                      int tid, int lane, int wv) {
  unsigned int inc = v;
#pragma unroll
  for (int d = 1; d < 64; d <<= 1) {
    unsigned int u = __shfl_down(inc, d, 64);
    if (lane + d < 64) inc += u;
  }
  if (lane == 0) partw[wv] = inc;  // wave total
  __syncthreads();
  if (tid < 16) {
    unsigned int tot = partw[tid];
    unsigned int inc2 = tot;
#pragma unroll
    for (int d = 1; d < 16; d <<= 1) {
      unsigned int u = __shfl_down(inc2, d, 64);
      if (tid + d < 16) inc2 += u;
    }
    partw[tid] = inc2 - tot;  // strict suffix of later waves
  }
  __syncthreads();
  return partw[wv] + (inc - v);
}

template <int KSEL, int SLOTK, int TBLSZ, bool GATED>
__global__ __launch_bounds__(1024) void topk_sort_t(const float* __restrict__ scores,
                                                    const float4* __restrict__ boxes,
                                                    float* __restrict__ sscore,
                                                    float4* __restrict__ sbox,
                                                    const unsigned int* __restrict__ state) {
  int b = blockIdx.x;
  if (GATED && state[b * 192 + 189]) return;  // common path: NMS already done
  const float* sc = scores + (size_t)b * NANCH;
  __shared__ unsigned int hist[4096];
  __shared__ unsigned int part[1024];
  __shared__ unsigned short pidA[SLOTK * 64];
  __shared__ unsigned short pidB[SLOTK * 64];
  __shared__ unsigned short table[TBLSZ];   // 64 digits x SLOTK slots (padded)
  __shared__ int res[8];
  int tid = threadIdx.x;
  int lane = tid & 63;
  int wv = tid >> 6;

  // ---------- phase 1: top-12-bit histogram ----------
  for (int i = tid; i < 4096; i += 1024) hist[i] = 0;
  __syncthreads();
  for (int i = tid; i < NANCH; i += 1024) atomicAdd(&hist[mono_of(sc[i]) >> 20], 1u);
  __syncthreads();
  {
    unsigned int h0 = hist[4 * tid], h1 = hist[4 * tid + 1];
    unsigned int h2 = hist[4 * tid + 2], h3 = hist[4 * tid + 3];
    unsigned int c = suffix_strict(h0 + h1 + h2 + h3, part, tid, lane, wv);
    const unsigned int need = KSEL;
    if (c < need && c + h3 >= need) { res[0] = 4 * tid + 3; res[1] = (int)c; }
    c += h3;
    if (c < need && c + h2 >= need) { res[0] = 4 * tid + 2; res[1] = (int)c; }
    c += h2;
    if (c < need && c + h1 >= need) { res[0] = 4 * tid + 1; res[1] = (int)c; }
    c += h1;
    if (c < need && c + h0 >= need) { res[0] = 4 * tid + 0; res[1] = (int)c; }
  }
  __syncthreads();
  int t1 = res[0], a1 = res[1];
  __syncthreads();

  // ---------- phase 2: middle-12 bits within bin t1 ----------
  for (int i = tid; i < 4096; i += 1024) hist[i] = 0;
  __syncthreads();
  for (int i = tid; i < NANCH; i += 1024) {
    unsigned int m = mono_of(sc[i]);
    if ((int)(m >> 20) == t1) atomicAdd(&hist[(m >> 8) & 0xFFF], 1u);
  }
  __syncthreads();
  {
    unsigned int h0 = hist[4 * tid], h1 = hist[4 * tid + 1];
    unsigned int h2 = hist[4 * tid + 2], h3 = hist[4 * tid + 3];
    unsigned int c = suffix_strict(h0 + h1 + h2 + h3, part, tid, lane, wv);
    const unsigned int need = (unsigned)(KSEL - a1);
    if (c < need && c + h3 >= need) { res[2] = 4 * tid + 3; res[3] = (int)c; }
    c += h3;
    if (c < need && c + h2 >= need) { res[2] = 4 * tid + 2; res[3] = (int)c; }
    c += h2;
    if (c < need && c + h1 >= need) { res[2] = 4 * tid + 1; res[3] = (int)c; }
    c += h1;
    if (c < need && c + h0 >= need) { res[2] = 4 * tid + 0; res[3] = (int)c; }
  }
  __syncthreads();
  int t2 = res[2], a2 = res[3];
  __syncthreads();

  // ---------- phase 3: low-8 bits within (t1,t2) ----------
  for (int i = tid; i < 256; i += 1024) hist[i] = 0;
  __syncthreads();
  unsigned int top24 = ((unsigned int)t1 << 12) | (unsigned int)t2;
  for (int i = tid; i < NANCH; i += 1024) {
    unsigned int m = mono_of(sc[i]);
    if ((m >> 8) == top24) atomicAdd(&hist[m & 0xFF], 1u);
  }
  __syncthreads();
  {
    unsigned int hb = (tid < 256) ? hist[tid] : 0;
    unsigned int c = suffix_strict(hb, part, tid, lane, wv);
    if (tid < 256) {
      const unsigned int need = (unsigned)(KSEL - a1 - a2);
      if (c < need && c + hb >= need) {
        res[4] = tid;
        res[6] = (int)(need - c);                         // ties_needed
        res[7] = (hb == need - c) ? NANCH : -1;           // idx_cut or TBD
      }
    }
  }
  __syncthreads();
  int t3 = res[4];
  unsigned int T = (top24 << 8) | (unsigned int)t3;
  int ties_needed = res[6];
  int idx_cut = res[7];
  __syncthreads();

  // ---------- phase 4 (rare): tie resolution by smallest index ----------
  if (idx_cut < 0) {
    for (int i = tid; i < 704; i += 1024) hist[i] = 0;
    __syncthreads();
    for (int i = tid; i < NANCH; i += 1024)
      if (mono_of(sc[i]) == T) atomicAdd(&hist[i >> 5], 1u);
    __syncthreads();
    if (tid == 0) {
      int c = 0, cut = NANCH;
      for (int bin = 0; bin < 704; ++bin) {
        int hc = (int)hist[bin];
        if (c + hc >= ties_needed) {
          int c2 = c;
          for (int idx = bin * 32; idx < bin * 32 + 32; ++idx) {
            if (idx < NANCH && mono_of(sc[idx]) == T) {
              ++c2;
              if (c2 == ties_needed) { cut = idx; break; }
            }
          }
          break;
        }
        c += hc;
      }
      res[7] = cut;
    }
    __syncthreads();
    idx_cut = res[7];
    __syncthreads();
  }

  // ---------- phase 5: deterministic idx-order compact (blocked ranges + scan) ----------
  int base0 = tid * 22;  // 1024*22 = 22528 >= NANCH
  unsigned int selm = 0;
  int cnt = 0;
  for (int k = 0; k < 22; ++k) {
    int i = base0 + k;
    if (i < NANCH) {
      unsigned int m = mono_of(sc[i]);
      if (m > T || (m == T && i <= idx_cut)) { selm |= 1u << k; ++cnt; }
    }
  }
  {
    int inc = cnt;
#pragma unroll
    for (int d = 1; d < 64; d <<= 1) {
      int u = __shfl_up(inc, d, 64);
      if (lane >= d) inc += u;
    }
    if (lane == 63) part[wv] = (unsigned int)inc;
    __syncthreads();
    if (tid < 16) {
      int v = (int)part[tid];
      int inc2 = v;
#pragma unroll
      for (int d = 1; d < 16; d <<= 1) {
        int u = __shfl_up(inc2, d, 16);
        if (tid >= d) inc2 += u;
      }
      part[tid] = (unsigned int)(inc2 - v);  // exclusive wave base
    }
    __syncthreads();
    int pos = (int)part[wv] + (inc - cnt);
    for (int k = 0; k < 22; ++k)
      if ((selm >> k) & 1u) pidA[pos++] = (unsigned short)(base0 + k);
  }
  __syncthreads();

  // ---------- phase 6: 6-pass 6-bit stable LSD radix, key = ~mono (asc) ----------
  unsigned short* src = pidA;
  unsigned short* dst = pidB;
  constexpr int KITER = (SLOTK + 15) / 16;
  constexpr int VPT = TBLSZ / 1024;
  for (int pass = 0; pass < 6; ++pass) {
    int shift = pass * 6;
    for (int i = tid; i < TBLSZ; i += 1024) table[i] = 0;
    __syncthreads();
    int dig[KITER], irk[KITER], pidr[KITER];
#pragma unroll
    for (int k = 0; k < KITER; ++k) {
      dig[k] = 0; irk[k] = 0; pidr[k] = 0;
      int s = wv + 16 * k;          // wave-uniform
      if (s < SLOTK) {
        int e = s * 64 + lane;
        bool act = e < KSEL;
        int pid = act ? (int)src[e] : 0;
        unsigned int key = act ? ~mono_of(sc[pid]) : 0u;
        int d = (int)((key >> shift) & 63u);
        uint64_t peers = __ballot(act);
#pragma unroll
        for (int bb = 0; bb < 6; ++bb) {
          uint64_t bl = __ballot(((d >> bb) & 1) != 0);
          peers &= ((d >> bb) & 1) ? bl : ~bl;
        }
        if (act) {
          dig[k] = d;
          pidr[k] = pid;
          irk[k] = (int)__popcll(peers & ((1ull << lane) - 1ull));
          int leader = __ffsll((long long)peers) - 1;
          if (lane == leader)
            table[d * SLOTK + s] = (unsigned short)__popcll(peers);
        }
      }
    }
    __syncthreads();
    // exclusive scan over table[0..TBLSZ) (digit-major, slot-minor)
    {
      int tb = tid * VPT;
      int v[VPT];
      int lsum = 0;
#pragma unroll
      for (int q = 0; q < VPT; ++q) { v[q] = table[tb + q]; lsum += v[q]; }
      int inc = lsum;
#pragma unroll
      for (int d = 1; d < 64; d <<= 1) {
        int u = __shfl_up(inc, d, 64);
        if (lane >= d) inc += u;
      }
      if (lane == 63) part[wv] = (unsigned int)inc;
      __syncthreads();
      if (tid < 16) {
        int vv = (int)part[tid];
        int inc2 = vv;
#pragma unroll
        for (int d = 1; d < 16; d <<= 1) {
          int u = __shfl_up(inc2, d, 16);
          if (tid >= d) inc2 += u;
        }
        part[tid] = (unsigned int)(inc2 - vv);
      }
      __syncthreads();
      int run = (int)part[wv] + (inc - lsum);
#pragma unroll
      for (int q = 0; q < VPT; ++q) { table[tb + q] = (unsigned short)run; run += v[q]; }
    }
    __syncthreads();
    // scatter (stable): pos = base(digit,slot) + intra-slot rank
#pragma unroll
    for (int k = 0; k < KITER; ++k) {
      int s = wv + 16 * k;
      if (s < SLOTK) {
        int e = s * 64 + lane;
        if (e < KSEL) {
          int pos = (int)table[dig[k] * SLOTK + s] + irk[k];
          dst[pos] = (unsigned short)pidr[k];
        }
      }
    }
    __syncthreads();
    unsigned short* tmp = src; src = dst; dst = tmp;
  }
  // 6 passes -> result back in pidA (== src)

  // ---------- phase 7: gather sorted scores/boxes ----------
  for (int r = tid; r < KSEL; r += 1024) {
    int idx = (int)src[r];
    sscore[(size_t)b * NPRE + r] = sc[idx];
    sbox[(size_t)b * NPRE + r] = boxes[(size_t)b * NANCH + idx];
  }
}

// ---------------- IoU suppression bitmask (shared body) ----------------
__device__ __forceinline__ void iou_tile(const float4* __restrict__ sbox,
                                         uint64_t* __restrict__ M,
                                         int b, int it, int jt, int tid,
                                         float4* bi, float4* bj) {
  if (tid < 64) {
    int i = it * 64 + tid;
    bi[tid] = (i < NPRE) ? sbox[(size_t)b * NPRE + i] : make_float4(0, 0, 0, 0);
  }
  {
    int j = jt * 256 + tid;
    bj[tid] = (j < NPRE) ? sbox[(size_t)b * NPRE + j] : make_float4(0, 0, 0, 0);
  }
  __syncthreads();
  int li = tid & 63, wq = tid >> 6;
  int i = it * 64 + li;
  int w = jt * 4 + wq;
  if (i < NPRE && w < NW) {
    float4 A = bi[li];
    float areaA = (A.z - A.x) * (A.w - A.y);
    uint64_t bits = 0;
#pragma unroll 8
    for (int jj = 0; jj < 64; ++jj) {
      int j = w * 64 + jj;
      float4 Bx = bj[wq * 64 + jj];
      float ix1 = fmaxf(A.x, Bx.x), iy1 = fmaxf(A.y, Bx.y);
      float ix2 = fminf(A.z, Bx.z), iy2 = fminf(A.w, Bx.w);
      float inter = fmaxf(ix2 - ix1, 0.f) * fmaxf(iy2 - iy1, 0.f);
      float areaB = (Bx.z - Bx.x) * (Bx.w - Bx.y);
      float iou = inter / (areaA + areaB - inter);
      if ((j > i) && (j < NPRE) && (iou > 0.7f)) bits |= (1ull << jj);
    }
    M[((size_t)b * NPRE + i) * NW + w] = bits;
  }
}

// common path: rows < CMAX*64 AND columns w < CMAX
__global__ __launch_bounds__(256) void iou_mat(const float4* __restrict__ sbox,
                                               uint64_t* __restrict__ M) {
  __shared__ float4 bi[64];
  __shared__ float4 bj[256];
  iou_tile(sbox, M, blockIdx.z, blockIdx.x, blockIdx.y, threadIdx.x, bi, bj);
}

// fallback complement: (rows >= 2048, all cols) + (rows < 2048, cols >= 32)
__global__ __launch_bounds__(256) void iou_rest(const float4* __restrict__ sbox,
                                                uint64_t* __restrict__ M,
                                                const unsigned int* __restrict__ state) {
  if (state[blockIdx.z * 192 + 189]) return;  // done
  int it = blockIdx.x, jt = blockIdx.y;
  if (it < CMAX && jt < CMAX / 4) return;     // covered by iou_mat
  __shared__ float4 bi[64];
  __shared__ float4 bj[256];
  iou_tile(sbox, M, blockIdx.z, it, jt, threadIdx.x, bi, bj);
}

// ---------------- NMS scan: wave0 serial closure + block-parallel OR + early exit ----------------
__device__ inline uint64_t shfl64(uint64_t v, int src) {
  int lo = __shfl((int)(unsigned int)(v & 0xFFFFFFFFull), src, 64);
  int hi = __shfl((int)(unsigned int)(v >> 32), src, 64);
  return ((uint64_t)(unsigned int)hi << 32) | (unsigned int)lo;
}

// one NMS chunk step; OR restricted to w < wlimit. keptS (LDS) optional.
__device__ __forceinline__ void nms_chunk(const uint64_t* __restrict__ Mb,
                                          const float* __restrict__ sscore,
                                          uint64_t* __restrict__ keep,
                                          int b, int c, int tid, int wlimit,
                                          unsigned int* supLo, unsigned int* supHi,
                                          int* klist, int* knS, int* countS,
                                          uint64_t* keptS) {
  int ibase = c * 64;
  if (tid < 64) {
    int lane = tid;
    if (lane == 0) *knS = 0;
    uint64_t supc = ((uint64_t)supHi[c] << 32) | supLo[c];
    uint64_t validm = (c == NW - 1) ? ((1ull << (NPRE - (NW - 1) * 64)) - 1ull) : ~0ull;
    int pos = ibase + lane;
    uint64_t myrow = (pos < NPRE) ? Mb[(size_t)pos * NW + c] : 0ull;
    bool sval = (pos < NPRE) && (sscore[(size_t)b * NPRE + pos] >= 0.f);
    uint64_t vb = __ballot(sval);
    uint64_t cur = validm & ~supc;
    uint64_t kept = 0;
    while (cur) {
      int i = __ffsll((long long)cur) - 1;
      kept |= (1ull << i);
      cur &= ~(1ull << i);
      uint64_t row = shfl64(myrow, i);
      cur &= ~row;
    }
    if (kept & (1ull << lane)) {
      int pp = atomicAdd(knS, 1);
      klist[pp] = lane;
    }
    if (lane == 0) {
      keep[b * NW + c] = kept;
      if (keptS) keptS[c] = kept;
      *countS += __popcll(kept & vb);
    }
  }
  __syncthreads();  // [A] klist/knS/count visible; sup[c] consumed
  int kn = *knS;
  for (int t = tid; t < kn * 128; t += 1024) {
    int ii = t >> 7, w = t & 127;
    if (w > c && w < wlimit) {
      uint64_t row = Mb[(size_t)(ibase + klist[ii]) * NW + w];
      unsigned int lo = (unsigned int)row;
      unsigned int hi = (unsigned int)(row >> 32);
      if (lo) atomicOr(&supLo[w], lo);
      if (hi) atomicOr(&supHi[w], hi);
    }
  }
  __syncthreads();  // [B] sup updated before next chunk's closure
}

// phase A: chunks 0..CMAX, OR width limited to CMAX. R23: on the common path
// (done==1) this kernel emits the output directly from LDS-resident kept
// words (keptS) -- nms_finish then early-outs, removing its global re-reads
// (keep[], sscore rescan, fence) from the common critical path.
__global__ __launch_bounds__(1024) void nms_scan(const uint64_t* __restrict__ M,
                                                 const float* __restrict__ sscore,
                                                 uint64_t* __restrict__ keep,
                                                 unsigned int* __restrict__ state,
                                                 const float4* __restrict__ sbox,
                                                 float* __restrict__ out) {
  __shared__ unsigned int supLo[NW], supHi[NW];
  __shared__ int klist[64];
  __shared__ int knS;
  __shared__ int countS;
  __shared__ uint64_t keptS[NW];
  __shared__ int cnt[128];
  __shared__ uint64_t fw[NW];
  int b = blockIdx.x;
  int tid = threadIdx.x;
  const uint64_t* Mb = M + (size_t)b * NPRE * NW;

  for (int w = tid; w < NW; w += 1024) {
    supLo[w] = 0;
    supHi[w] = 0;
    keptS[w] = 0;
    keep[b * NW + w] = 0;  // early-exit / fallback leaves untouched chunks zeroed
  }
  if (tid == 0) countS = 0;
  __syncthreads();

  int done = 0;
  for (int c = 0; c < CMAX; ++c) {
    nms_chunk(Mb, sscore, keep, b, c, tid, CMAX, supLo, supHi, klist, &knS, &countS, keptS);
    if (countS >= 300) { done = 1; break; }  // uniform: countS read post-barrier
  }
  __syncthreads();
  unsigned int* st = state + b * 192;
  for (int w = tid; w < NW; w += 1024) { st[w] = supLo[w]; st[94 + w] = supHi[w]; }
  if (tid == 0) { st[188] = (unsigned int)countS; st[189] = (unsigned int)done; }

  if (done) {
    // ---- common-path emit (from LDS keptS; identical logic to nms_finish) ----
    for (int i = tid; i < 1200; i += 1024) out[b * 1200 + i] = 0.f;
    if (tid < 300) {
      out[2400 + b * 300 + tid] = 0.f;
      out[3000 + b * 300 + tid] = 0.f;
    }
    uint64_t fwv = 0;
    if (tid < NW) {
      uint64_t kw = keptS[tid];
      while (kw) {
        int j = __ffsll((long long)kw) - 1;
        kw &= kw - 1;
        if (sscore[(size_t)b * NPRE + tid * 64 + j] >= 0.f) fwv |= (1ull << j);
      }
      fw[tid] = fwv;
    }
    if (tid < 128) cnt[tid] = (tid < NW) ? __popcll(fwv) : 0;
    __syncthreads();
    for (int off = 1; off < 128; off <<= 1) {
      int v = 0, u = 0;
      if (tid < 128) {
        v = cnt[tid];
        u = (tid >= off) ? cnt[tid - off] : 0;
      }
      __syncthreads();
      if (tid < 128) cnt[tid] = v + u;
      __syncthreads();
    }
    if (tid < NW) {
      int base = cnt[tid] - __popcll(fw[tid]);
      uint64_t ww = fw[tid];
      while (ww) {
        int j = __ffsll((long long)ww) - 1;
        ww &= ww - 1;
        if (base < 300) {
          int p = tid * 64 + j;
          float4 bx = sbox[(size_t)b * NPRE + p];
          float* ob = out + b * 1200 + base * 4;
          ob[0] = bx.x; ob[1] = bx.y; ob[2] = bx.z; ob[3] = bx.w;
          out[2400 + b * 300 + base] = sscore[(size_t)b * NPRE + p];
          out[3000 + b * 300 + base] = 1.0f;
        }
        ++base;
      }
    }
  }
}

// fallback scan + emit. Common path (st[189]==1): output already emitted by
// nms_scan -> return immediately. Fallback: reconstruct sup[w>=CMAX], continue
// chunks CMAX..NW full-width, then emit.
__global__ __launch_bounds__(1024) void nms_finish(const uint64_t* __restrict__ M,
                                                   const float* __restrict__ sscore,
                                                   uint64_t* __restrict__ keep,
                                                   const unsigned int* __restrict__ state,
                                                   const float4* __restrict__ sbox,
                                                   float* __restrict__ out) {
  __shared__ unsigned int supLo[NW], supHi[NW];
  __shared__ int klist[64];
  __shared__ int knS;
  __shared__ int countS;
  __shared__ int cnt[128];
  __shared__ uint64_t fw[NW];
  int b = blockIdx.x;
  int tid = threadIdx.x;
  const uint64_t* Mb = M + (size_t)b * NPRE * NW;
  const unsigned int* st = state + b * 192;

  if (st[189]) return;  // common path: nms_scan already emitted

  for (int w = tid; w < NW; w += 1024) { supLo[w] = st[w]; supHi[w] = st[94 + w]; }
  if (tid == 0) countS = (int)st[188];
  __syncthreads();
  // reconstruct sup words >= CMAX from kept rows of chunks < CMAX
  for (int c = 0; c < CMAX; ++c) {
    uint64_t kw = keep[b * NW + c];
    if (!kw) continue;  // uniform (all threads read same global)
    int ibase = c * 64;
    const int WREST = NW - CMAX;  // 62
    for (int t = tid; t < 64 * WREST; t += 1024) {
      int j = t / WREST;
      int w = CMAX + (t % WREST);
      if ((kw >> j) & 1ull) {
        uint64_t row = Mb[(size_t)(ibase + j) * NW + w];
        unsigned int lo = (unsigned int)row;
        unsigned int hi = (unsigned int)(row >> 32);
        if (lo) atomicOr(&supLo[w], lo);
        if (hi) atomicOr(&supHi[w], hi);
      }
    }
  }
  __syncthreads();
  for (int c = CMAX; c < NW; ++c) {
    nms_chunk(Mb, sscore, keep, b, c, tid, NW, supLo, supHi, klist, &knS, &countS, nullptr);
    if (countS >= 300) break;
  }
  __threadfence();  // keep[] writes visible to part 2 reads
  __syncthreads();

  // ---- part 2: emit ----
  for (int i = tid; i < 1200; i += 1024) out[b * 1200 + i] = 0.f;
  for (int i = tid; i < 300; i += 1024) {
    out[2400 + b * 300 + i] = 0.f;
    out[3000 + b * 300 + i] = 0.f;
  }
  uint64_t w = 0;
  if (tid < NW) {
    uint64_t kw = keep[b * NW + tid];
    while (kw) {
      int j = __ffsll((long long)kw) - 1;
      kw &= kw - 1;
      if (sscore[(size_t)b * NPRE + tid * 64 + j] >= 0.f) w |= (1ull << j);
    }
    fw[tid] = w;
  }
  if (tid < 128) cnt[tid] = (tid < NW) ? __popcll(w) : 0;
  __syncthreads();
  for (int off = 1; off < 128; off <<= 1) {
    int v = 0, u = 0;
    if (tid < 128) {
      v = cnt[tid];
      u = (tid >= off) ? cnt[tid - off] : 0;
    }
    __syncthreads();
    if (tid < 128) cnt[tid] = v + u;
    __syncthreads();
  }
  if (tid < NW) {
    int base = cnt[tid] - __popcll(fw[tid]);
    uint64_t ww = fw[tid];
    while (ww) {
      int j = __ffsll((long long)ww) - 1;
      ww &= ww - 1;
      if (base < 300) {
        int p = tid * 64 + j;
        float4 bx = sbox[(size_t)b * NPRE + p];
        float* ob = out + b * 1200 + base * 4;
        ob[0] = bx.x; ob[1] = bx.y; ob[2] = bx.z; ob[3] = bx.w;
        out[2400 + b * 300 + base] = sscore[(size_t)b * NPRE + p];
        out[3000 + b * 300 + base] = 1.0f;
      }
      ++base;
    }
  }
}

// ---------------- launch ----------------
extern "C" void kernel_launch(void* const* d_in, const int* in_sizes, int n_in,
                              void* d_out, int out_size, void* d_ws, size_t ws_size,
                              hipStream_t stream) {
  const float* x       = (const float*)d_in[0];
  const float* conv1_w = (const float*)d_in[1];
  const float* conv1_b = (const float*)d_in[2];
  const float* obj_w   = (const float*)d_in[3];
  const float* obj_b   = (const float*)d_in[4];
  const float* loc_w   = (const float*)d_in[5];
  const float* loc_b   = (const float*)d_in[6];
  const float* anch    = (const float*)d_in[7];
  const int*   img_h   = (const int*)d_in[8];
  const int*   img_w   = (const int*)d_in[9];

  char* base = (char*)d_ws;
  // split layout needs: wt(4.72M) + hpart(40.96M) + tail(7.4M) = 52.36 MB
  const size_t NEED_SPLIT = 52359424;
  bool use_split = (ws_size >= NEED_SPLIT);

  float* wt = (float*)(base + 0);  // 4,718,592
  float* h;                        // split: 4 partials (40,960,000); mono: 10,240,000
  uint64_t* M;                     // aliases h region (9,024,000 fits either way)
  float* scores;
  float4* boxes;
  float* sscore;
  float4* sbox;
  uint64_t* keep;
  float* xp;
  unsigned int* state;
  float* wt54b;

  size_t off = 4718592;
  h = (float*)(base + off);
  M = (uint64_t*)(base + off);
  off += use_split ? 40960000 : 10240000;
  scores = (float*)(base + off); off += 180000;
  boxes  = (float4*)(base + off); off += 720000;
  sscore = (float*)(base + off); off += 48000;
  sbox   = (float4*)(base + off);
  wt54b  = (float*)sbox;  // aliases sbox: prep writes, heads reads, topk ph7 overwrites after
  off += 192000;
  keep   = (uint64_t*)(base + off); off += 1504;
  xp     = (float*)(base + off); off += 5537792;
  state  = (unsigned int*)(base + off);

  hipLaunchKernelGGL(prep, dim3(6668), dim3(256), 0, stream,
                     conv1_w, wt, x, xp, obj_w, loc_w, wt54b);
  if (use_split) {
    // split-K=4: y = oc_tile(0..3) | kh(0..3)<<2; partials to h[kh], no atomics
    hipLaunchKernelGGL(conv1_gemm_split, dim3(20, 16, 2), dim3(256), 0, stream, xp, wt, h);
    hipLaunchKernelGGL((heads_t<true>), dim3(1250), dim3(64), 0, stream, h, conv1_b, wt54b,
                       obj_b, loc_b, anch, img_h, img_w, scores, boxes);
  } else {
    // fallback: exact R7 mono path (known-good)
    hipLaunchKernelGGL(conv1_gemm_mono, dim3(40, 8, 2), dim3(256), 0, stream, xp, wt,
                       conv1_b, h);
    hipLaunchKernelGGL((heads_t<false>), dim3(1250), dim3(64), 0, stream, h, conv1_b, wt54b,
                       obj_b, loc_b, anch, img_h, img_w, scores, boxes);
  }
  // common path: sort only top-2048 (all NMS consumes within CMAX budget)
  hipLaunchKernelGGL((topk_sort_t<KFAST, 32, 2048, false>), dim3(2), dim3(1024), 0, stream,
                     scores, boxes, sscore, sbox, state);
  hipLaunchKernelGGL(iou_mat, dim3(CMAX, CMAX / 4, 2), dim3(256), 0, stream, sbox, M);
  hipLaunchKernelGGL(nms_scan, dim3(2), dim3(1024), 0, stream, M, sscore, keep, state,
                     sbox, (float*)d_out);
  // fallback chain (gated on !done): full 6000 sort -> remaining IoU -> rest-scan+emit
  hipLaunchKernelGGL((topk_sort_t<NPRE, 94, 6144, true>), dim3(2), dim3(1024), 0, stream,
                     scores, boxes, sscore, sbox, state);
  hipLaunchKernelGGL(iou_rest, dim3(NW, 24, 2), dim3(256), 0, stream, sbox, M, state);
  hipLaunchKernelGGL(nms_finish, dim3(2), dim3(1024), 0, stream, M, sscore, keep, state,
                     sbox, (float*)d_out);
}

// Round 10
// 376.601 us; speedup vs baseline: 1.0237x; 1.0009x over previous
//
#include <hip/hip_runtime.h>
#include <stdint.h>

// ---------------- constants ----------------
#define NPOS 2500      // 50*50
#define NANCH 22500    // NPOS*9
#define NPRE 6000
#define NW 94          // ceil(6000/64)
#define XPAD 2704      // 52*52 padded plane
#define CMAX 32        // proven NMS chunk budget (2048 candidates)
#define KFAST 2048     // common-path sort depth (= CMAX*64)
#define HPART 2560000  // floats per split-K partial (2*2500*512)

// async global->LDS DMA (gfx950). dst is wave-uniform base + lane*size.
__device__ __forceinline__ void gl_lds4(const float* g, float* l) {
  __builtin_amdgcn_global_load_lds((const __attribute__((address_space(1))) void*)g,
                                   (__attribute__((address_space(3))) void*)l, 4, 0, 0);
}
__device__ __forceinline__ void gl_lds16(const float* g, float* l) {
  __builtin_amdgcn_global_load_lds((const __attribute__((address_space(1))) void*)g,
                                   (__attribute__((address_space(3))) void*)l, 16, 0, 0);
}

// ---------------- fused prep: weight transpose + x pad(f4) + head-weight transpose ----------------
// R25: role B vectorized to float4 (pure copy, bit-exact); grid 6668 -> 2612.
__global__ __launch_bounds__(256) void prep(const float* __restrict__ w,
                                            float* __restrict__ wt,
                                            const float* __restrict__ x,
                                            float* __restrict__ xp,
                                            const float* __restrict__ objw,
                                            const float* __restrict__ locw,
                                            float* __restrict__ wt54b) {
  __shared__ float tile[32][33];
  int bid = blockIdx.x;
  int tid = threadIdx.x;
  if (bid < 1152) {
    // ---- role A: conv weight transpose ----
    int k0 = (bid % 72) * 32;   // k' = ic*9 + tap
    int o0 = (bid / 72) * 32;
    int tx = tid & 31;
    int ty = tid >> 5;  // 0..7
#pragma unroll
    for (int i = 0; i < 4; ++i) {
      int oc = o0 + ty + i * 8;
      int kp = k0 + tx;
      tile[ty + i * 8][tx] = w[(size_t)oc * 2304 + kp];
    }
    __syncthreads();
#pragma unroll
    for (int i = 0; i < 4; ++i) {
      int kp = k0 + ty + i * 8;
      int ic = kp / 9, tap = kp % 9;
      wt[((size_t)tap * 256 + ic) * 512 + (o0 + tx)] = tile[tx][ty + i * 8];
    }
  } else if (bid < 2504) {
    // ---- role B: zero-pad x, one float4 per thread (2704 = 676 f4/plane) ----
    int t = (bid - 1152) * 256 + tid;   // float4 index
    if (t < 2 * 256 * 676) {
      int c = t / 676;        // b*256 + ic
      int q = t % 676;
      int r0 = q * 4;
      float v[4];
#pragma unroll
      for (int k = 0; k < 4; ++k) {
        int r = r0 + k;
        int yy = r / 52, xx = r % 52;
        v[k] = (yy >= 1 && yy <= 50 && xx >= 1 && xx <= 50)
                   ? x[(size_t)c * NPOS + (yy - 1) * 50 + (xx - 1)]
                   : 0.f;
      }
      ((float4*)xp)[t] = make_float4(v[0], v[1], v[2], v[3]);
    }
  } else {
    // ---- role C: head-weight transpose to [k/4][oc][4] ----
    int t = (bid - 2504) * 256 + tid;
    if (t < 54 * 512) {
      int oc = t / 512, k = t % 512;
      float v = (oc < 18) ? objw[(size_t)oc * 512 + k] : locw[(size_t)(oc - 18) * 512 + k];
      wt54b[((size_t)(k >> 2) * 64 + oc) * 4 + (k & 3)] = v;
    }
  }
}

// ---------------- conv1 split-K=4 (EXACT R20, measured 174.5us). FROZEN. ----------------
__global__ __launch_bounds__(256) void conv1_gemm_split(const float* __restrict__ xp,
                                                        const float* __restrict__ wt,
                                                        float* __restrict__ hpart) {
  __shared__ __align__(16) float As[32][128];
  __shared__ __align__(16) float Bs[32][128];
  int b = blockIdx.z;
  int m0 = blockIdx.x * 128;
  int oc0 = (blockIdx.y & 3) * 128;
  int kh = blockIdx.y >> 2;        // 0..3: icc pair (kh*2, kh*2+1)
  int tid = threadIdx.x;
  int lane = tid & 63;
  int wv = tid >> 6;   // wave 0..3
  int tm = tid >> 4;   // 0..15
  int tn = tid & 15;   // 0..15
  float acc[8][8] = {};

  int p0r = m0 + lane;
  int p0c = p0r < NPOS ? p0r : (NPOS - 1);
  int p1r = m0 + 64 + lane;
  int p1c = p1r < NPOS ? p1r : (NPOS - 1);
  const float* gA0 = xp + (size_t)b * 256 * XPAD + (p0c / 50) * 52 + (p0c % 50) + 53;
  const float* gA1 = xp + (size_t)b * 256 * XPAD + (p1c / 50) * 52 + (p1c % 50) + 53;
  int brow = lane >> 5, bcol4 = (lane & 31) * 4;

  for (int tap = 0; tap < 9; ++tap) {
    int ky = tap / 3 - 1, kx = tap % 3 - 1;
    int koff = ky * 52 + kx;
#pragma unroll
    for (int ii = 0; ii < 2; ++ii) {
      int ic0 = (kh * 2 + ii) * 32;
      __syncthreads();  // LDS consumed by previous chunk's compute
#pragma unroll
      for (int j = 0; j < 8; ++j) {
        int kk = wv * 8 + j;
        gl_lds4(gA0 + (size_t)(ic0 + kk) * XPAD + koff, &As[kk][0]);
        gl_lds4(gA1 + (size_t)(ic0 + kk) * XPAD + koff, &As[kk][64]);
      }
#pragma unroll
      for (int q = 0; q < 4; ++q) {
        int r0 = wv * 8 + q * 2;  // instr covers rows r0, r0+1 (1KB)
        gl_lds16(wt + ((size_t)tap * 256 + ic0 + r0 + brow) * 512 + oc0 + bcol4,
                 &Bs[r0][0]);
      }
      __syncthreads();  // drains vmcnt -> DMAs complete
#pragma unroll 4
      for (int kk = 0; kk < 32; ++kk) {
        float4 a0 = *(const float4*)&As[kk][tm * 4];
        float4 a1 = *(const float4*)&As[kk][64 + tm * 4];
        float4 b0 = *(const float4*)&Bs[kk][tn * 4];
        float4 b1 = *(const float4*)&Bs[kk][64 + tn * 4];
        float am[8] = {a0.x, a0.y, a0.z, a0.w, a1.x, a1.y, a1.z, a1.w};
        float bn[8] = {b0.x, b0.y, b0.z, b0.w, b1.x, b1.y, b1.z, b1.w};
#pragma unroll
        for (int i = 0; i < 8; ++i)
#pragma unroll
          for (int j = 0; j < 8; ++j) acc[i][j] = fmaf(am[i], bn[j], acc[i][j]);
      }
    }
  }
  float* hp = hpart + (size_t)kh * HPART;
#pragma unroll
  for (int i = 0; i < 8; ++i) {
    int row = m0 + ((i & 4) ? 64 : 0) + tm * 4 + (i & 3);
    if (row < NPOS) {
      float* hrow = &hp[((size_t)b * NPOS + row) * 512 + oc0];
      float4 v0 = make_float4(acc[i][0], acc[i][1], acc[i][2], acc[i][3]);
      float4 v1 = make_float4(acc[i][4], acc[i][5], acc[i][6], acc[i][7]);
      *(float4*)&hrow[tn * 4] = v0;
      *(float4*)&hrow[64 + tn * 4] = v1;
    }
  }
}

// ---------------- conv1 mono (EXACT R7, known-good 202us): ws fallback ----------------
__global__ __launch_bounds__(256) void conv1_gemm_mono(const float* __restrict__ xp,
                                                       const float* __restrict__ wt,
                                                       const float* __restrict__ bias,
                                                       float* __restrict__ h) {
  __shared__ __align__(16) float As[32][64];
  __shared__ __align__(16) float Bs[32][64];
  int b = blockIdx.z;
  int m0 = blockIdx.x * 64;
  int oc0 = blockIdx.y * 64;
  int tid = threadIdx.x;
  int lane = tid & 63;
  int wv = tid >> 6;
  int tn = tid & 15, tm = tid >> 4;
  float acc[4][4] = {};

  int p = m0 + lane;
  int pc = p < NPOS ? p : (NPOS - 1);
  int py = pc / 50, px = pc % 50;
  const float* gA0 = xp + (size_t)b * 256 * XPAD + py * 52 + px + 53;
  int brow = lane >> 4, bcol4 = (lane & 15) * 4;

  for (int tap = 0; tap < 9; ++tap) {
    int ky = tap / 3 - 1, kx = tap % 3 - 1;
    int koff = ky * 52 + kx;
    for (int icc = 0; icc < 8; ++icc) {
      int ic0 = icc * 32;
      __syncthreads();
#pragma unroll
      for (int j = 0; j < 8; ++j) {
        int kk = wv * 8 + j;
        gl_lds4(gA0 + (size_t)(ic0 + kk) * XPAD + koff, &As[kk][0]);
      }
#pragma unroll
      for (int q = 0; q < 2; ++q) {
        int r0 = wv * 8 + q * 4;
        gl_lds16(wt + ((size_t)tap * 256 + ic0 + r0 + brow) * 512 + oc0 + bcol4,
                 &Bs[r0][0]);
      }
      __syncthreads();
#pragma unroll
      for (int kk = 0; kk < 32; ++kk) {
        float4 av = *(const float4*)&As[kk][tm * 4];
        float4 bv = *(const float4*)&Bs[kk][tn * 4];
        float am[4] = {av.x, av.y, av.z, av.w};
        float bn[4] = {bv.x, bv.y, bv.z, bv.w};
#pragma unroll
        for (int i = 0; i < 4; ++i)
#pragma unroll
          for (int j = 0; j < 4; ++j) acc[i][j] = fmaf(am[i], bn[j], acc[i][j]);
      }
    }
  }
#pragma unroll
  for (int i = 0; i < 4; ++i) {
    int pp = m0 + tm * 4 + i;
    if (pp < NPOS) {
      float4 v;
      float* vp = (float*)&v;
#pragma unroll
      for (int j = 0; j < 4; ++j) {
        int oc = oc0 + tn * 4 + j;
        vp[j] = fmaxf(acc[i][j] + bias[oc], 0.f);
      }
      *(float4*)&h[((size_t)b * NPOS + pp) * 512 + oc0 + tn * 4] = v;
    }
  }
}

// ---------------- heads (split variant): sums 4 partials + bias + relu on load ----------------
template <bool SPLIT>
__global__ __launch_bounds__(64) void heads_t(const float* __restrict__ h,
                                              const float* __restrict__ convb,
                                              const float* __restrict__ wt54b,
                                              const float* __restrict__ objb,
                                              const float* __restrict__ locb,
                                              const float* __restrict__ anch,
                                              const int* __restrict__ imgh,
                                              const int* __restrict__ imgw,
                                              float* __restrict__ scores,
                                              float4* __restrict__ boxes) {
  __shared__ float hv[4 * 512];
  __shared__ float outs[4][64];
  int blk = blockIdx.x;             // 0..1249
  int b = blk / 625;
  int p0 = (blk % 625) * 4;         // 4 consecutive positions
  int lane = threadIdx.x;
  const float4* h4 = (const float4*)h;
  size_t base = ((size_t)b * NPOS + p0) * 128;  // float4 units
  float4* hv4 = (float4*)hv;
  if (SPLIT) {
    const float4* cb4 = (const float4*)convb;
#pragma unroll
    for (int q = 0; q < 8; ++q) {
      int f = lane + 64 * q;
      float4 s0 = h4[base + f];
      float4 s1 = h4[(HPART / 4) + base + f];
      float4 s2 = h4[2 * (HPART / 4) + base + f];
      float4 s3 = h4[3 * (HPART / 4) + base + f];
      float4 bb = cb4[f & 127];
      float4 r;
      r.x = fmaxf(((s0.x + s1.x) + s2.x) + s3.x + bb.x, 0.f);
      r.y = fmaxf(((s0.y + s1.y) + s2.y) + s3.y + bb.y, 0.f);
      r.z = fmaxf(((s0.z + s1.z) + s2.z) + s3.z + bb.z, 0.f);
      r.w = fmaxf(((s0.w + s1.w) + s2.w) + s3.w + bb.w, 0.f);
      hv4[f] = r;
    }
  } else {
#pragma unroll
    for (int q = 0; q < 8; ++q) {
      int f = lane + 64 * q;
      hv4[f] = h4[base + f];
    }
  }
  __syncthreads();
  if (lane < 54) {
    float bias0 = (lane < 18) ? objb[lane] : locb[lane - 18];
    float a0 = bias0, a1 = bias0, a2 = bias0, a3 = bias0;
    const float4* w4 = (const float4*)wt54b;
#pragma unroll 4
    for (int k = 0; k < 128; ++k) {
      float4 wv = w4[k * 64 + lane];
      float4 h0 = hv4[k], h1 = hv4[128 + k], h2 = hv4[256 + k], h3 = hv4[384 + k];
      a0 = fmaf(wv.x, h0.x, a0); a0 = fmaf(wv.y, h0.y, a0);
      a0 = fmaf(wv.z, h0.z, a0); a0 = fmaf(wv.w, h0.w, a0);
      a1 = fmaf(wv.x, h1.x, a1); a1 = fmaf(wv.y, h1.y, a1);
      a1 = fmaf(wv.z, h1.z, a1); a1 = fmaf(wv.w, h1.w, a1);
      a2 = fmaf(wv.x, h2.x, a2); a2 = fmaf(wv.y, h2.y, a2);
      a2 = fmaf(wv.z, h2.z, a2); a2 = fmaf(wv.w, h2.w, a2);
      a3 = fmaf(wv.x, h3.x, a3); a3 = fmaf(wv.y, h3.y, a3);
      a3 = fmaf(wv.z, h3.z, a3); a3 = fmaf(wv.w, h3.w, a3);
    }
    outs[0][lane] = a0; outs[1][lane] = a1; outs[2][lane] = a2; outs[3][lane] = a3;
  }
  __syncthreads();
  if (lane < 36) {
    int pi = lane / 9, a = lane % 9;
    int p = p0 + pi;
    float l0 = outs[pi][2 * a], l1 = outs[pi][2 * a + 1];
    float mx = fmaxf(l0, l1);
    float e0 = expf(l0 - mx);
    float e1 = expf(l1 - mx);
    float s = e1 / (e0 + e1);
    float d0 = outs[pi][18 + 4 * a + 0];
    float d1 = outs[pi][18 + 4 * a + 1];
    float d2 = outs[pi][18 + 4 * a + 2];
    float d3 = outs[pi][18 + 4 * a + 3];
    int ai = p * 9 + a;
    float4 A = ((const float4*)anch)[ai];
    float aw = A.z - A.x, ah = A.w - A.y;
    float acx = A.x + 0.5f * aw, acy = A.y + 0.5f * ah;
    float cx = acx + d0 * aw, cy = acy + d1 * ah;
    float w = aw * expf(d2), hh = ah * expf(d3);
    float W = (float)imgw[0], H = (float)imgh[0];
    float x1 = fminf(fmaxf(cx - 0.5f * w, 0.f), W);
    float y1 = fminf(fmaxf(cy - 0.5f * hh, 0.f), H);
    float x2 = fminf(fmaxf(cx + 0.5f * w, 0.f), W);
    float y2 = fminf(fmaxf(cy + 0.5f * hh, 0.f), H);
    bool valid = (x2 - x1 >= 16.f) && (y2 - y1 >= 16.f);
    scores[(size_t)b * NANCH + ai] = valid ? s : -1.f;
    boxes[(size_t)b * NANCH + ai] = make_float4(x1, y1, x2, y2);
  }
}

// ---------------- top-K select + stable radix sort (one block per batch) ----------------
__device__ inline unsigned int mono_of(float f) {
  unsigned int u = __float_as_uint(f);
  return (u & 0x80000000u) ? ~u : (u | 0x80000000u);
}

// strict suffix sum over 1024 per-thread values (2 barriers)
__device__ __forceinline__ unsigned int suffix_strict(unsigned int v,
                                                      unsigned int* partw,
                                                      int tid, int lane, int wv) {
  unsigned int inc = v;
#pragma unroll
  for (int d = 1; d < 64; d <<= 1) {
    unsigned int u = __shfl_down(inc, d, 64);
    if (lane + d < 64) inc += u;
  }
  if (lane == 0) partw[wv] = inc;  // wave total
  __syncthreads();
  if (tid < 16) {
    unsigned int tot = partw[tid];
    unsigned int inc2 = tot;
#pragma unroll
    for (int d = 1; d < 16; d <<= 1) {
      unsigned int u = __shfl_down(inc2, d, 64);
      if (tid + d < 16) inc2 += u;
    }
    partw[tid] = inc2 - tot;  // strict suffix of later waves
  }
  __syncthreads();
  return partw[wv] + (inc - v);
}

template <int KSEL, int SLOTK, int TBLSZ, bool GATED>
__global__ __launch_bounds__(1024) void topk_sort_t(const float* __restrict__ scores,
                                                    const float4* __restrict__ boxes,
                                                    float* __restrict__ sscore,
                                                    float4* __restrict__ sbox,
                                                    const unsigned int* __restrict__ state) {
  int b = blockIdx.x;
  if (GATED && state[b * 192 + 189]) return;  // common path: NMS already done
  const float* sc = scores + (size_t)b * NANCH;
  __shared__ unsigned int hist[4096];
  __shared__ unsigned int part[1024];
  __shared__ unsigned short pidA[SLOTK * 64];
  __shared__ unsigned short pidB[SLOTK * 64];
  __shared__ unsigned short table[TBLSZ];   // 64 digits x SLOTK slots (padded)
  __shared__ int res[8];
  int tid = threadIdx.x;
  int lane = tid & 63;
  int wv = tid >> 6;

  // ---------- phase 1: top-12-bit histogram ----------
  for (int i = tid; i < 4096; i += 1024) hist[i] = 0;
  __syncthreads();
  for (int i = tid; i < NANCH; i += 1024) atomicAdd(&hist[mono_of(sc[i]) >> 20], 1u);
  __syncthreads();
  {
    unsigned int h0 = hist[4 * tid], h1 = hist[4 * tid + 1];
    unsigned int h2 = hist[4 * tid + 2], h3 = hist[4 * tid + 3];
    unsigned int c = suffix_strict(h0 + h1 + h2 + h3, part, tid, lane, wv);
    const unsigned int need = KSEL;
    if (c < need && c + h3 >= need) { res[0] = 4 * tid + 3; res[1] = (int)c; }
    c += h3;
    if (c < need && c + h2 >= need) { res[0] = 4 * tid + 2; res[1] = (int)c; }
    c += h2;
    if (c < need && c + h1 >= need) { res[0] = 4 * tid + 1; res[1] = (int)c; }
    c += h1;
    if (c < need && c + h0 >= need) { res[0] = 4 * tid + 0; res[1] = (int)c; }
  }
  __syncthreads();
  int t1 = res[0], a1 = res[1];
  __syncthreads();

  // ---------- phase 2: middle-12 bits within bin t1 ----------
  for (int i = tid; i < 4096; i += 1024) hist[i] = 0;
  __syncthreads();
  for (int i = tid; i < NANCH; i += 1024) {
    unsigned int m = mono_of(sc[i]);
    if ((int)(m >> 20) == t1) atomicAdd(&hist[(m >> 8) & 0xFFF], 1u);
  }
  __syncthreads();
  {
    unsigned int h0 = hist[4 * tid], h1 = hist[4 * tid + 1];
    unsigned int h2 = hist[4 * tid + 2], h3 = hist[4 * tid + 3];
    unsigned int c = suffix_strict(h0 + h1 + h2 + h3, part, tid, lane, wv);
    const unsigned int need = (unsigned)(KSEL - a1);
    if (c < need && c + h3 >= need) { res[2] = 4 * tid + 3; res[3] = (int)c; }
    c += h3;
    if (c < need && c + h2 >= need) { res[2] = 4 * tid + 2; res[3] = (int)c; }
    c += h2;
    if (c < need && c + h1 >= need) { res[2] = 4 * tid + 1; res[3] = (int)c; }
    c += h1;
    if (c < need && c + h0 >= need) { res[2] = 4 * tid + 0; res[3] = (int)c; }
  }
  __syncthreads();
  int t2 = res[2], a2 = res[3];
  __syncthreads();

  // ---------- phase 3: low-8 bits within (t1,t2) ----------
  for (int i = tid; i < 256; i += 1024) hist[i] = 0;
  __syncthreads();
  unsigned int top24 = ((unsigned int)t1 << 12) | (unsigned int)t2;
  for (int i = tid; i < NANCH; i += 1024) {
    unsigned int m = mono_of(sc[i]);
    if ((m >> 8) == top24) atomicAdd(&hist[m & 0xFF], 1u);
  }
  __syncthreads();
  {
    unsigned int hb = (tid < 256) ? hist[tid] : 0;
    unsigned int c = suffix_strict(hb, part, tid, lane, wv);
    if (tid < 256) {
      const unsigned int need = (unsigned)(KSEL - a1 - a2);
      if (c < need && c + hb >= need) {
        res[4] = tid;
        res[6] = (int)(need - c);                         // ties_needed
        res[7] = (hb == need - c) ? NANCH : -1;           // idx_cut or TBD
      }
    }
  }
  __syncthreads();
  int t3 = res[4];
  unsigned int T = (top24 << 8) | (unsigned int)t3;
  int ties_needed = res[6];
  int idx_cut = res[7];
  __syncthreads();

  // ---------- phase 4 (rare): tie resolution by smallest index ----------
  if (idx_cut < 0) {
    for (int i = tid; i < 704; i += 1024) hist[i] = 0;
    __syncthreads();
    for (int i = tid; i < NANCH; i += 1024)
      if (mono_of(sc[i]) == T) atomicAdd(&hist[i >> 5], 1u);
    __syncthreads();
    if (tid == 0) {
      int c = 0, cut = NANCH;
      for (int bin = 0; bin < 704; ++bin) {
        int hc = (int)hist[bin];
        if (c + hc >= ties_needed) {
          int c2 = c;
          for (int idx = bin * 32; idx < bin * 32 + 32; ++idx) {
            if (idx < NANCH && mono_of(sc[idx]) == T) {
              ++c2;
              if (c2 == ties_needed) { cut = idx; break; }
            }
          }
          break;
        }
        c += hc;
      }
      res[7] = cut;
    }
    __syncthreads();
    idx_cut = res[7];
    __syncthreads();
  }

  // ---------- phase 5: deterministic idx-order compact (blocked ranges + scan) ----------
  int base0 = tid * 22;  // 1024*22 = 22528 >= NANCH
  unsigned int selm = 0;
  int cnt = 0;
  for (int k = 0; k < 22; ++k) {
    int i = base0 + k;
    if (i < NANCH) {
      unsigned int m = mono_of(sc[i]);
      if (m > T || (m == T && i <= idx_cut)) { selm |= 1u << k; ++cnt; }
    }
  }
  {
    int inc = cnt;
#pragma unroll
    for (int d = 1; d < 64; d <<= 1) {
      int u = __shfl_up(inc, d, 64);
      if (lane >= d) inc += u;
    }
    if (lane == 63) part[wv] = (unsigned int)inc;
    __syncthreads();
    if (tid < 16) {
      int v = (int)part[tid];
      int inc2 = v;
#pragma unroll
      for (int d = 1; d < 16; d <<= 1) {
        int u = __shfl_up(inc2, d, 16);
        if (tid >= d) inc2 += u;
      }
      part[tid] = (unsigned int)(inc2 - v);  // exclusive wave base
    }
    __syncthreads();
    int pos = (int)part[wv] + (inc - cnt);
    for (int k = 0; k < 22; ++k)
      if ((selm >> k) & 1u) pidA[pos++] = (unsigned short)(base0 + k);
  }
  __syncthreads();

  // ---------- phase 6: 6-pass 6-bit stable LSD radix, key = ~mono (asc) ----------
  unsigned short* src = pidA;
  unsigned short* dst = pidB;
  constexpr int KITER = (SLOTK + 15) / 16;
  constexpr int VPT = TBLSZ / 1024;
  for (int pass = 0; pass < 6; ++pass) {
    int shift = pass * 6;
    for (int i = tid; i < TBLSZ; i += 1024) table[i] = 0;
    __syncthreads();
    int dig[KITER], irk[KITER], pidr[KITER];
#pragma unroll
    for (int k = 0; k < KITER; ++k) {
      dig[k] = 0; irk[k] = 0; pidr[k] = 0;
      int s = wv + 16 * k;          // wave-uniform
      if (s < SLOTK) {
        int e = s * 64 + lane;
        bool act = e < KSEL;
        int pid = act ? (int)src[e] : 0;
        unsigned int key = act ? ~mono_of(sc[pid]) : 0u;
        int d = (int)((key >> shift) & 63u);
        uint64_t peers = __ballot(act);
#pragma unroll
        for (int bb = 0; bb < 6; ++bb) {
          uint64_t bl = __ballot(((d >> bb) & 1) != 0);
          peers &= ((d >> bb) & 1) ? bl : ~bl;
        }
        if (act) {
          dig[k] = d;
          pidr[k] = pid;
          irk[k] = (int)__popcll(peers & ((1ull << lane) - 1ull));
          int leader = __ffsll((long long)peers) - 1;
          if (lane == leader)
            table[d * SLOTK + s] = (unsigned short)__popcll(peers);
        }
      }
    }
    __syncthreads();
    // exclusive scan over table[0..TBLSZ) (digit-major, slot-minor)
    {
      int tb = tid * VPT;
      int v[VPT];
      int lsum = 0;
#pragma unroll
      for (int q = 0; q < VPT; ++q) { v[q] = table[tb + q]; lsum += v[q]; }
      int inc = lsum;
#pragma unroll
      for (int d = 1; d < 64; d <<= 1) {
        int u = __shfl_up(inc, d, 64);
        if (lane >= d) inc += u;
      }
      if (lane == 63) part[wv] = (unsigned int)inc;
      __syncthreads();
      if (tid < 16) {
        int vv = (int)part[tid];
        int inc2 = vv;
#pragma unroll
        for (int d = 1; d < 16; d <<= 1) {
          int u = __shfl_up(inc2, d, 16);
          if (tid >= d) inc2 += u;
        }
        part[tid] = (unsigned int)(inc2 - vv);
      }
      __syncthreads();
      int run = (int)part[wv] + (inc - lsum);
#pragma unroll
      for (int q = 0; q < VPT; ++q) { table[tb + q] = (unsigned short)run; run += v[q]; }
    }
    __syncthreads();
    // scatter (stable): pos = base(digit,slot) + intra-slot rank
#pragma unroll
    for (int k = 0; k < KITER; ++k) {
      int s = wv + 16 * k;
      if (s < SLOTK) {
        int e = s * 64 + lane;
        if (e < KSEL) {
          int pos = (int)table[dig[k] * SLOTK + s] + irk[k];
          dst[pos] = (unsigned short)pidr[k];
        }
      }
    }
    __syncthreads();
    unsigned short* tmp = src; src = dst; dst = tmp;
  }
  // 6 passes -> result back in pidA (== src)

  // ---------- phase 7: gather sorted scores/boxes ----------
  for (int r = tid; r < KSEL; r += 1024) {
    int idx = (int)src[r];
    sscore[(size_t)b * NPRE + r] = sc[idx];
    sbox[(size_t)b * NPRE + r] = boxes[(size_t)b * NANCH + idx];
  }
}

// ---------------- IoU suppression bitmask ----------------
__device__ __forceinline__ void iou_compute(const float4* bi, const float4* bj,
                                            uint64_t* __restrict__ M,
                                            int b, int it, int jt, int tid) {
  int li = tid & 63, wq = tid >> 6;
  int i = it * 64 + li;
  int w = jt * 4 + wq;
  if (i < NPRE && w < NW) {
    float4 A = bi[li];
    float areaA = (A.z - A.x) * (A.w - A.y);
    uint64_t bits = 0;
#pragma unroll 8
    for (int jj = 0; jj < 64; ++jj) {
      int j = w * 64 + jj;
      float4 Bx = bj[wq * 64 + jj];
      float ix1 = fmaxf(A.x, Bx.x), iy1 = fmaxf(A.y, Bx.y);
      float ix2 = fminf(A.z, Bx.z), iy2 = fminf(A.w, Bx.w);
      float inter = fmaxf(ix2 - ix1, 0.f) * fmaxf(iy2 - iy1, 0.f);
      float areaB = (Bx.z - Bx.x) * (Bx.w - Bx.y);
      float iou = inter / (areaA + areaB - inter);
      if ((j > i) && (j < NPRE) && (iou > 0.7f)) bits |= (1ull << jj);
    }
    M[((size_t)b * NPRE + i) * NW + w] = bits;
  }
}

// common path: rows < CMAX*64 AND columns w < CMAX
__global__ __launch_bounds__(256) void iou_mat(const float4* __restrict__ sbox,
                                               uint64_t* __restrict__ M) {
  __shared__ float4 bi[64];
  __shared__ float4 bj[256];
  int b = blockIdx.z, it = blockIdx.x, jt = blockIdx.y;
  int tid = threadIdx.x;
  if (tid < 64) {
    int i = it * 64 + tid;
    bi[tid] = (i < NPRE) ? sbox[(size_t)b * NPRE + i] : make_float4(0, 0, 0, 0);
  }
  {
    int j = jt * 256 + tid;
    bj[tid] = (j < NPRE) ? sbox[(size_t)b * NPRE + j] : make_float4(0, 0, 0, 0);
  }
  __syncthreads();
  iou_compute(bi, bj, M, b, it, jt, tid);
}

// fallback complement, R25: each block covers 16 words (4 jt sub-tiles) ->
// grid (94, 6, 2) = 1128 blocks (was 4512). Common path: early return.
__global__ __launch_bounds__(256) void iou_rest(const float4* __restrict__ sbox,
                                                uint64_t* __restrict__ M,
                                                const unsigned int* __restrict__ state) {
  if (state[blockIdx.z * 192 + 189]) return;  // done
  int it = blockIdx.x, jt16 = blockIdx.y, b = blockIdx.z;
  int tid = threadIdx.x;
  __shared__ float4 bi[64];
  __shared__ float4 bj[256];
  if (tid < 64) {
    int i = it * 64 + tid;
    bi[tid] = (i < NPRE) ? sbox[(size_t)b * NPRE + i] : make_float4(0, 0, 0, 0);
  }
#pragma unroll
  for (int q = 0; q < 4; ++q) {
    int jt = jt16 * 4 + q;
    bool skip = (it < CMAX && jt < CMAX / 4);  // covered by iou_mat (block-uniform)
    __syncthreads();  // bi ready (q=0) / previous compute's bj reads done (WAR)
    if (!skip) {
      int j = jt * 256 + tid;
      bj[tid] = (j < NPRE) ? sbox[(size_t)b * NPRE + j] : make_float4(0, 0, 0, 0);
    }
    __syncthreads();
    if (!skip) iou_compute(bi, bj, M, b, it, jt, tid);
  }
}

// ---------------- NMS scan: wave0 serial closure + block-parallel OR + early exit ----------------
__device__ inline uint64_t shfl64(uint64_t v, int src) {
  int lo = __shfl((int)(unsigned int)(v & 0xFFFFFFFFull), src, 64);
  int hi = __shfl((int)(unsigned int)(v >> 32), src, 64);
  return ((uint64_t)(unsigned int)hi << 32) | (unsigned int)lo;
}

// one NMS chunk step; OR restricted to w < wlimit. keptS (LDS) optional.
__device__ __forceinline__ void nms_chunk(const uint64_t* __restrict__ Mb,
                                          const float* __restrict__ sscore,
                                          uint64_t* __restrict__ keep,
                                          int b, int c, int tid, int wlimit,
                                          unsigned int* supLo, unsigned int* supHi,
                                          int* klist, int* knS, int* countS,
                                          uint64_t* keptS) {
  int ibase = c * 64;
  if (tid < 64) {
    int lane = tid;
    if (lane == 0) *knS = 0;
    uint64_t supc = ((uint64_t)supHi[c] << 32) | supLo[c];
    uint64_t validm = (c == NW - 1) ? ((1ull << (NPRE - (NW - 1) * 64)) - 1ull) : ~0ull;
    int pos = ibase + lane;
    uint64_t myrow = (pos < NPRE) ? Mb[(size_t)pos * NW + c] : 0ull;
    bool sval = (pos < NPRE) && (sscore[(size_t)b * NPRE + pos] >= 0.f);
    uint64_t vb = __ballot(sval);
    uint64_t cur = validm & ~supc;
    uint64_t kept = 0;
    while (cur) {
      int i = __ffsll((long long)cur) - 1;
      kept |= (1ull << i);
      cur &= ~(1ull << i);
      uint64_t row = shfl64(myrow, i);
      cur &= ~row;
    }
    if (kept & (1ull << lane)) {
      int pp = atomicAdd(knS, 1);
      klist[pp] = lane;
    }
    if (lane == 0) {
      keep[b * NW + c] = kept;
      if (keptS) keptS[c] = kept;
      *countS += __popcll(kept & vb);
    }
  }
  __syncthreads();  // [A] klist/knS/count visible; sup[c] consumed
  int kn = *knS;
  for (int t = tid; t < kn * 128; t += 1024) {
    int ii = t >> 7, w = t & 127;
    if (w > c && w < wlimit) {
      uint64_t row = Mb[(size_t)(ibase + klist[ii]) * NW + w];
      unsigned int lo = (unsigned int)row;
      unsigned int hi = (unsigned int)(row >> 32);
      if (lo) atomicOr(&supLo[w], lo);
      if (hi) atomicOr(&supHi[w], hi);
    }
  }
  __syncthreads();  // [B] sup updated before next chunk's closure
}

// phase A: chunks 0..CMAX, OR width limited to CMAX. Common path (done):
// emits output directly from LDS keptS; nms_finish then early-outs.
__global__ __launch_bounds__(1024) void nms_scan(const uint64_t* __restrict__ M,
                                                 const float* __restrict__ sscore,
                                                 uint64_t* __restrict__ keep,
                                                 unsigned int* __restrict__ state,
                                                 const float4* __restrict__ sbox,
                                                 float* __restrict__ out) {
  __shared__ unsigned int supLo[NW], supHi[NW];
  __shared__ int klist[64];
  __shared__ int knS;
  __shared__ int countS;
  __shared__ uint64_t keptS[NW];
  __shared__ int cnt[128];
  __shared__ uint64_t fw[NW];
  int b = blockIdx.x;
  int tid = threadIdx.x;
  const uint64_t* Mb = M + (size_t)b * NPRE * NW;

  for (int w = tid; w < NW; w += 1024) {
    supLo[w] = 0;
    supHi[w] = 0;
    keptS[w] = 0;
    keep[b * NW + w] = 0;  // early-exit / fallback leaves untouched chunks zeroed
  }
  if (tid == 0) countS = 0;
  __syncthreads();

  int done = 0;
  for (int c = 0; c < CMAX; ++c) {
    nms_chunk(Mb, sscore, keep, b, c, tid, CMAX, supLo, supHi, klist, &knS, &countS, keptS);
    if (countS >= 300) { done = 1; break; }  // uniform: countS read post-barrier
  }
  __syncthreads();
  unsigned int* st = state + b * 192;
  for (int w = tid; w < NW; w += 1024) { st[w] = supLo[w]; st[94 + w] = supHi[w]; }
  if (tid == 0) { st[188] = (unsigned int)countS; st[189] = (unsigned int)done; }

  if (done) {
    // ---- common-path emit (from LDS keptS) ----
    for (int i = tid; i < 1200; i += 1024) out[b * 1200 + i] = 0.f;
    if (tid < 300) {
      out[2400 + b * 300 + tid] = 0.f;
      out[3000 + b * 300 + tid] = 0.f;
    }
    uint64_t fwv = 0;
    if (tid < NW) {
      uint64_t kw = keptS[tid];
      while (kw) {
        int j = __ffsll((long long)kw) - 1;
        kw &= kw - 1;
        if (sscore[(size_t)b * NPRE + tid * 64 + j] >= 0.f) fwv |= (1ull << j);
      }
      fw[tid] = fwv;
    }
    if (tid < 128) cnt[tid] = (tid < NW) ? __popcll(fwv) : 0;
    __syncthreads();
    for (int off = 1; off < 128; off <<= 1) {
      int v = 0, u = 0;
      if (tid < 128) {
        v = cnt[tid];
        u = (tid >= off) ? cnt[tid - off] : 0;
      }
      __syncthreads();
      if (tid < 128) cnt[tid] = v + u;
      __syncthreads();
    }
    if (tid < NW) {
      int base = cnt[tid] - __popcll(fw[tid]);
      uint64_t ww = fw[tid];
      while (ww) {
        int j = __ffsll((long long)ww) - 1;
        ww &= ww - 1;
        if (base < 300) {
          int p = tid * 64 + j;
          float4 bx = sbox[(size_t)b * NPRE + p];
          float* ob = out + b * 1200 + base * 4;
          ob[0] = bx.x; ob[1] = bx.y; ob[2] = bx.z; ob[3] = bx.w;
          out[2400 + b * 300 + base] = sscore[(size_t)b * NPRE + p];
          out[3000 + b * 300 + base] = 1.0f;
        }
        ++base;
      }
    }
  }
}

// fallback scan + emit. Common path (st[189]==1): return immediately.
__global__ __launch_bounds__(1024) void nms_finish(const uint64_t* __restrict__ M,
                                                   const float* __restrict__ sscore,
                                                   uint64_t* __restrict__ keep,
                                                   const unsigned int* __restrict__ state,
                                                   const float4* __restrict__ sbox,
                                                   float* __restrict__ out) {
  __shared__ unsigned int supLo[NW], supHi[NW];
  __shared__ int klist[64];
  __shared__ int knS;
  __shared__ int countS;
  __shared__ int cnt[128];
  __shared__ uint64_t fw[NW];
  int b = blockIdx.x;
  int tid = threadIdx.x;
  const uint64_t* Mb = M + (size_t)b * NPRE * NW;
  const unsigned int* st = state + b * 192;

  if (st[189]) return;  // common path: nms_scan already emitted

  for (int w = tid; w < NW; w += 1024) { supLo[w] = st[w]; supHi[w] = st[94 + w]; }
  if (tid == 0) countS = (int)st[188];
  __syncthreads();
  // reconstruct sup words >= CMAX from kept rows of chunks < CMAX
  for (int c = 0; c < CMAX; ++c) {
    uint64_t kw = keep[b * NW + c];
    if (!kw) continue;  // uniform (all threads read same global)
    int ibase = c * 64;
    const int WREST = NW - CMAX;  // 62
    for (int t = tid; t < 64 * WREST; t += 1024) {
      int j = t / WREST;
      int w = CMAX + (t % WREST);
      if ((kw >> j) & 1ull) {
        uint64_t row = Mb[(size_t)(ibase + j) * NW + w];
        unsigned int lo = (unsigned int)row;
        unsigned int hi = (unsigned int)(row >> 32);
        if (lo) atomicOr(&supLo[w], lo);
        if (hi) atomicOr(&supHi[w], hi);
      }
    }
  }
  __syncthreads();
  for (int c = CMAX; c < NW; ++c) {
    nms_chunk(Mb, sscore, keep, b, c, tid, NW, supLo, supHi, klist, &knS, &countS, nullptr);
    if (countS >= 300) break;
  }
  __threadfence();  // keep[] writes visible to part 2 reads
  __syncthreads();

  // ---- part 2: emit ----
  for (int i = tid; i < 1200; i += 1024) out[b * 1200 + i] = 0.f;
  if (tid < 300) {
    out[2400 + b * 300 + tid] = 0.f;
    out[3000 + b * 300 + tid] = 0.f;
  }
  uint64_t w = 0;
  if (tid < NW) {
    uint64_t kw = keep[b * NW + tid];
    while (kw) {
      int j = __ffsll((long long)kw) - 1;
      kw &= kw - 1;
      if (sscore[(size_t)b * NPRE + tid * 64 + j] >= 0.f) w |= (1ull << j);
    }
    fw[tid] = w;
  }
  if (tid < 128) cnt[tid] = (tid < NW) ? __popcll(w) : 0;
  __syncthreads();
  for (int off = 1; off < 128; off <<= 1) {
    int v = 0, u = 0;
    if (tid < 128) {
      v = cnt[tid];
      u = (tid >= off) ? cnt[tid - off] : 0;
    }
    __syncthreads();
    if (tid < 128) cnt[tid] = v + u;
    __syncthreads();
  }
  if (tid < NW) {
    int base = cnt[tid] - __popcll(fw[tid]);
    uint64_t ww = fw[tid];
    while (ww) {
      int j = __ffsll((long long)ww) - 1;
      ww &= ww - 1;
      if (base < 300) {
        int p = tid * 64 + j;
        float4 bx = sbox[(size_t)b * NPRE + p];
        float* ob = out + b * 1200 + base * 4;
        ob[0] = bx.x; ob[1] = bx.y; ob[2] = bx.z; ob[3] = bx.w;
        out[2400 + b * 300 + base] = sscore[(size_t)b * NPRE + p];
        out[3000 + b * 300 + base] = 1.0f;
      }
      ++base;
    }
  }
}

// ---------------- launch ----------------
extern "C" void kernel_launch(void* const* d_in, const int* in_sizes, int n_in,
                              void* d_out, int out_size, void* d_ws, size_t ws_size,
                              hipStream_t stream) {
  const float* x       = (const float*)d_in[0];
  const float* conv1_w = (const float*)d_in[1];
  const float* conv1_b = (const float*)d_in[2];
  const float* obj_w   = (const float*)d_in[3];
  const float* obj_b   = (const float*)d_in[4];
  const float* loc_w   = (const float*)d_in[5];
  const float* loc_b   = (const float*)d_in[6];
  const float* anch    = (const float*)d_in[7];
  const int*   img_h   = (const int*)d_in[8];
  const int*   img_w   = (const int*)d_in[9];

  char* base = (char*)d_ws;
  const size_t NEED_SPLIT = 52359424;
  bool use_split = (ws_size >= NEED_SPLIT);

  float* wt = (float*)(base + 0);  // 4,718,592
  float* h;
  uint64_t* M;
  float* scores;
  float4* boxes;
  float* sscore;
  float4* sbox;
  uint64_t* keep;
  float* xp;
  unsigned int* state;
  float* wt54b;

  size_t off = 4718592;
  h = (float*)(base + off);
  M = (uint64_t*)(base + off);
  off += use_split ? 40960000 : 10240000;
  scores = (float*)(base + off); off += 180000;
  boxes  = (float4*)(base + off); off += 720000;
  sscore = (float*)(base + off); off += 48000;
  sbox   = (float4*)(base + off);
  wt54b  = (float*)sbox;  // aliases sbox: prep writes, heads reads, topk ph7 overwrites after
  off += 192000;
  keep   = (uint64_t*)(base + off); off += 1504;
  xp     = (float*)(base + off); off += 5537792;
  state  = (unsigned int*)(base + off);

  hipLaunchKernelGGL(prep, dim3(2612), dim3(256), 0, stream,
                     conv1_w, wt, x, xp, obj_w, loc_w, wt54b);
  if (use_split) {
    hipLaunchKernelGGL(conv1_gemm_split, dim3(20, 16, 2), dim3(256), 0, stream, xp, wt, h);
    hipLaunchKernelGGL((heads_t<true>), dim3(1250), dim3(64), 0, stream, h, conv1_b, wt54b,
                       obj_b, loc_b, anch, img_h, img_w, scores, boxes);
  } else {
    hipLaunchKernelGGL(conv1_gemm_mono, dim3(40, 8, 2), dim3(256), 0, stream, xp, wt,
                       conv1_b, h);
    hipLaunchKernelGGL((heads_t<false>), dim3(1250), dim3(64), 0, stream, h, conv1_b, wt54b,
                       obj_b, loc_b, anch, img_h, img_w, scores, boxes);
  }
  // common path: sort only top-2048 (all NMS consumes within CMAX budget)
  hipLaunchKernelGGL((topk_sort_t<KFAST, 32, 2048, false>), dim3(2), dim3(1024), 0, stream,
                     scores, boxes, sscore, sbox, state);
  hipLaunchKernelGGL(iou_mat, dim3(CMAX, CMAX / 4, 2), dim3(256), 0, stream, sbox, M);
  hipLaunchKernelGGL(nms_scan, dim3(2), dim3(1024), 0, stream, M, sscore, keep, state,
                     sbox, (float*)d_out);
  // fallback chain (gated on !done): full 6000 sort -> remaining IoU -> rest-scan+emit
  hipLaunchKernelGGL((topk_sort_t<NPRE, 94, 6144, true>), dim3(2), dim3(1024), 0, stream,
                     scores, boxes, sscore, sbox, state);
  hipLaunchKernelGGL(iou_rest, dim3(NW, 6, 2), dim3(256), 0, stream, sbox, M, state);
  hipLaunchKernelGGL(nms_finish, dim3(2), dim3(1024), 0, stream, M, sscore, keep, state,
                     sbox, (float*)d_out);
}

// Round 11
// 362.915 us; speedup vs baseline: 1.0623x; 1.0377x over previous
//
#include <hip/hip_runtime.h>
#include <stdint.h>

// ---------------- constants ----------------
#define NPOS 2500      // 50*50
#define NANCH 22500    // NPOS*9
#define NPRE 6000
#define NW 94          // ceil(6000/64)
#define XPAD 2704      // 52*52 padded plane
#define CMAX 32        // proven NMS chunk budget (2048 candidates)
#define KFAST 2048     // common-path sort depth (= CMAX*64)
#define HPART 2560000  // floats per split-K partial (2*2500*512)

// async global->LDS DMA (gfx950). dst is wave-uniform base + lane*size.
__device__ __forceinline__ void gl_lds4(const float* g, float* l) {
  __builtin_amdgcn_global_load_lds((const __attribute__((address_space(1))) void*)g,
                                   (__attribute__((address_space(3))) void*)l, 4, 0, 0);
}
__device__ __forceinline__ void gl_lds16(const float* g, float* l) {
  __builtin_amdgcn_global_load_lds((const __attribute__((address_space(1))) void*)g,
                                   (__attribute__((address_space(3))) void*)l, 16, 0, 0);
}

// ---------------- fused prep: weight transpose + x pad(f4) + head-weight transpose ----------------
__global__ __launch_bounds__(256) void prep(const float* __restrict__ w,
                                            float* __restrict__ wt,
                                            const float* __restrict__ x,
                                            float* __restrict__ xp,
                                            const float* __restrict__ objw,
                                            const float* __restrict__ locw,
                                            float* __restrict__ wt54b) {
  __shared__ float tile[32][33];
  int bid = blockIdx.x;
  int tid = threadIdx.x;
  if (bid < 1152) {
    // ---- role A: conv weight transpose ----
    int k0 = (bid % 72) * 32;   // k' = ic*9 + tap
    int o0 = (bid / 72) * 32;
    int tx = tid & 31;
    int ty = tid >> 5;  // 0..7
#pragma unroll
    for (int i = 0; i < 4; ++i) {
      int oc = o0 + ty + i * 8;
      int kp = k0 + tx;
      tile[ty + i * 8][tx] = w[(size_t)oc * 2304 + kp];
    }
    __syncthreads();
#pragma unroll
    for (int i = 0; i < 4; ++i) {
      int kp = k0 + ty + i * 8;
      int ic = kp / 9, tap = kp % 9;
      wt[((size_t)tap * 256 + ic) * 512 + (o0 + tx)] = tile[tx][ty + i * 8];
    }
  } else if (bid < 2504) {
    // ---- role B: zero-pad x, one float4 per thread (2704 = 676 f4/plane) ----
    int t = (bid - 1152) * 256 + tid;   // float4 index
    if (t < 2 * 256 * 676) {
      int c = t / 676;        // b*256 + ic
      int q = t % 676;
      int r0 = q * 4;
      float v[4];
#pragma unroll
      for (int k = 0; k < 4; ++k) {
        int r = r0 + k;
        int yy = r / 52, xx = r % 52;
        v[k] = (yy >= 1 && yy <= 50 && xx >= 1 && xx <= 50)
                   ? x[(size_t)c * NPOS + (yy - 1) * 50 + (xx - 1)]
                   : 0.f;
      }
      ((float4*)xp)[t] = make_float4(v[0], v[1], v[2], v[3]);
    }
  } else {
    // ---- role C: head-weight transpose to [k/4][oc][4] ----
    int t = (bid - 2504) * 256 + tid;
    if (t < 54 * 512) {
      int oc = t / 512, k = t % 512;
      float v = (oc < 18) ? objw[(size_t)oc * 512 + k] : locw[(size_t)(oc - 18) * 512 + k];
      wt54b[((size_t)(k >> 2) * 64 + oc) * 4 + (k & 3)] = v;
    }
  }
}

// ---------------- conv1 split-K=N (R26) ----------------
// R20 structure (2-barrier BK=32 chunks, 128x128 tile, 8x8/thread, 16 FMA per
// ds_read_b128) — proven 172-174us at NSPLIT=4 (640 blocks = 2.5 blocks/CU,
// LDS pipe 67% utilized; residual = barrier-drain exposure). NSPLIT=8 doubles
// grid to 1280 blocks = 5 blocks/CU (160KB LDS = exact fit) = 20 waves/CU to
// hide the drains; 9 chunks/block. Same staging + accumulation order per
// chunk; partial partition differs (same reorder class harness accepted).
template <int NSPLIT>
__global__ __launch_bounds__(256) void conv1_gemm_split(const float* __restrict__ xp,
                                                        const float* __restrict__ wt,
                                                        float* __restrict__ hpart) {
  constexpr int ICC_PER = 8 / NSPLIT;  // 32-ic chunks per block per tap
  __shared__ __align__(16) float As[32][128];
  __shared__ __align__(16) float Bs[32][128];
  int b = blockIdx.z;
  int m0 = blockIdx.x * 128;
  int oc0 = (blockIdx.y & 3) * 128;
  int kh = blockIdx.y >> 2;        // 0..NSPLIT-1
  int tid = threadIdx.x;
  int lane = tid & 63;
  int wv = tid >> 6;   // wave 0..3
  int tm = tid >> 4;   // 0..15
  int tn = tid & 15;   // 0..15
  float acc[8][8] = {};

  int p0r = m0 + lane;
  int p0c = p0r < NPOS ? p0r : (NPOS - 1);
  int p1r = m0 + 64 + lane;
  int p1c = p1r < NPOS ? p1r : (NPOS - 1);
  const float* gA0 = xp + (size_t)b * 256 * XPAD + (p0c / 50) * 52 + (p0c % 50) + 53;
  const float* gA1 = xp + (size_t)b * 256 * XPAD + (p1c / 50) * 52 + (p1c % 50) + 53;
  int brow = lane >> 5, bcol4 = (lane & 31) * 4;

  for (int tap = 0; tap < 9; ++tap) {
    int ky = tap / 3 - 1, kx = tap % 3 - 1;
    int koff = ky * 52 + kx;
#pragma unroll
    for (int ii = 0; ii < ICC_PER; ++ii) {
      int ic0 = (kh * ICC_PER + ii) * 32;
      __syncthreads();  // LDS consumed by previous chunk's compute
#pragma unroll
      for (int j = 0; j < 8; ++j) {
        int kk = wv * 8 + j;
        gl_lds4(gA0 + (size_t)(ic0 + kk) * XPAD + koff, &As[kk][0]);
        gl_lds4(gA1 + (size_t)(ic0 + kk) * XPAD + koff, &As[kk][64]);
      }
#pragma unroll
      for (int q = 0; q < 4; ++q) {
        int r0 = wv * 8 + q * 2;  // instr covers rows r0, r0+1 (1KB)
        gl_lds16(wt + ((size_t)tap * 256 + ic0 + r0 + brow) * 512 + oc0 + bcol4,
                 &Bs[r0][0]);
      }
      __syncthreads();  // drains vmcnt -> DMAs complete
#pragma unroll 4
      for (int kk = 0; kk < 32; ++kk) {
        float4 a0 = *(const float4*)&As[kk][tm * 4];
        float4 a1 = *(const float4*)&As[kk][64 + tm * 4];
        float4 b0 = *(const float4*)&Bs[kk][tn * 4];
        float4 b1 = *(const float4*)&Bs[kk][64 + tn * 4];
        float am[8] = {a0.x, a0.y, a0.z, a0.w, a1.x, a1.y, a1.z, a1.w};
        float bn[8] = {b0.x, b0.y, b0.z, b0.w, b1.x, b1.y, b1.z, b1.w};
#pragma unroll
        for (int i = 0; i < 8; ++i)
#pragma unroll
          for (int j = 0; j < 8; ++j) acc[i][j] = fmaf(am[i], bn[j], acc[i][j]);
      }
    }
  }
  float* hp = hpart + (size_t)kh * HPART;
#pragma unroll
  for (int i = 0; i < 8; ++i) {
    int row = m0 + ((i & 4) ? 64 : 0) + tm * 4 + (i & 3);
    if (row < NPOS) {
      float* hrow = &hp[((size_t)b * NPOS + row) * 512 + oc0];
      float4 v0 = make_float4(acc[i][0], acc[i][1], acc[i][2], acc[i][3]);
      float4 v1 = make_float4(acc[i][4], acc[i][5], acc[i][6], acc[i][7]);
      *(float4*)&hrow[tn * 4] = v0;
      *(float4*)&hrow[64 + tn * 4] = v1;
    }
  }
}

// ---------------- conv1 mono (EXACT R7, known-good 202us): ws fallback ----------------
__global__ __launch_bounds__(256) void conv1_gemm_mono(const float* __restrict__ xp,
                                                       const float* __restrict__ wt,
                                                       const float* __restrict__ bias,
                                                       float* __restrict__ h) {
  __shared__ __align__(16) float As[32][64];
  __shared__ __align__(16) float Bs[32][64];
  int b = blockIdx.z;
  int m0 = blockIdx.x * 64;
  int oc0 = blockIdx.y * 64;
  int tid = threadIdx.x;
  int lane = tid & 63;
  int wv = tid >> 6;
  int tn = tid & 15, tm = tid >> 4;
  float acc[4][4] = {};

  int p = m0 + lane;
  int pc = p < NPOS ? p : (NPOS - 1);
  int py = pc / 50, px = pc % 50;
  const float* gA0 = xp + (size_t)b * 256 * XPAD + py * 52 + px + 53;
  int brow = lane >> 4, bcol4 = (lane & 15) * 4;

  for (int tap = 0; tap < 9; ++tap) {
    int ky = tap / 3 - 1, kx = tap % 3 - 1;
    int koff = ky * 52 + kx;
    for (int icc = 0; icc < 8; ++icc) {
      int ic0 = icc * 32;
      __syncthreads();
#pragma unroll
      for (int j = 0; j < 8; ++j) {
        int kk = wv * 8 + j;
        gl_lds4(gA0 + (size_t)(ic0 + kk) * XPAD + koff, &As[kk][0]);
      }
#pragma unroll
      for (int q = 0; q < 2; ++q) {
        int r0 = wv * 8 + q * 4;
        gl_lds16(wt + ((size_t)tap * 256 + ic0 + r0 + brow) * 512 + oc0 + bcol4,
                 &Bs[r0][0]);
      }
      __syncthreads();
#pragma unroll
      for (int kk = 0; kk < 32; ++kk) {
        float4 av = *(const float4*)&As[kk][tm * 4];
        float4 bv = *(const float4*)&Bs[kk][tn * 4];
        float am[4] = {av.x, av.y, av.z, av.w};
        float bn[4] = {bv.x, bv.y, bv.z, bv.w};
#pragma unroll
        for (int i = 0; i < 4; ++i)
#pragma unroll
          for (int j = 0; j < 4; ++j) acc[i][j] = fmaf(am[i], bn[j], acc[i][j]);
      }
    }
  }
#pragma unroll
  for (int i = 0; i < 4; ++i) {
    int pp = m0 + tm * 4 + i;
    if (pp < NPOS) {
      float4 v;
      float* vp = (float*)&v;
#pragma unroll
      for (int j = 0; j < 4; ++j) {
        int oc = oc0 + tn * 4 + j;
        vp[j] = fmaxf(acc[i][j] + bias[oc], 0.f);
      }
      *(float4*)&h[((size_t)b * NPOS + pp) * 512 + oc0 + tn * 4] = v;
    }
  }
}

// ---------------- heads: NSPLIT=0 -> mono load; else sum NSPLIT partials + bias + relu ----------------
template <int NSPLIT>
__global__ __launch_bounds__(64) void heads_t(const float* __restrict__ h,
                                              const float* __restrict__ convb,
                                              const float* __restrict__ wt54b,
                                              const float* __restrict__ objb,
                                              const float* __restrict__ locb,
                                              const float* __restrict__ anch,
                                              const int* __restrict__ imgh,
                                              const int* __restrict__ imgw,
                                              float* __restrict__ scores,
                                              float4* __restrict__ boxes) {
  __shared__ float hv[4 * 512];
  __shared__ float outs[4][64];
  int blk = blockIdx.x;             // 0..1249
  int b = blk / 625;
  int p0 = (blk % 625) * 4;         // 4 consecutive positions
  int lane = threadIdx.x;
  const float4* h4 = (const float4*)h;
  size_t base = ((size_t)b * NPOS + p0) * 128;  // float4 units
  float4* hv4 = (float4*)hv;
  if (NSPLIT == 0) {
#pragma unroll
    for (int q = 0; q < 8; ++q) {
      int f = lane + 64 * q;
      hv4[f] = h4[base + f];
    }
  } else {
    const float4* cb4 = (const float4*)convb;
#pragma unroll
    for (int q = 0; q < 8; ++q) {
      int f = lane + 64 * q;
      float4 s = h4[base + f];  // partial 0
#pragma unroll
      for (int k = 1; k < NSPLIT; ++k) {
        float4 sk = h4[(size_t)k * (HPART / 4) + base + f];
        s.x += sk.x; s.y += sk.y; s.z += sk.z; s.w += sk.w;
      }
      float4 bb = cb4[f & 127];
      float4 r;
      r.x = fmaxf(s.x + bb.x, 0.f);
      r.y = fmaxf(s.y + bb.y, 0.f);
      r.z = fmaxf(s.z + bb.z, 0.f);
      r.w = fmaxf(s.w + bb.w, 0.f);
      hv4[f] = r;
    }
  }
  __syncthreads();
  if (lane < 54) {
    float bias0 = (lane < 18) ? objb[lane] : locb[lane - 18];
    float a0 = bias0, a1 = bias0, a2 = bias0, a3 = bias0;
    const float4* w4 = (const float4*)wt54b;
#pragma unroll 4
    for (int k = 0; k < 128; ++k) {
      float4 wv = w4[k * 64 + lane];
      float4 h0 = hv4[k], h1 = hv4[128 + k], h2 = hv4[256 + k], h3 = hv4[384 + k];
      a0 = fmaf(wv.x, h0.x, a0); a0 = fmaf(wv.y, h0.y, a0);
      a0 = fmaf(wv.z, h0.z, a0); a0 = fmaf(wv.w, h0.w, a0);
      a1 = fmaf(wv.x, h1.x, a1); a1 = fmaf(wv.y, h1.y, a1);
      a1 = fmaf(wv.z, h1.z, a1); a1 = fmaf(wv.w, h1.w, a1);
      a2 = fmaf(wv.x, h2.x, a2); a2 = fmaf(wv.y, h2.y, a2);
      a2 = fmaf(wv.z, h2.z, a2); a2 = fmaf(wv.w, h2.w, a2);
      a3 = fmaf(wv.x, h3.x, a3); a3 = fmaf(wv.y, h3.y, a3);
      a3 = fmaf(wv.z, h3.z, a3); a3 = fmaf(wv.w, h3.w, a3);
    }
    outs[0][lane] = a0; outs[1][lane] = a1; outs[2][lane] = a2; outs[3][lane] = a3;
  }
  __syncthreads();
  if (lane < 36) {
    int pi = lane / 9, a = lane % 9;
    int p = p0 + pi;
    float l0 = outs[pi][2 * a], l1 = outs[pi][2 * a + 1];
    float mx = fmaxf(l0, l1);
    float e0 = expf(l0 - mx);
    float e1 = expf(l1 - mx);
    float s = e1 / (e0 + e1);
    float d0 = outs[pi][18 + 4 * a + 0];
    float d1 = outs[pi][18 + 4 * a + 1];
    float d2 = outs[pi][18 + 4 * a + 2];
    float d3 = outs[pi][18 + 4 * a + 3];
    int ai = p * 9 + a;
    float4 A = ((const float4*)anch)[ai];
    float aw = A.z - A.x, ah = A.w - A.y;
    float acx = A.x + 0.5f * aw, acy = A.y + 0.5f * ah;
    float cx = acx + d0 * aw, cy = acy + d1 * ah;
    float w = aw * expf(d2), hh = ah * expf(d3);
    float W = (float)imgw[0], H = (float)imgh[0];
    float x1 = fminf(fmaxf(cx - 0.5f * w, 0.f), W);
    float y1 = fminf(fmaxf(cy - 0.5f * hh, 0.f), H);
    float x2 = fminf(fmaxf(cx + 0.5f * w, 0.f), W);
    float y2 = fminf(fmaxf(cy + 0.5f * hh, 0.f), H);
    bool valid = (x2 - x1 >= 16.f) && (y2 - y1 >= 16.f);
    scores[(size_t)b * NANCH + ai] = valid ? s : -1.f;
    boxes[(size_t)b * NANCH + ai] = make_float4(x1, y1, x2, y2);
  }
}

// ---------------- top-K select + stable radix sort (one block per batch) ----------------
__device__ inline unsigned int mono_of(float f) {
  unsigned int u = __float_as_uint(f);
  return (u & 0x80000000u) ? ~u : (u | 0x80000000u);
}

// strict suffix sum over 1024 per-thread values (2 barriers)
__device__ __forceinline__ unsigned int suffix_strict(unsigned int v,
                                                      unsigned int* partw,
                                                      int tid, int lane, int wv) {
  unsigned int inc = v;
#pragma unroll
  for (int d = 1; d < 64; d <<= 1) {
    unsigned int u = __shfl_down(inc, d, 64);
    if (lane + d < 64) inc += u;
  }
  if (lane == 0) partw[wv] = inc;  // wave total
  __syncthreads();
  if (tid < 16) {
    unsigned int tot = partw[tid];
    unsigned int inc2 = tot;
#pragma unroll
    for (int d = 1; d < 16; d <<= 1) {
      unsigned int u = __shfl_down(inc2, d, 64);
      if (tid + d < 16) inc2 += u;
    }
    partw[tid] = inc2 - tot;  // strict suffix of later waves
  }
  __syncthreads();
  return partw[wv] + (inc - v);
}

template <int KSEL, int SLOTK, int TBLSZ, bool GATED>
__global__ __launch_bounds__(1024) void topk_sort_t(const float* __restrict__ scores,
                                                    const float4* __restrict__ boxes,
                                                    float* __restrict__ sscore,
                                                    float4* __restrict__ sbox,
                                                    const unsigned int* __restrict__ state) {
  int b = blockIdx.x;
  if (GATED && state[b * 192 + 189]) return;  // common path: NMS already done
  const float* sc = scores + (size_t)b * NANCH;
  __shared__ unsigned int hist[4096];
  __shared__ unsigned int part[1024];
  __shared__ unsigned short pidA[SLOTK * 64];
  __shared__ unsigned short pidB[SLOTK * 64];
  __shared__ unsigned short table[TBLSZ];   // 64 digits x SLOTK slots (padded)
  __shared__ int res[8];
  int tid = threadIdx.x;
  int lane = tid & 63;
  int wv = tid >> 6;

  // ---------- phase 1: top-12-bit histogram ----------
  for (int i = tid; i < 4096; i += 1024) hist[i] = 0;
  __syncthreads();
  for (int i = tid; i < NANCH; i += 1024) atomicAdd(&hist[mono_of(sc[i]) >> 20], 1u);
  __syncthreads();
  {
    unsigned int h0 = hist[4 * tid], h1 = hist[4 * tid + 1];
    unsigned int h2 = hist[4 * tid + 2], h3 = hist[4 * tid + 3];
    unsigned int c = suffix_strict(h0 + h1 + h2 + h3, part, tid, lane, wv);
    const unsigned int need = KSEL;
    if (c < need && c + h3 >= need) { res[0] = 4 * tid + 3; res[1] = (int)c; }
    c += h3;
    if (c < need && c + h2 >= need) { res[0] = 4 * tid + 2; res[1] = (int)c; }
    c += h2;
    if (c < need && c + h1 >= need) { res[0] = 4 * tid + 1; res[1] = (int)c; }
    c += h1;
    if (c < need && c + h0 >= need) { res[0] = 4 * tid + 0; res[1] = (int)c; }
  }
  __syncthreads();
  int t1 = res[0], a1 = res[1];
  __syncthreads();

  // ---------- phase 2: middle-12 bits within bin t1 ----------
  for (int i = tid; i < 4096; i += 1024) hist[i] = 0;
  __syncthreads();
  for (int i = tid; i < NANCH; i += 1024) {
    unsigned int m = mono_of(sc[i]);
    if ((int)(m >> 20) == t1) atomicAdd(&hist[(m >> 8) & 0xFFF], 1u);
  }
  __syncthreads();
  {
    unsigned int h0 = hist[4 * tid], h1 = hist[4 * tid + 1];
    unsigned int h2 = hist[4 * tid + 2], h3 = hist[4 * tid + 3];
    unsigned int c = suffix_strict(h0 + h1 + h2 + h3, part, tid, lane, wv);
    const unsigned int need = (unsigned)(KSEL - a1);
    if (c < need && c + h3 >= need) { res[2] = 4 * tid + 3; res[3] = (int)c; }
    c += h3;
    if (c < need && c + h2 >= need) { res[2] = 4 * tid + 2; res[3] = (int)c; }
    c += h2;
    if (c < need && c + h1 >= need) { res[2] = 4 * tid + 1; res[3] = (int)c; }
    c += h1;
    if (c < need && c + h0 >= need) { res[2] = 4 * tid + 0; res[3] = (int)c; }
  }
  __syncthreads();
  int t2 = res[2], a2 = res[3];
  __syncthreads();

  // ---------- phase 3: low-8 bits within (t1,t2) ----------
  for (int i = tid; i < 256; i += 1024) hist[i] = 0;
  __syncthreads();
  unsigned int top24 = ((unsigned int)t1 << 12) | (unsigned int)t2;
  for (int i = tid; i < NANCH; i += 1024) {
    unsigned int m = mono_of(sc[i]);
    if ((m >> 8) == top24) atomicAdd(&hist[m & 0xFF], 1u);
  }
  __syncthreads();
  {
    unsigned int hb = (tid < 256) ? hist[tid] : 0;
    unsigned int c = suffix_strict(hb, part, tid, lane, wv);
    if (tid < 256) {
      const unsigned int need = (unsigned)(KSEL - a1 - a2);
      if (c < need && c + hb >= need) {
        res[4] = tid;
        res[6] = (int)(need - c);                         // ties_needed
        res[7] = (hb == need - c) ? NANCH : -1;           // idx_cut or TBD
      }
    }
  }
  __syncthreads();
  int t3 = res[4];
  unsigned int T = (top24 << 8) | (unsigned int)t3;
  int ties_needed = res[6];
  int idx_cut = res[7];
  __syncthreads();

  // ---------- phase 4 (rare): tie resolution by smallest index ----------
  if (idx_cut < 0) {
    for (int i = tid; i < 704; i += 1024) hist[i] = 0;
    __syncthreads();
    for (int i = tid; i < NANCH; i += 1024)
      if (mono_of(sc[i]) == T) atomicAdd(&hist[i >> 5], 1u);
    __syncthreads();
    if (tid == 0) {
      int c = 0, cut = NANCH;
      for (int bin = 0; bin < 704; ++bin) {
        int hc = (int)hist[bin];
        if (c + hc >= ties_needed) {
          int c2 = c;
          for (int idx = bin * 32; idx < bin * 32 + 32; ++idx) {
            if (idx < NANCH && mono_of(sc[idx]) == T) {
              ++c2;
              if (c2 == ties_needed) { cut = idx; break; }
            }
          }
          break;
        }
        c += hc;
      }
      res[7] = cut;
    }
    __syncthreads();
    idx_cut = res[7];
    __syncthreads();
  }

  // ---------- phase 5: deterministic idx-order compact (blocked ranges + scan) ----------
  int base0 = tid * 22;  // 1024*22 = 22528 >= NANCH
  unsigned int selm = 0;
  int cnt = 0;
  for (int k = 0; k < 22; ++k) {
    int i = base0 + k;
    if (i < NANCH) {
      unsigned int m = mono_of(sc[i]);
      if (m > T || (m == T && i <= idx_cut)) { selm |= 1u << k; ++cnt; }
    }
  }
  {
    int inc = cnt;
#pragma unroll
    for (int d = 1; d < 64; d <<= 1) {
      int u = __shfl_up(inc, d, 64);
      if (lane >= d) inc += u;
    }
    if (lane == 63) part[wv] = (unsigned int)inc;
    __syncthreads();
    if (tid < 16) {
      int v = (int)part[tid];
      int inc2 = v;
#pragma unroll
      for (int d = 1; d < 16; d <<= 1) {
        int u = __shfl_up(inc2, d, 16);
        if (tid >= d) inc2 += u;
      }
      part[tid] = (unsigned int)(inc2 - v);  // exclusive wave base
    }
    __syncthreads();
    int pos = (int)part[wv] + (inc - cnt);
    for (int k = 0; k < 22; ++k)
      if ((selm >> k) & 1u) pidA[pos++] = (unsigned short)(base0 + k);
  }
  __syncthreads();

  // ---------- phase 6: 6-pass 6-bit stable LSD radix, key = ~mono (asc) ----------
  unsigned short* src = pidA;
  unsigned short* dst = pidB;
  constexpr int KITER = (SLOTK + 15) / 16;
  constexpr int VPT = TBLSZ / 1024;
  for (int pass = 0; pass < 6; ++pass) {
    int shift = pass * 6;
    for (int i = tid; i < TBLSZ; i += 1024) table[i] = 0;
    __syncthreads();
    int dig[KITER], irk[KITER], pidr[KITER];
#pragma unroll
    for (int k = 0; k < KITER; ++k) {
      dig[k] = 0; irk[k] = 0; pidr[k] = 0;
      int s = wv + 16 * k;          // wave-uniform
      if (s < SLOTK) {
        int e = s * 64 + lane;
        bool act = e < KSEL;
        int pid = act ? (int)src[e] : 0;
        unsigned int key = act ? ~mono_of(sc[pid]) : 0u;
        int d = (int)((key >> shift) & 63u);
        uint64_t peers = __ballot(act);
#pragma unroll
        for (int bb = 0; bb < 6; ++bb) {
          uint64_t bl = __ballot(((d >> bb) & 1) != 0);
          peers &= ((d >> bb) & 1) ? bl : ~bl;
        }
        if (act) {
          dig[k] = d;
          pidr[k] = pid;
          irk[k] = (int)__popcll(peers & ((1ull << lane) - 1ull));
          int leader = __ffsll((long long)peers) - 1;
          if (lane == leader)
            table[d * SLOTK + s] = (unsigned short)__popcll(peers);
        }
      }
    }
    __syncthreads();
    // exclusive scan over table[0..TBLSZ) (digit-major, slot-minor)
    {
      int tb = tid * VPT;
      int v[VPT];
      int lsum = 0;
#pragma unroll
      for (int q = 0; q < VPT; ++q) { v[q] = table[tb + q]; lsum += v[q]; }
      int inc = lsum;
#pragma unroll
      for (int d = 1; d < 64; d <<= 1) {
        int u = __shfl_up(inc, d, 64);
        if (lane >= d) inc += u;
      }
      if (lane == 63) part[wv] = (unsigned int)inc;
      __syncthreads();
      if (tid < 16) {
        int vv = (int)part[tid];
        int inc2 = vv;
#pragma unroll
        for (int d = 1; d < 16; d <<= 1) {
          int u = __shfl_up(inc2, d, 16);
          if (tid >= d) inc2 += u;
        }
        part[tid] = (unsigned int)(inc2 - vv);
      }
      __syncthreads();
      int run = (int)part[wv] + (inc - lsum);
#pragma unroll
      for (int q = 0; q < VPT; ++q) { table[tb + q] = (unsigned short)run; run += v[q]; }
    }
    __syncthreads();
    // scatter (stable): pos = base(digit,slot) + intra-slot rank
#pragma unroll
    for (int k = 0; k < KITER; ++k) {
      int s = wv + 16 * k;
      if (s < SLOTK) {
        int e = s * 64 + lane;
        if (e < KSEL) {
          int pos = (int)table[dig[k] * SLOTK + s] + irk[k];
          dst[pos] = (unsigned short)pidr[k];
        }
      }
    }
    __syncthreads();
    unsigned short* tmp = src; src = dst; dst = tmp;
  }
  // 6 passes -> result back in pidA (== src)

  // ---------- phase 7: gather sorted scores/boxes ----------
  for (int r = tid; r < KSEL; r += 1024) {
    int idx = (int)src[r];
    sscore[(size_t)b * NPRE + r] = sc[idx];
    sbox[(size_t)b * NPRE + r] = boxes[(size_t)b * NANCH + idx];
  }
}

// ---------------- IoU suppression bitmask ----------------
__device__ __forceinline__ void iou_compute(const float4* bi, const float4* bj,
                                            uint64_t* __restrict__ M,
                                            int b, int it, int jt, int tid) {
  int li = tid & 63, wq = tid >> 6;
  int i = it * 64 + li;
  int w = jt * 4 + wq;
  if (i < NPRE && w < NW) {
    float4 A = bi[li];
    float areaA = (A.z - A.x) * (A.w - A.y);
    uint64_t bits = 0;
#pragma unroll 8
    for (int jj = 0; jj < 64; ++jj) {
      int j = w * 64 + jj;
      float4 Bx = bj[wq * 64 + jj];
      float ix1 = fmaxf(A.x, Bx.x), iy1 = fmaxf(A.y, Bx.y);
      float ix2 = fminf(A.z, Bx.z), iy2 = fminf(A.w, Bx.w);
      float inter = fmaxf(ix2 - ix1, 0.f) * fmaxf(iy2 - iy1, 0.f);
      float areaB = (Bx.z - Bx.x) * (Bx.w - Bx.y);
      float iou = inter / (areaA + areaB - inter);
      if ((j > i) && (j < NPRE) && (iou > 0.7f)) bits |= (1ull << jj);
    }
    M[((size_t)b * NPRE + i) * NW + w] = bits;
  }
}

// common path: rows < CMAX*64 AND columns w < CMAX
__global__ __launch_bounds__(256) void iou_mat(const float4* __restrict__ sbox,
                                               uint64_t* __restrict__ M) {
  __shared__ float4 bi[64];
  __shared__ float4 bj[256];
  int b = blockIdx.z, it = blockIdx.x, jt = blockIdx.y;
  int tid = threadIdx.x;
  if (tid < 64) {
    int i = it * 64 + tid;
    bi[tid] = (i < NPRE) ? sbox[(size_t)b * NPRE + i] : make_float4(0, 0, 0, 0);
  }
  {
    int j = jt * 256 + tid;
    bj[tid] = (j < NPRE) ? sbox[(size_t)b * NPRE + j] : make_float4(0, 0, 0, 0);
  }
  __syncthreads();
  iou_compute(bi, bj, M, b, it, jt, tid);
}

// fallback complement: each block covers 16 words (4 jt sub-tiles)
__global__ __launch_bounds__(256) void iou_rest(const float4* __restrict__ sbox,
                                                uint64_t* __restrict__ M,
                                                const unsigned int* __restrict__ state) {
  if (state[blockIdx.z * 192 + 189]) return;  // done
  int it = blockIdx.x, jt16 = blockIdx.y, b = blockIdx.z;
  int tid = threadIdx.x;
  __shared__ float4 bi[64];
  __shared__ float4 bj[256];
  if (tid < 64) {
    int i = it * 64 + tid;
    bi[tid] = (i < NPRE) ? sbox[(size_t)b * NPRE + i] : make_float4(0, 0, 0, 0);
  }
#pragma unroll
  for (int q = 0; q < 4; ++q) {
    int jt = jt16 * 4 + q;
    bool skip = (it < CMAX && jt < CMAX / 4);  // covered by iou_mat (block-uniform)
    __syncthreads();  // bi ready (q=0) / previous compute's bj reads done (WAR)
    if (!skip) {
      int j = jt * 256 + tid;
      bj[tid] = (j < NPRE) ? sbox[(size_t)b * NPRE + j] : make_float4(0, 0, 0, 0);
    }
    __syncthreads();
    if (!skip) iou_compute(bi, bj, M, b, it, jt, tid);
  }
}

// ---------------- NMS scan: wave0 serial closure + block-parallel OR + early exit ----------------
__device__ inline uint64_t shfl64(uint64_t v, int src) {
  int lo = __shfl((int)(unsigned int)(v & 0xFFFFFFFFull), src, 64);
  int hi = __shfl((int)(unsigned int)(v >> 32), src, 64);
  return ((uint64_t)(unsigned int)hi << 32) | (unsigned int)lo;
}

// one NMS chunk step; OR restricted to w < wlimit. keptS (LDS) optional.
__device__ __forceinline__ void nms_chunk(const uint64_t* __restrict__ Mb,
                                          const float* __restrict__ sscore,
                                          uint64_t* __restrict__ keep,
                                          int b, int c, int tid, int wlimit,
                                          unsigned int* supLo, unsigned int* supHi,
                                          int* klist, int* knS, int* countS,
                                          uint64_t* keptS) {
  int ibase = c * 64;
  if (tid < 64) {
    int lane = tid;
    if (lane == 0) *knS = 0;
    uint64_t supc = ((uint64_t)supHi[c] << 32) | supLo[c];
    uint64_t validm = (c == NW - 1) ? ((1ull << (NPRE - (NW - 1) * 64)) - 1ull) : ~0ull;
    int pos = ibase + lane;
    uint64_t myrow = (pos < NPRE) ? Mb[(size_t)pos * NW + c] : 0ull;
    bool sval = (pos < NPRE) && (sscore[(size_t)b * NPRE + pos] >= 0.f);
    uint64_t vb = __ballot(sval);
    uint64_t cur = validm & ~supc;
    uint64_t kept = 0;
    while (cur) {
      int i = __ffsll((long long)cur) - 1;
      kept |= (1ull << i);
      cur &= ~(1ull << i);
      uint64_t row = shfl64(myrow, i);
      cur &= ~row;
    }
    if (kept & (1ull << lane)) {
      int pp = atomicAdd(knS, 1);
      klist[pp] = lane;
    }
    if (lane == 0) {
      keep[b * NW + c] = kept;
      if (keptS) keptS[c] = kept;
      *countS += __popcll(kept & vb);
    }
  }
  __syncthreads();  // [A] klist/knS/count visible; sup[c] consumed
  int kn = *knS;
  for (int t = tid; t < kn * 128; t += 1024) {
    int ii = t >> 7, w = t & 127;
    if (w > c && w < wlimit) {
      uint64_t row = Mb[(size_t)(ibase + klist[ii]) * NW + w];
      unsigned int lo = (unsigned int)row;
      unsigned int hi = (unsigned int)(row >> 32);
      if (lo) atomicOr(&supLo[w], lo);
      if (hi) atomicOr(&supHi[w], hi);
    }
  }
  __syncthreads();  // [B] sup updated before next chunk's closure
}

// phase A: chunks 0..CMAX, OR width limited to CMAX. Common path (done):
// emits output directly from LDS keptS; nms_finish then early-outs.
__global__ __launch_bounds__(1024) void nms_scan(const uint64_t* __restrict__ M,
                                                 const float* __restrict__ sscore,
                                                 uint64_t* __restrict__ keep,
                                                 unsigned int* __restrict__ state,
                                                 const float4* __restrict__ sbox,
                                                 float* __restrict__ out) {
  __shared__ unsigned int supLo[NW], supHi[NW];
  __shared__ int klist[64];
  __shared__ int knS;
  __shared__ int countS;
  __shared__ uint64_t keptS[NW];
  __shared__ int cnt[128];
  __shared__ uint64_t fw[NW];
  int b = blockIdx.x;
  int tid = threadIdx.x;
  const uint64_t* Mb = M + (size_t)b * NPRE * NW;

  for (int w = tid; w < NW; w += 1024) {
    supLo[w] = 0;
    supHi[w] = 0;
    keptS[w] = 0;
    keep[b * NW + w] = 0;  // early-exit / fallback leaves untouched chunks zeroed
  }
  if (tid == 0) countS = 0;
  __syncthreads();

  int done = 0;
  for (int c = 0; c < CMAX; ++c) {
    nms_chunk(Mb, sscore, keep, b, c, tid, CMAX, supLo, supHi, klist, &knS, &countS, keptS);
    if (countS >= 300) { done = 1; break; }  // uniform: countS read post-barrier
  }
  __syncthreads();
  unsigned int* st = state + b * 192;
  for (int w = tid; w < NW; w += 1024) { st[w] = supLo[w]; st[94 + w] = supHi[w]; }
  if (tid == 0) { st[188] = (unsigned int)countS; st[189] = (unsigned int)done; }

  if (done) {
    // ---- common-path emit (from LDS keptS) ----
    for (int i = tid; i < 1200; i += 1024) out[b * 1200 + i] = 0.f;
    if (tid < 300) {
      out[2400 + b * 300 + tid] = 0.f;
      out[3000 + b * 300 + tid] = 0.f;
    }
    uint64_t fwv = 0;
    if (tid < NW) {
      uint64_t kw = keptS[tid];
      while (kw) {
        int j = __ffsll((long long)kw) - 1;
        kw &= kw - 1;
        if (sscore[(size_t)b * NPRE + tid * 64 + j] >= 0.f) fwv |= (1ull << j);
      }
      fw[tid] = fwv;
    }
    if (tid < 128) cnt[tid] = (tid < NW) ? __popcll(fwv) : 0;
    __syncthreads();
    for (int off = 1; off < 128; off <<= 1) {
      int v = 0, u = 0;
      if (tid < 128) {
        v = cnt[tid];
        u = (tid >= off) ? cnt[tid - off] : 0;
      }
      __syncthreads();
      if (tid < 128) cnt[tid] = v + u;
      __syncthreads();
    }
    if (tid < NW) {
      int base = cnt[tid] - __popcll(fw[tid]);
      uint64_t ww = fw[tid];
      while (ww) {
        int j = __ffsll((long long)ww) - 1;
        ww &= ww - 1;
        if (base < 300) {
          int p = tid * 64 + j;
          float4 bx = sbox[(size_t)b * NPRE + p];
          float* ob = out + b * 1200 + base * 4;
          ob[0] = bx.x; ob[1] = bx.y; ob[2] = bx.z; ob[3] = bx.w;
          out[2400 + b * 300 + base] = sscore[(size_t)b * NPRE + p];
          out[3000 + b * 300 + base] = 1.0f;
        }
        ++base;
      }
    }
  }
}

// fallback scan + emit. Common path (st[189]==1): return immediately.
__global__ __launch_bounds__(1024) void nms_finish(const uint64_t* __restrict__ M,
                                                   const float* __restrict__ sscore,
                                                   uint64_t* __restrict__ keep,
                                                   const unsigned int* __restrict__ state,
                                                   const float4* __restrict__ sbox,
                                                   float* __restrict__ out) {
  __shared__ unsigned int supLo[NW], supHi[NW];
  __shared__ int klist[64];
  __shared__ int knS;
  __shared__ int countS;
  __shared__ int cnt[128];
  __shared__ uint64_t fw[NW];
  int b = blockIdx.x;
  int tid = threadIdx.x;
  const uint64_t* Mb = M + (size_t)b * NPRE * NW;
  const unsigned int* st = state + b * 192;

  if (st[189]) return;  // common path: nms_scan already emitted

  for (int w = tid; w < NW; w += 1024) { supLo[w] = st[w]; supHi[w] = st[94 + w]; }
  if (tid == 0) countS = (int)st[188];
  __syncthreads();
  // reconstruct sup words >= CMAX from kept rows of chunks < CMAX
  for (int c = 0; c < CMAX; ++c) {
    uint64_t kw = keep[b * NW + c];
    if (!kw) continue;  // uniform (all threads read same global)
    int ibase = c * 64;
    const int WREST = NW - CMAX;  // 62
    for (int t = tid; t < 64 * WREST; t += 1024) {
      int j = t / WREST;
      int w = CMAX + (t % WREST);
      if ((kw >> j) & 1ull) {
        uint64_t row = Mb[(size_t)(ibase + j) * NW + w];
        unsigned int lo = (unsigned int)row;
        unsigned int hi = (unsigned int)(row >> 32);
        if (lo) atomicOr(&supLo[w], lo);
        if (hi) atomicOr(&supHi[w], hi);
      }
    }
  }
  __syncthreads();
  for (int c = CMAX; c < NW; ++c) {
    nms_chunk(Mb, sscore, keep, b, c, tid, NW, supLo, supHi, klist, &knS, &countS, nullptr);
    if (countS >= 300) break;
  }
  __threadfence();  // keep[] writes visible to part 2 reads
  __syncthreads();

  // ---- part 2: emit ----
  for (int i = tid; i < 1200; i += 1024) out[b * 1200 + i] = 0.f;
  if (tid < 300) {
    out[2400 + b * 300 + tid] = 0.f;
    out[3000 + b * 300 + tid] = 0.f;
  }
  uint64_t w = 0;
  if (tid < NW) {
    uint64_t kw = keep[b * NW + tid];
    while (kw) {
      int j = __ffsll((long long)kw) - 1;
      kw &= kw - 1;
      if (sscore[(size_t)b * NPRE + tid * 64 + j] >= 0.f) w |= (1ull << j);
    }
    fw[tid] = w;
  }
  if (tid < 128) cnt[tid] = (tid < NW) ? __popcll(w) : 0;
  __syncthreads();
  for (int off = 1; off < 128; off <<= 1) {
    int v = 0, u = 0;
    if (tid < 128) {
      v = cnt[tid];
      u = (tid >= off) ? cnt[tid - off] : 0;
    }
    __syncthreads();
    if (tid < 128) cnt[tid] = v + u;
    __syncthreads();
  }
  if (tid < NW) {
    int base = cnt[tid] - __popcll(fw[tid]);
    uint64_t ww = fw[tid];
    while (ww) {
      int j = __ffsll((long long)ww) - 1;
      ww &= ww - 1;
      if (base < 300) {
        int p = tid * 64 + j;
        float4 bx = sbox[(size_t)b * NPRE + p];
        float* ob = out + b * 1200 + base * 4;
        ob[0] = bx.x; ob[1] = bx.y; ob[2] = bx.z; ob[3] = bx.w;
        out[2400 + b * 300 + base] = sscore[(size_t)b * NPRE + p];
        out[3000 + b * 300 + base] = 1.0f;
      }
      ++base;
    }
  }
}

// ---------------- launch ----------------
extern "C" void kernel_launch(void* const* d_in, const int* in_sizes, int n_in,
                              void* d_out, int out_size, void* d_ws, size_t ws_size,
                              hipStream_t stream) {
  const float* x       = (const float*)d_in[0];
  const float* conv1_w = (const float*)d_in[1];
  const float* conv1_b = (const float*)d_in[2];
  const float* obj_w   = (const float*)d_in[3];
  const float* obj_b   = (const float*)d_in[4];
  const float* loc_w   = (const float*)d_in[5];
  const float* loc_b   = (const float*)d_in[6];
  const float* anch    = (const float*)d_in[7];
  const int*   img_h   = (const int*)d_in[8];
  const int*   img_w   = (const int*)d_in[9];

  char* base = (char*)d_ws;
  // split8: wt(4.72M) + 8 partials (81.92M) + tail(7.4M) = 93.32 MB
  // split4: wt(4.72M) + 4 partials (40.96M) + tail(7.4M) = 52.36 MB
  const size_t NEED8 = 93319424;
  const size_t NEED4 = 52359424;
  int nsplit = (ws_size >= NEED8) ? 8 : (ws_size >= NEED4) ? 4 : 0;

  float* wt = (float*)(base + 0);  // 4,718,592
  float* h;
  uint64_t* M;
  float* scores;
  float4* boxes;
  float* sscore;
  float4* sbox;
  uint64_t* keep;
  float* xp;
  unsigned int* state;
  float* wt54b;

  size_t off = 4718592;
  h = (float*)(base + off);
  M = (uint64_t*)(base + off);  // aliases h region (9,024,000 B fits all tiers)
  off += (nsplit == 8) ? 81920000 : (nsplit == 4) ? 40960000 : 10240000;
  scores = (float*)(base + off); off += 180000;
  boxes  = (float4*)(base + off); off += 720000;
  sscore = (float*)(base + off); off += 48000;
  sbox   = (float4*)(base + off);
  wt54b  = (float*)sbox;  // aliases sbox: prep writes, heads reads, topk ph7 overwrites after
  off += 192000;
  keep   = (uint64_t*)(base + off); off += 1504;
  xp     = (float*)(base + off); off += 5537792;
  state  = (unsigned int*)(base + off);

  hipLaunchKernelGGL(prep, dim3(2612), dim3(256), 0, stream,
                     conv1_w, wt, x, xp, obj_w, loc_w, wt54b);
  if (nsplit == 8) {
    // split-K=8: y = oc_tile(0..3) | kh(0..7)<<2 -> 1280 blocks = 5 blocks/CU
    hipLaunchKernelGGL((conv1_gemm_split<8>), dim3(20, 32, 2), dim3(256), 0, stream,
                       xp, wt, h);
    hipLaunchKernelGGL((heads_t<8>), dim3(1250), dim3(64), 0, stream, h, conv1_b, wt54b,
                       obj_b, loc_b, anch, img_h, img_w, scores, boxes);
  } else if (nsplit == 4) {
    hipLaunchKernelGGL((conv1_gemm_split<4>), dim3(20, 16, 2), dim3(256), 0, stream,
                       xp, wt, h);
    hipLaunchKernelGGL((heads_t<4>), dim3(1250), dim3(64), 0, stream, h, conv1_b, wt54b,
                       obj_b, loc_b, anch, img_h, img_w, scores, boxes);
  } else {
    hipLaunchKernelGGL(conv1_gemm_mono, dim3(40, 8, 2), dim3(256), 0, stream, xp, wt,
                       conv1_b, h);
    hipLaunchKernelGGL((heads_t<0>), dim3(1250), dim3(64), 0, stream, h, conv1_b, wt54b,
                       obj_b, loc_b, anch, img_h, img_w, scores, boxes);
  }
  // common path: sort only top-2048 (all NMS consumes within CMAX budget)
  hipLaunchKernelGGL((topk_sort_t<KFAST, 32, 2048, false>), dim3(2), dim3(1024), 0, stream,
                     scores, boxes, sscore, sbox, state);
  hipLaunchKernelGGL(iou_mat, dim3(CMAX, CMAX / 4, 2), dim3(256), 0, stream, sbox, M);
  hipLaunchKernelGGL(nms_scan, dim3(2), dim3(1024), 0, stream, M, sscore, keep, state,
                     sbox, (float*)d_out);
  // fallback chain (gated on !done): full 6000 sort -> remaining IoU -> rest-scan+emit
  hipLaunchKernelGGL((topk_sort_t<NPRE, 94, 6144, true>), dim3(2), dim3(1024), 0, stream,
                     scores, boxes, sscore, sbox, state);
  hipLaunchKernelGGL(iou_rest, dim3(NW, 6, 2), dim3(256), 0, stream, sbox, M, state);
  hipLaunchKernelGGL(nms_finish, dim3(2), dim3(1024), 0, stream, M, sscore, keep, state,
                     sbox, (float*)d_out);
}

// Round 12
// 352.312 us; speedup vs baseline: 1.0943x; 1.0301x over previous
//
#include <hip/hip_runtime.h>
#include <stdint.h>

// ---------------- constants ----------------
#define NPOS 2500      // 50*50
#define NANCH 22500    // NPOS*9
#define NPRE 6000
#define NW 94          // ceil(6000/64)
#define XPAD 2704      // 52*52 padded plane
#define CMAX 32        // proven NMS chunk budget (2048 candidates)
#define KFAST 2048     // common-path sort depth (= CMAX*64)
#define HPART 2560000  // floats per split-K partial (2*2500*512)

// async global->LDS DMA (gfx950). dst is wave-uniform base + lane*size.
__device__ __forceinline__ void gl_lds4(const float* g, float* l) {
  __builtin_amdgcn_global_load_lds((const __attribute__((address_space(1))) void*)g,
                                   (__attribute__((address_space(3))) void*)l, 4, 0, 0);
}
__device__ __forceinline__ void gl_lds16(const float* g, float* l) {
  __builtin_amdgcn_global_load_lds((const __attribute__((address_space(1))) void*)g,
                                   (__attribute__((address_space(3))) void*)l, 16, 0, 0);
}

// ---------------- fused prep: weight transpose + x pad(f4) + head-weight transpose ----------------
__global__ __launch_bounds__(256) void prep(const float* __restrict__ w,
                                            float* __restrict__ wt,
                                            const float* __restrict__ x,
                                            float* __restrict__ xp,
                                            const float* __restrict__ objw,
                                            const float* __restrict__ locw,
                                            float* __restrict__ wt54b) {
  __shared__ float tile[32][33];
  int bid = blockIdx.x;
  int tid = threadIdx.x;
  if (bid < 1152) {
    // ---- role A: conv weight transpose ----
    int k0 = (bid % 72) * 32;   // k' = ic*9 + tap
    int o0 = (bid / 72) * 32;
    int tx = tid & 31;
    int ty = tid >> 5;  // 0..7
#pragma unroll
    for (int i = 0; i < 4; ++i) {
      int oc = o0 + ty + i * 8;
      int kp = k0 + tx;
      tile[ty + i * 8][tx] = w[(size_t)oc * 2304 + kp];
    }
    __syncthreads();
#pragma unroll
    for (int i = 0; i < 4; ++i) {
      int kp = k0 + ty + i * 8;
      int ic = kp / 9, tap = kp % 9;
      wt[((size_t)tap * 256 + ic) * 512 + (o0 + tx)] = tile[tx][ty + i * 8];
    }
  } else if (bid < 2504) {
    // ---- role B: zero-pad x, one float4 per thread (2704 = 676 f4/plane) ----
    int t = (bid - 1152) * 256 + tid;   // float4 index
    if (t < 2 * 256 * 676) {
      int c = t / 676;        // b*256 + ic
      int q = t % 676;
      int r0 = q * 4;
      float v[4];
#pragma unroll
      for (int k = 0; k < 4; ++k) {
        int r = r0 + k;
        int yy = r / 52, xx = r % 52;
        v[k] = (yy >= 1 && yy <= 50 && xx >= 1 && xx <= 50)
                   ? x[(size_t)c * NPOS + (yy - 1) * 50 + (xx - 1)]
                   : 0.f;
      }
      ((float4*)xp)[t] = make_float4(v[0], v[1], v[2], v[3]);
    }
  } else {
    // ---- role C: head-weight transpose to [k/4][oc][4] ----
    int t = (bid - 2504) * 256 + tid;
    if (t < 54 * 512) {
      int oc = t / 512, k = t % 512;
      float v = (oc < 18) ? objw[(size_t)oc * 512 + k] : locw[(size_t)(oc - 18) * 512 + k];
      wt54b[((size_t)(k >> 2) * 64 + oc) * 4 + (k & 3)] = v;
    }
  }
}

// ---------------- conv1 split-K=N (R26: NSPLIT=8 = 150us, FROZEN) ----------------
template <int NSPLIT>
__global__ __launch_bounds__(256) void conv1_gemm_split(const float* __restrict__ xp,
                                                        const float* __restrict__ wt,
                                                        float* __restrict__ hpart) {
  constexpr int ICC_PER = 8 / NSPLIT;  // 32-ic chunks per block per tap
  __shared__ __align__(16) float As[32][128];
  __shared__ __align__(16) float Bs[32][128];
  int b = blockIdx.z;
  int m0 = blockIdx.x * 128;
  int oc0 = (blockIdx.y & 3) * 128;
  int kh = blockIdx.y >> 2;        // 0..NSPLIT-1
  int tid = threadIdx.x;
  int lane = tid & 63;
  int wv = tid >> 6;   // wave 0..3
  int tm = tid >> 4;   // 0..15
  int tn = tid & 15;   // 0..15
  float acc[8][8] = {};

  int p0r = m0 + lane;
  int p0c = p0r < NPOS ? p0r : (NPOS - 1);
  int p1r = m0 + 64 + lane;
  int p1c = p1r < NPOS ? p1r : (NPOS - 1);
  const float* gA0 = xp + (size_t)b * 256 * XPAD + (p0c / 50) * 52 + (p0c % 50) + 53;
  const float* gA1 = xp + (size_t)b * 256 * XPAD + (p1c / 50) * 52 + (p1c % 50) + 53;
  int brow = lane >> 5, bcol4 = (lane & 31) * 4;

  for (int tap = 0; tap < 9; ++tap) {
    int ky = tap / 3 - 1, kx = tap % 3 - 1;
    int koff = ky * 52 + kx;
#pragma unroll
    for (int ii = 0; ii < ICC_PER; ++ii) {
      int ic0 = (kh * ICC_PER + ii) * 32;
      __syncthreads();  // LDS consumed by previous chunk's compute
#pragma unroll
      for (int j = 0; j < 8; ++j) {
        int kk = wv * 8 + j;
        gl_lds4(gA0 + (size_t)(ic0 + kk) * XPAD + koff, &As[kk][0]);
        gl_lds4(gA1 + (size_t)(ic0 + kk) * XPAD + koff, &As[kk][64]);
      }
#pragma unroll
      for (int q = 0; q < 4; ++q) {
        int r0 = wv * 8 + q * 2;  // instr covers rows r0, r0+1 (1KB)
        gl_lds16(wt + ((size_t)tap * 256 + ic0 + r0 + brow) * 512 + oc0 + bcol4,
                 &Bs[r0][0]);
      }
      __syncthreads();  // drains vmcnt -> DMAs complete
#pragma unroll 4
      for (int kk = 0; kk < 32; ++kk) {
        float4 a0 = *(const float4*)&As[kk][tm * 4];
        float4 a1 = *(const float4*)&As[kk][64 + tm * 4];
        float4 b0 = *(const float4*)&Bs[kk][tn * 4];
        float4 b1 = *(const float4*)&Bs[kk][64 + tn * 4];
        float am[8] = {a0.x, a0.y, a0.z, a0.w, a1.x, a1.y, a1.z, a1.w};
        float bn[8] = {b0.x, b0.y, b0.z, b0.w, b1.x, b1.y, b1.z, b1.w};
#pragma unroll
        for (int i = 0; i < 8; ++i)
#pragma unroll
          for (int j = 0; j < 8; ++j) acc[i][j] = fmaf(am[i], bn[j], acc[i][j]);
      }
    }
  }
  float* hp = hpart + (size_t)kh * HPART;
#pragma unroll
  for (int i = 0; i < 8; ++i) {
    int row = m0 + ((i & 4) ? 64 : 0) + tm * 4 + (i & 3);
    if (row < NPOS) {
      float* hrow = &hp[((size_t)b * NPOS + row) * 512 + oc0];
      float4 v0 = make_float4(acc[i][0], acc[i][1], acc[i][2], acc[i][3]);
      float4 v1 = make_float4(acc[i][4], acc[i][5], acc[i][6], acc[i][7]);
      *(float4*)&hrow[tn * 4] = v0;
      *(float4*)&hrow[64 + tn * 4] = v1;
    }
  }
}

// ---------------- conv1 mono (EXACT R7, known-good 202us): ws fallback ----------------
__global__ __launch_bounds__(256) void conv1_gemm_mono(const float* __restrict__ xp,
                                                       const float* __restrict__ wt,
                                                       const float* __restrict__ bias,
                                                       float* __restrict__ h) {
  __shared__ __align__(16) float As[32][64];
  __shared__ __align__(16) float Bs[32][64];
  int b = blockIdx.z;
  int m0 = blockIdx.x * 64;
  int oc0 = blockIdx.y * 64;
  int tid = threadIdx.x;
  int lane = tid & 63;
  int wv = tid >> 6;
  int tn = tid & 15, tm = tid >> 4;
  float acc[4][4] = {};

  int p = m0 + lane;
  int pc = p < NPOS ? p : (NPOS - 1);
  int py = pc / 50, px = pc % 50;
  const float* gA0 = xp + (size_t)b * 256 * XPAD + py * 52 + px + 53;
  int brow = lane >> 4, bcol4 = (lane & 15) * 4;

  for (int tap = 0; tap < 9; ++tap) {
    int ky = tap / 3 - 1, kx = tap % 3 - 1;
    int koff = ky * 52 + kx;
    for (int icc = 0; icc < 8; ++icc) {
      int ic0 = icc * 32;
      __syncthreads();
#pragma unroll
      for (int j = 0; j < 8; ++j) {
        int kk = wv * 8 + j;
        gl_lds4(gA0 + (size_t)(ic0 + kk) * XPAD + koff, &As[kk][0]);
      }
#pragma unroll
      for (int q = 0; q < 2; ++q) {
        int r0 = wv * 8 + q * 4;
        gl_lds16(wt + ((size_t)tap * 256 + ic0 + r0 + brow) * 512 + oc0 + bcol4,
                 &Bs[r0][0]);
      }
      __syncthreads();
#pragma unroll
      for (int kk = 0; kk < 32; ++kk) {
        float4 av = *(const float4*)&As[kk][tm * 4];
        float4 bv = *(const float4*)&Bs[kk][tn * 4];
        float am[4] = {av.x, av.y, av.z, av.w};
        float bn[4] = {bv.x, bv.y, bv.z, bv.w};
#pragma unroll
        for (int i = 0; i < 4; ++i)
#pragma unroll
          for (int j = 0; j < 4; ++j) acc[i][j] = fmaf(am[i], bn[j], acc[i][j]);
      }
    }
  }
#pragma unroll
  for (int i = 0; i < 4; ++i) {
    int pp = m0 + tm * 4 + i;
    if (pp < NPOS) {
      float4 v;
      float* vp = (float*)&v;
#pragma unroll
      for (int j = 0; j < 4; ++j) {
        int oc = oc0 + tn * 4 + j;
        vp[j] = fmaxf(acc[i][j] + bias[oc], 0.f);
      }
      *(float4*)&h[((size_t)b * NPOS + pp) * 512 + oc0 + tn * 4] = v;
    }
  }
}

// ---------------- heads: NSPLIT=0 -> mono load; else sum NSPLIT partials + bias + relu ----------------
template <int NSPLIT>
__global__ __launch_bounds__(64) void heads_t(const float* __restrict__ h,
                                              const float* __restrict__ convb,
                                              const float* __restrict__ wt54b,
                                              const float* __restrict__ objb,
                                              const float* __restrict__ locb,
                                              const float* __restrict__ anch,
                                              const int* __restrict__ imgh,
                                              const int* __restrict__ imgw,
                                              float* __restrict__ scores,
                                              float4* __restrict__ boxes) {
  __shared__ float hv[4 * 512];
  __shared__ float outs[4][64];
  int blk = blockIdx.x;             // 0..1249
  int b = blk / 625;
  int p0 = (blk % 625) * 4;         // 4 consecutive positions
  int lane = threadIdx.x;
  const float4* h4 = (const float4*)h;
  size_t base = ((size_t)b * NPOS + p0) * 128;  // float4 units
  float4* hv4 = (float4*)hv;
  if (NSPLIT == 0) {
#pragma unroll
    for (int q = 0; q < 8; ++q) {
      int f = lane + 64 * q;
      hv4[f] = h4[base + f];
    }
  } else {
    const float4* cb4 = (const float4*)convb;
#pragma unroll
    for (int q = 0; q < 8; ++q) {
      int f = lane + 64 * q;
      float4 s = h4[base + f];  // partial 0
#pragma unroll
      for (int k = 1; k < NSPLIT; ++k) {
        float4 sk = h4[(size_t)k * (HPART / 4) + base + f];
        s.x += sk.x; s.y += sk.y; s.z += sk.z; s.w += sk.w;
      }
      float4 bb = cb4[f & 127];
      float4 r;
      r.x = fmaxf(s.x + bb.x, 0.f);
      r.y = fmaxf(s.y + bb.y, 0.f);
      r.z = fmaxf(s.z + bb.z, 0.f);
      r.w = fmaxf(s.w + bb.w, 0.f);
      hv4[f] = r;
    }
  }
  __syncthreads();
  if (lane < 54) {
    float bias0 = (lane < 18) ? objb[lane] : locb[lane - 18];
    float a0 = bias0, a1 = bias0, a2 = bias0, a3 = bias0;
    const float4* w4 = (const float4*)wt54b;
#pragma unroll 4
    for (int k = 0; k < 128; ++k) {
      float4 wv = w4[k * 64 + lane];
      float4 h0 = hv4[k], h1 = hv4[128 + k], h2 = hv4[256 + k], h3 = hv4[384 + k];
      a0 = fmaf(wv.x, h0.x, a0); a0 = fmaf(wv.y, h0.y, a0);
      a0 = fmaf(wv.z, h0.z, a0); a0 = fmaf(wv.w, h0.w, a0);
      a1 = fmaf(wv.x, h1.x, a1); a1 = fmaf(wv.y, h1.y, a1);
      a1 = fmaf(wv.z, h1.z, a1); a1 = fmaf(wv.w, h1.w, a1);
      a2 = fmaf(wv.x, h2.x, a2); a2 = fmaf(wv.y, h2.y, a2);
      a2 = fmaf(wv.z, h2.z, a2); a2 = fmaf(wv.w, h2.w, a2);
      a3 = fmaf(wv.x, h3.x, a3); a3 = fmaf(wv.y, h3.y, a3);
      a3 = fmaf(wv.z, h3.z, a3); a3 = fmaf(wv.w, h3.w, a3);
    }
    outs[0][lane] = a0; outs[1][lane] = a1; outs[2][lane] = a2; outs[3][lane] = a3;
  }
  __syncthreads();
  if (lane < 36) {
    int pi = lane / 9, a = lane % 9;
    int p = p0 + pi;
    float l0 = outs[pi][2 * a], l1 = outs[pi][2 * a + 1];
    float mx = fmaxf(l0, l1);
    float e0 = expf(l0 - mx);
    float e1 = expf(l1 - mx);
    float s = e1 / (e0 + e1);
    float d0 = outs[pi][18 + 4 * a + 0];
    float d1 = outs[pi][18 + 4 * a + 1];
    float d2 = outs[pi][18 + 4 * a + 2];
    float d3 = outs[pi][18 + 4 * a + 3];
    int ai = p * 9 + a;
    float4 A = ((const float4*)anch)[ai];
    float aw = A.z - A.x, ah = A.w - A.y;
    float acx = A.x + 0.5f * aw, acy = A.y + 0.5f * ah;
    float cx = acx + d0 * aw, cy = acy + d1 * ah;
    float w = aw * expf(d2), hh = ah * expf(d3);
    float W = (float)imgw[0], H = (float)imgh[0];
    float x1 = fminf(fmaxf(cx - 0.5f * w, 0.f), W);
    float y1 = fminf(fmaxf(cy - 0.5f * hh, 0.f), H);
    float x2 = fminf(fmaxf(cx + 0.5f * w, 0.f), W);
    float y2 = fminf(fmaxf(cy + 0.5f * hh, 0.f), H);
    bool valid = (x2 - x1 >= 16.f) && (y2 - y1 >= 16.f);
    scores[(size_t)b * NANCH + ai] = valid ? s : -1.f;
    boxes[(size_t)b * NANCH + ai] = make_float4(x1, y1, x2, y2);
  }
}

// ---------------- top-K select + stable radix sort (one block per batch) ----------------
// R27: all 22500 scores staged in LDS (scL, 90KB); phases 1/2/3/5 scans and
// radix key gathers hit LDS (~6-12cyc) instead of global (200-900cyc). With
// pools: 120KB (KFAST) / 143KB (full) < 160KB LDS. Values copied bitwise.
__device__ inline unsigned int mono_of(float f) {
  unsigned int u = __float_as_uint(f);
  return (u & 0x80000000u) ? ~u : (u | 0x80000000u);
}

// strict suffix sum over 1024 per-thread values (2 barriers)
__device__ __forceinline__ unsigned int suffix_strict(unsigned int v,
                                                      unsigned int* partw,
                                                      int tid, int lane, int wv) {
  unsigned int inc = v;
#pragma unroll
  for (int d = 1; d < 64; d <<= 1) {
    unsigned int u = __shfl_down(inc, d, 64);
    if (lane + d < 64) inc += u;
  }
  if (lane == 0) partw[wv] = inc;  // wave total
  __syncthreads();
  if (tid < 16) {
    unsigned int tot = partw[tid];
    unsigned int inc2 = tot;
#pragma unroll
    for (int d = 1; d < 16; d <<= 1) {
      unsigned int u = __shfl_down(inc2, d, 64);
      if (tid + d < 16) inc2 += u;
    }
    partw[tid] = inc2 - tot;  // strict suffix of later waves
  }
  __syncthreads();
  return partw[wv] + (inc - v);
}

template <int KSEL, int SLOTK, int TBLSZ, bool GATED>
__global__ __launch_bounds__(1024) void topk_sort_t(const float* __restrict__ scores,
                                                    const float4* __restrict__ boxes,
                                                    float* __restrict__ sscore,
                                                    float4* __restrict__ sbox,
                                                    const unsigned int* __restrict__ state) {
  int b = blockIdx.x;
  if (GATED && state[b * 192 + 189]) return;  // common path: NMS already done
  const float* sc = scores + (size_t)b * NANCH;
  __shared__ float scL[NANCH];              // 90KB score stage
  __shared__ unsigned int hist[4096];
  __shared__ unsigned int part[1024];
  __shared__ unsigned short pidA[SLOTK * 64];
  __shared__ unsigned short pidB[SLOTK * 64];
  __shared__ unsigned short table[TBLSZ];   // 64 digits x SLOTK slots (padded)
  __shared__ int res[8];
  int tid = threadIdx.x;
  int lane = tid & 63;
  int wv = tid >> 6;

  // ---------- phase 0: stage scores to LDS (coalesced, once) ----------
  for (int i = tid; i < NANCH; i += 1024) scL[i] = sc[i];
  // ---------- phase 1: top-12-bit histogram ----------
  for (int i = tid; i < 4096; i += 1024) hist[i] = 0;
  __syncthreads();
  for (int i = tid; i < NANCH; i += 1024) atomicAdd(&hist[mono_of(scL[i]) >> 20], 1u);
  __syncthreads();
  {
    unsigned int h0 = hist[4 * tid], h1 = hist[4 * tid + 1];
    unsigned int h2 = hist[4 * tid + 2], h3 = hist[4 * tid + 3];
    unsigned int c = suffix_strict(h0 + h1 + h2 + h3, part, tid, lane, wv);
    const unsigned int need = KSEL;
    if (c < need && c + h3 >= need) { res[0] = 4 * tid + 3; res[1] = (int)c; }
    c += h3;
    if (c < need && c + h2 >= need) { res[0] = 4 * tid + 2; res[1] = (int)c; }
    c += h2;
    if (c < need && c + h1 >= need) { res[0] = 4 * tid + 1; res[1] = (int)c; }
    c += h1;
    if (c < need && c + h0 >= need) { res[0] = 4 * tid + 0; res[1] = (int)c; }
  }
  __syncthreads();
  int t1 = res[0], a1 = res[1];
  __syncthreads();

  // ---------- phase 2: middle-12 bits within bin t1 ----------
  for (int i = tid; i < 4096; i += 1024) hist[i] = 0;
  __syncthreads();
  for (int i = tid; i < NANCH; i += 1024) {
    unsigned int m = mono_of(scL[i]);
    if ((int)(m >> 20) == t1) atomicAdd(&hist[(m >> 8) & 0xFFF], 1u);
  }
  __syncthreads();
  {
    unsigned int h0 = hist[4 * tid], h1 = hist[4 * tid + 1];
    unsigned int h2 = hist[4 * tid + 2], h3 = hist[4 * tid + 3];
    unsigned int c = suffix_strict(h0 + h1 + h2 + h3, part, tid, lane, wv);
    const unsigned int need = (unsigned)(KSEL - a1);
    if (c < need && c + h3 >= need) { res[2] = 4 * tid + 3; res[3] = (int)c; }
    c += h3;
    if (c < need && c + h2 >= need) { res[2] = 4 * tid + 2; res[3] = (int)c; }
    c += h2;
    if (c < need && c + h1 >= need) { res[2] = 4 * tid + 1; res[3] = (int)c; }
    c += h1;
    if (c < need && c + h0 >= need) { res[2] = 4 * tid + 0; res[3] = (int)c; }
  }
  __syncthreads();
  int t2 = res[2], a2 = res[3];
  __syncthreads();

  // ---------- phase 3: low-8 bits within (t1,t2) ----------
  for (int i = tid; i < 256; i += 1024) hist[i] = 0;
  __syncthreads();
  unsigned int top24 = ((unsigned int)t1 << 12) | (unsigned int)t2;
  for (int i = tid; i < NANCH; i += 1024) {
    unsigned int m = mono_of(scL[i]);
    if ((m >> 8) == top24) atomicAdd(&hist[m & 0xFF], 1u);
  }
  __syncthreads();
  {
    unsigned int hb = (tid < 256) ? hist[tid] : 0;
    unsigned int c = suffix_strict(hb, part, tid, lane, wv);
    if (tid < 256) {
      const unsigned int need = (unsigned)(KSEL - a1 - a2);
      if (c < need && c + hb >= need) {
        res[4] = tid;
        res[6] = (int)(need - c);                         // ties_needed
        res[7] = (hb == need - c) ? NANCH : -1;           // idx_cut or TBD
      }
    }
  }
  __syncthreads();
  int t3 = res[4];
  unsigned int T = (top24 << 8) | (unsigned int)t3;
  int ties_needed = res[6];
  int idx_cut = res[7];
  __syncthreads();

  // ---------- phase 4 (rare): tie resolution by smallest index ----------
  if (idx_cut < 0) {
    for (int i = tid; i < 704; i += 1024) hist[i] = 0;
    __syncthreads();
    for (int i = tid; i < NANCH; i += 1024)
      if (mono_of(scL[i]) == T) atomicAdd(&hist[i >> 5], 1u);
    __syncthreads();
    if (tid == 0) {
      int c = 0, cut = NANCH;
      for (int bin = 0; bin < 704; ++bin) {
        int hc = (int)hist[bin];
        if (c + hc >= ties_needed) {
          int c2 = c;
          for (int idx = bin * 32; idx < bin * 32 + 32; ++idx) {
            if (idx < NANCH && mono_of(scL[idx]) == T) {
              ++c2;
              if (c2 == ties_needed) { cut = idx; break; }
            }
          }
          break;
        }
        c += hc;
      }
      res[7] = cut;
    }
    __syncthreads();
    idx_cut = res[7];
    __syncthreads();
  }

  // ---------- phase 5: deterministic idx-order compact (blocked ranges + scan) ----------
  int base0 = tid * 22;  // 1024*22 = 22528 >= NANCH
  unsigned int selm = 0;
  int cnt = 0;
  for (int k = 0; k < 22; ++k) {
    int i = base0 + k;
    if (i < NANCH) {
      unsigned int m = mono_of(scL[i]);
      if (m > T || (m == T && i <= idx_cut)) { selm |= 1u << k; ++cnt; }
    }
  }
  {
    int inc = cnt;
#pragma unroll
    for (int d = 1; d < 64; d <<= 1) {
      int u = __shfl_up(inc, d, 64);
      if (lane >= d) inc += u;
    }
    if (lane == 63) part[wv] = (unsigned int)inc;
    __syncthreads();
    if (tid < 16) {
      int v = (int)part[tid];
      int inc2 = v;
#pragma unroll
      for (int d = 1; d < 16; d <<= 1) {
        int u = __shfl_up(inc2, d, 16);
        if (tid >= d) inc2 += u;
      }
      part[tid] = (unsigned int)(inc2 - v);  // exclusive wave base
    }
    __syncthreads();
    int pos = (int)part[wv] + (inc - cnt);
    for (int k = 0; k < 22; ++k)
      if ((selm >> k) & 1u) pidA[pos++] = (unsigned short)(base0 + k);
  }
  __syncthreads();

  // ---------- phase 6: 6-pass 6-bit stable LSD radix, key = ~mono (asc) ----------
  unsigned short* src = pidA;
  unsigned short* dst = pidB;
  constexpr int KITER = (SLOTK + 15) / 16;
  constexpr int VPT = TBLSZ / 1024;
  for (int pass = 0; pass < 6; ++pass) {
    int shift = pass * 6;
    for (int i = tid; i < TBLSZ; i += 1024) table[i] = 0;
    __syncthreads();
    int dig[KITER], irk[KITER], pidr[KITER];
#pragma unroll
    for (int k = 0; k < KITER; ++k) {
      dig[k] = 0; irk[k] = 0; pidr[k] = 0;
      int s = wv + 16 * k;          // wave-uniform
      if (s < SLOTK) {
        int e = s * 64 + lane;
        bool act = e < KSEL;
        int pid = act ? (int)src[e] : 0;
        unsigned int key = act ? ~mono_of(scL[pid]) : 0u;
        int d = (int)((key >> shift) & 63u);
        uint64_t peers = __ballot(act);
#pragma unroll
        for (int bb = 0; bb < 6; ++bb) {
          uint64_t bl = __ballot(((d >> bb) & 1) != 0);
          peers &= ((d >> bb) & 1) ? bl : ~bl;
        }
        if (act) {
          dig[k] = d;
          pidr[k] = pid;
          irk[k] = (int)__popcll(peers & ((1ull << lane) - 1ull));
          int leader = __ffsll((long long)peers) - 1;
          if (lane == leader)
            table[d * SLOTK + s] = (unsigned short)__popcll(peers);
        }
      }
    }
    __syncthreads();
    // exclusive scan over table[0..TBLSZ) (digit-major, slot-minor)
    {
      int tb = tid * VPT;
      int v[VPT];
      int lsum = 0;
#pragma unroll
      for (int q = 0; q < VPT; ++q) { v[q] = table[tb + q]; lsum += v[q]; }
      int inc = lsum;
#pragma unroll
      for (int d = 1; d < 64; d <<= 1) {
        int u = __shfl_up(inc, d, 64);
        if (lane >= d) inc += u;
      }
      if (lane == 63) part[wv] = (unsigned int)inc;
      __syncthreads();
      if (tid < 16) {
        int vv = (int)part[tid];
        int inc2 = vv;
#pragma unroll
        for (int d = 1; d < 16; d <<= 1) {
          int u = __shfl_up(inc2, d, 16);
          if (tid >= d) inc2 += u;
        }
        part[tid] = (unsigned int)(inc2 - vv);
      }
      __syncthreads();
      int run = (int)part[wv] + (inc - lsum);
#pragma unroll
      for (int q = 0; q < VPT; ++q) { table[tb + q] = (unsigned short)run; run += v[q]; }
    }
    __syncthreads();
    // scatter (stable): pos = base(digit,slot) + intra-slot rank
#pragma unroll
    for (int k = 0; k < KITER; ++k) {
      int s = wv + 16 * k;
      if (s < SLOTK) {
        int e = s * 64 + lane;
        if (e < KSEL) {
          int pos = (int)table[dig[k] * SLOTK + s] + irk[k];
          dst[pos] = (unsigned short)pidr[k];
        }
      }
    }
    __syncthreads();
    unsigned short* tmp = src; src = dst; dst = tmp;
  }
  // 6 passes -> result back in pidA (== src)

  // ---------- phase 7: gather sorted scores/boxes ----------
  for (int r = tid; r < KSEL; r += 1024) {
    int idx = (int)src[r];
    sscore[(size_t)b * NPRE + r] = scL[idx];
    sbox[(size_t)b * NPRE + r] = boxes[(size_t)b * NANCH + idx];
  }
}

// ---------------- IoU suppression bitmask ----------------
__device__ __forceinline__ void iou_compute(const float4* bi, const float4* bj,
                                            uint64_t* __restrict__ M,
                                            int b, int it, int jt, int tid) {
  int li = tid & 63, wq = tid >> 6;
  int i = it * 64 + li;
  int w = jt * 4 + wq;
  if (i < NPRE && w < NW) {
    float4 A = bi[li];
    float areaA = (A.z - A.x) * (A.w - A.y);
    uint64_t bits = 0;
#pragma unroll 8
    for (int jj = 0; jj < 64; ++jj) {
      int j = w * 64 + jj;
      float4 Bx = bj[wq * 64 + jj];
      float ix1 = fmaxf(A.x, Bx.x), iy1 = fmaxf(A.y, Bx.y);
      float ix2 = fminf(A.z, Bx.z), iy2 = fminf(A.w, Bx.w);
      float inter = fmaxf(ix2 - ix1, 0.f) * fmaxf(iy2 - iy1, 0.f);
      float areaB = (Bx.z - Bx.x) * (Bx.w - Bx.y);
      float iou = inter / (areaA + areaB - inter);
      if ((j > i) && (j < NPRE) && (iou > 0.7f)) bits |= (1ull << jj);
    }
    M[((size_t)b * NPRE + i) * NW + w] = bits;
  }
}

// common path: rows < CMAX*64 AND columns w < CMAX
__global__ __launch_bounds__(256) void iou_mat(const float4* __restrict__ sbox,
                                               uint64_t* __restrict__ M) {
  __shared__ float4 bi[64];
  __shared__ float4 bj[256];
  int b = blockIdx.z, it = blockIdx.x, jt = blockIdx.y;
  int tid = threadIdx.x;
  if (tid < 64) {
    int i = it * 64 + tid;
    bi[tid] = (i < NPRE) ? sbox[(size_t)b * NPRE + i] : make_float4(0, 0, 0, 0);
  }
  {
    int j = jt * 256 + tid;
    bj[tid] = (j < NPRE) ? sbox[(size_t)b * NPRE + j] : make_float4(0, 0, 0, 0);
  }
  __syncthreads();
  iou_compute(bi, bj, M, b, it, jt, tid);
}

// fallback complement: each block covers 16 words (4 jt sub-tiles)
__global__ __launch_bounds__(256) void iou_rest(const float4* __restrict__ sbox,
                                                uint64_t* __restrict__ M,
                                                const unsigned int* __restrict__ state) {
  if (state[blockIdx.z * 192 + 189]) return;  // done
  int it = blockIdx.x, jt16 = blockIdx.y, b = blockIdx.z;
  int tid = threadIdx.x;
  __shared__ float4 bi[64];
  __shared__ float4 bj[256];
  if (tid < 64) {
    int i = it * 64 + tid;
    bi[tid] = (i < NPRE) ? sbox[(size_t)b * NPRE + i] : make_float4(0, 0, 0, 0);
  }
#pragma unroll
  for (int q = 0; q < 4; ++q) {
    int jt = jt16 * 4 + q;
    bool skip = (it < CMAX && jt < CMAX / 4);  // covered by iou_mat (block-uniform)
    __syncthreads();  // bi ready (q=0) / previous compute's bj reads done (WAR)
    if (!skip) {
      int j = jt * 256 + tid;
      bj[tid] = (j < NPRE) ? sbox[(size_t)b * NPRE + j] : make_float4(0, 0, 0, 0);
    }
    __syncthreads();
    if (!skip) iou_compute(bi, bj, M, b, it, jt, tid);
  }
}

// ---------------- NMS scan: wave0 serial closure + block-parallel OR + early exit ----------------
__device__ inline uint64_t shfl64(uint64_t v, int src) {
  int lo = __shfl((int)(unsigned int)(v & 0xFFFFFFFFull), src, 64);
  int hi = __shfl((int)(unsigned int)(v >> 32), src, 64);
  return ((uint64_t)(unsigned int)hi << 32) | (unsigned int)lo;
}

// one NMS chunk step; OR restricted to w < wlimit. keptS (LDS) optional.
__device__ __forceinline__ void nms_chunk(const uint64_t* __restrict__ Mb,
                                          const float* __restrict__ sscore,
                                          uint64_t* __restrict__ keep,
                                          int b, int c, int tid, int wlimit,
                                          unsigned int* supLo, unsigned int* supHi,
                                          int* klist, int* knS, int* countS,
                                          uint64_t* keptS) {
  int ibase = c * 64;
  if (tid < 64) {
    int lane = tid;
    if (lane == 0) *knS = 0;
    uint64_t supc = ((uint64_t)supHi[c] << 32) | supLo[c];
    uint64_t validm = (c == NW - 1) ? ((1ull << (NPRE - (NW - 1) * 64)) - 1ull) : ~0ull;
    int pos = ibase + lane;
    uint64_t myrow = (pos < NPRE) ? Mb[(size_t)pos * NW + c] : 0ull;
    bool sval = (pos < NPRE) && (sscore[(size_t)b * NPRE + pos] >= 0.f);
    uint64_t vb = __ballot(sval);
    uint64_t cur = validm & ~supc;
    uint64_t kept = 0;
    while (cur) {
      int i = __ffsll((long long)cur) - 1;
      kept |= (1ull << i);
      cur &= ~(1ull << i);
      uint64_t row = shfl64(myrow, i);
      cur &= ~row;
    }
    if (kept & (1ull << lane)) {
      int pp = atomicAdd(knS, 1);
      klist[pp] = lane;
    }
    if (lane == 0) {
      keep[b * NW + c] = kept;
      if (keptS) keptS[c] = kept;
      *countS += __popcll(kept & vb);
    }
  }
  __syncthreads();  // [A] klist/knS/count visible; sup[c] consumed
  int kn = *knS;
  for (int t = tid; t < kn * 128; t += 1024) {
    int ii = t >> 7, w = t & 127;
    if (w > c && w < wlimit) {
      uint64_t row = Mb[(size_t)(ibase + klist[ii]) * NW + w];
      unsigned int lo = (unsigned int)row;
      unsigned int hi = (unsigned int)(row >> 32);
      if (lo) atomicOr(&supLo[w], lo);
      if (hi) atomicOr(&supHi[w], hi);
    }
  }
  __syncthreads();  // [B] sup updated before next chunk's closure
}

// phase A: chunks 0..CMAX, OR width limited to CMAX. Common path (done):
// emits output directly from LDS keptS; nms_finish then early-outs.
__global__ __launch_bounds__(1024) void nms_scan(const uint64_t* __restrict__ M,
                                                 const float* __restrict__ sscore,
                                                 uint64_t* __restrict__ keep,
                                                 unsigned int* __restrict__ state,
                                                 const float4* __restrict__ sbox,
                                                 float* __restrict__ out) {
  __shared__ unsigned int supLo[NW], supHi[NW];
  __shared__ int klist[64];
  __shared__ int knS;
  __shared__ int countS;
  __shared__ uint64_t keptS[NW];
  __shared__ int cnt[128];
  __shared__ uint64_t fw[NW];
  int b = blockIdx.x;
  int tid = threadIdx.x;
  const uint64_t* Mb = M + (size_t)b * NPRE * NW;

  for (int w = tid; w < NW; w += 1024) {
    supLo[w] = 0;
    supHi[w] = 0;
    keptS[w] = 0;
    keep[b * NW + w] = 0;  // early-exit / fallback leaves untouched chunks zeroed
  }
  if (tid == 0) countS = 0;
  __syncthreads();

  int done = 0;
  for (int c = 0; c < CMAX; ++c) {
    nms_chunk(Mb, sscore, keep, b, c, tid, CMAX, supLo, supHi, klist, &knS, &countS, keptS);
    if (countS >= 300) { done = 1; break; }  // uniform: countS read post-barrier
  }
  __syncthreads();
  unsigned int* st = state + b * 192;
  for (int w = tid; w < NW; w += 1024) { st[w] = supLo[w]; st[94 + w] = supHi[w]; }
  if (tid == 0) { st[188] = (unsigned int)countS; st[189] = (unsigned int)done; }

  if (done) {
    // ---- common-path emit (from LDS keptS) ----
    for (int i = tid; i < 1200; i += 1024) out[b * 1200 + i] = 0.f;
    if (tid < 300) {
      out[2400 + b * 300 + tid] = 0.f;
      out[3000 + b * 300 + tid] = 0.f;
    }
    uint64_t fwv = 0;
    if (tid < NW) {
      uint64_t kw = keptS[tid];
      while (kw) {
        int j = __ffsll((long long)kw) - 1;
        kw &= kw - 1;
        if (sscore[(size_t)b * NPRE + tid * 64 + j] >= 0.f) fwv |= (1ull << j);
      }
      fw[tid] = fwv;
    }
    if (tid < 128) cnt[tid] = (tid < NW) ? __popcll(fwv) : 0;
    __syncthreads();
    for (int off = 1; off < 128; off <<= 1) {
      int v = 0, u = 0;
      if (tid < 128) {
        v = cnt[tid];
        u = (tid >= off) ? cnt[tid - off] : 0;
      }
      __syncthreads();
      if (tid < 128) cnt[tid] = v + u;
      __syncthreads();
    }
    if (tid < NW) {
      int base = cnt[tid] - __popcll(fw[tid]);
      uint64_t ww = fw[tid];
      while (ww) {
        int j = __ffsll((long long)ww) - 1;
        ww &= ww - 1;
        if (base < 300) {
          int p = tid * 64 + j;
          float4 bx = sbox[(size_t)b * NPRE + p];
          float* ob = out + b * 1200 + base * 4;
          ob[0] = bx.x; ob[1] = bx.y; ob[2] = bx.z; ob[3] = bx.w;
          out[2400 + b * 300 + base] = sscore[(size_t)b * NPRE + p];
          out[3000 + b * 300 + base] = 1.0f;
        }
        ++base;
      }
    }
  }
}

// fallback scan + emit. Common path (st[189]==1): return immediately.
__global__ __launch_bounds__(1024) void nms_finish(const uint64_t* __restrict__ M,
                                                   const float* __restrict__ sscore,
                                                   uint64_t* __restrict__ keep,
                                                   const unsigned int* __restrict__ state,
                                                   const float4* __restrict__ sbox,
                                                   float* __restrict__ out) {
  __shared__ unsigned int supLo[NW], supHi[NW];
  __shared__ int klist[64];
  __shared__ int knS;
  __shared__ int countS;
  __shared__ int cnt[128];
  __shared__ uint64_t fw[NW];
  int b = blockIdx.x;
  int tid = threadIdx.x;
  const uint64_t* Mb = M + (size_t)b * NPRE * NW;
  const unsigned int* st = state + b * 192;

  if (st[189]) return;  // common path: nms_scan already emitted

  for (int w = tid; w < NW; w += 1024) { supLo[w] = st[w]; supHi[w] = st[94 + w]; }
  if (tid == 0) countS = (int)st[188];
  __syncthreads();
  // reconstruct sup words >= CMAX from kept rows of chunks < CMAX
  for (int c = 0; c < CMAX; ++c) {
    uint64_t kw = keep[b * NW + c];
    if (!kw) continue;  // uniform (all threads read same global)
    int ibase = c * 64;
    const int WREST = NW - CMAX;  // 62
    for (int t = tid; t < 64 * WREST; t += 1024) {
      int j = t / WREST;
      int w = CMAX + (t % WREST);
      if ((kw >> j) & 1ull) {
        uint64_t row = Mb[(size_t)(ibase + j) * NW + w];
        unsigned int lo = (unsigned int)row;
        unsigned int hi = (unsigned int)(row >> 32);
        if (lo) atomicOr(&supLo[w], lo);
        if (hi) atomicOr(&supHi[w], hi);
      }
    }
  }
  __syncthreads();
  for (int c = CMAX; c < NW; ++c) {
    nms_chunk(Mb, sscore, keep, b, c, tid, NW, supLo, supHi, klist, &knS, &countS, nullptr);
    if (countS >= 300) break;
  }
  __threadfence();  // keep[] writes visible to part 2 reads
  __syncthreads();

  // ---- part 2: emit ----
  for (int i = tid; i < 1200; i += 1024) out[b * 1200 + i] = 0.f;
  if (tid < 300) {
    out[2400 + b * 300 + tid] = 0.f;
    out[3000 + b * 300 + tid] = 0.f;
  }
  uint64_t w = 0;
  if (tid < NW) {
    uint64_t kw = keep[b * NW + tid];
    while (kw) {
      int j = __ffsll((long long)kw) - 1;
      kw &= kw - 1;
      if (sscore[(size_t)b * NPRE + tid * 64 + j] >= 0.f) w |= (1ull << j);
    }
    fw[tid] = w;
  }
  if (tid < 128) cnt[tid] = (tid < NW) ? __popcll(w) : 0;
  __syncthreads();
  for (int off = 1; off < 128; off <<= 1) {
    int v = 0, u = 0;
    if (tid < 128) {
      v = cnt[tid];
      u = (tid >= off) ? cnt[tid - off] : 0;
    }
    __syncthreads();
    if (tid < 128) cnt[tid] = v + u;
    __syncthreads();
  }
  if (tid < NW) {
    int base = cnt[tid] - __popcll(fw[tid]);
    uint64_t ww = fw[tid];
    while (ww) {
      int j = __ffsll((long long)ww) - 1;
      ww &= ww - 1;
      if (base < 300) {
        int p = tid * 64 + j;
        float4 bx = sbox[(size_t)b * NPRE + p];
        float* ob = out + b * 1200 + base * 4;
        ob[0] = bx.x; ob[1] = bx.y; ob[2] = bx.z; ob[3] = bx.w;
        out[2400 + b * 300 + base] = sscore[(size_t)b * NPRE + p];
        out[3000 + b * 300 + base] = 1.0f;
      }
      ++base;
    }
  }
}

// ---------------- launch ----------------
extern "C" void kernel_launch(void* const* d_in, const int* in_sizes, int n_in,
                              void* d_out, int out_size, void* d_ws, size_t ws_size,
                              hipStream_t stream) {
  const float* x       = (const float*)d_in[0];
  const float* conv1_w = (const float*)d_in[1];
  const float* conv1_b = (const float*)d_in[2];
  const float* obj_w   = (const float*)d_in[3];
  const float* obj_b   = (const float*)d_in[4];
  const float* loc_w   = (const float*)d_in[5];
  const float* loc_b   = (const float*)d_in[6];
  const float* anch    = (const float*)d_in[7];
  const int*   img_h   = (const int*)d_in[8];
  const int*   img_w   = (const int*)d_in[9];

  char* base = (char*)d_ws;
  // split8: wt(4.72M) + 8 partials (81.92M) + tail(7.4M) = 93.32 MB
  // split4: wt(4.72M) + 4 partials (40.96M) + tail(7.4M) = 52.36 MB
  const size_t NEED8 = 93319424;
  const size_t NEED4 = 52359424;
  int nsplit = (ws_size >= NEED8) ? 8 : (ws_size >= NEED4) ? 4 : 0;

  float* wt = (float*)(base + 0);  // 4,718,592
  float* h;
  uint64_t* M;
  float* scores;
  float4* boxes;
  float* sscore;
  float4* sbox;
  uint64_t* keep;
  float* xp;
  unsigned int* state;
  float* wt54b;

  size_t off = 4718592;
  h = (float*)(base + off);
  M = (uint64_t*)(base + off);  // aliases h region (9,024,000 B fits all tiers)
  off += (nsplit == 8) ? 81920000 : (nsplit == 4) ? 40960000 : 10240000;
  scores = (float*)(base + off); off += 180000;
  boxes  = (float4*)(base + off); off += 720000;
  sscore = (float*)(base + off); off += 48000;
  sbox   = (float4*)(base + off);
  wt54b  = (float*)sbox;  // aliases sbox: prep writes, heads reads, topk ph7 overwrites after
  off += 192000;
  keep   = (uint64_t*)(base + off); off += 1504;
  xp     = (float*)(base + off); off += 5537792;
  state  = (unsigned int*)(base + off);

  hipLaunchKernelGGL(prep, dim3(2612), dim3(256), 0, stream,
                     conv1_w, wt, x, xp, obj_w, loc_w, wt54b);
  if (nsplit == 8) {
    // split-K=8: y = oc_tile(0..3) | kh(0..7)<<2 -> 1280 blocks = 5 blocks/CU
    hipLaunchKernelGGL((conv1_gemm_split<8>), dim3(20, 32, 2), dim3(256), 0, stream,
                       xp, wt, h);
    hipLaunchKernelGGL((heads_t<8>), dim3(1250), dim3(64), 0, stream, h, conv1_b, wt54b,
                       obj_b, loc_b, anch, img_h, img_w, scores, boxes);
  } else if (nsplit == 4) {
    hipLaunchKernelGGL((conv1_gemm_split<4>), dim3(20, 16, 2), dim3(256), 0, stream,
                       xp, wt, h);
    hipLaunchKernelGGL((heads_t<4>), dim3(1250), dim3(64), 0, stream, h, conv1_b, wt54b,
                       obj_b, loc_b, anch, img_h, img_w, scores, boxes);
  } else {
    hipLaunchKernelGGL(conv1_gemm_mono, dim3(40, 8, 2), dim3(256), 0, stream, xp, wt,
                       conv1_b, h);
    hipLaunchKernelGGL((heads_t<0>), dim3(1250), dim3(64), 0, stream, h, conv1_b, wt54b,
                       obj_b, loc_b, anch, img_h, img_w, scores, boxes);
  }
  // common path: sort only top-2048 (all NMS consumes within CMAX budget)
  hipLaunchKernelGGL((topk_sort_t<KFAST, 32, 2048, false>), dim3(2), dim3(1024), 0, stream,
                     scores, boxes, sscore, sbox, state);
  hipLaunchKernelGGL(iou_mat, dim3(CMAX, CMAX / 4, 2), dim3(256), 0, stream, sbox, M);
  hipLaunchKernelGGL(nms_scan, dim3(2), dim3(1024), 0, stream, M, sscore, keep, state,
                     sbox, (float*)d_out);
  // fallback chain (gated on !done): full 6000 sort -> remaining IoU -> rest-scan+emit
  hipLaunchKernelGGL((topk_sort_t<NPRE, 94, 6144, true>), dim3(2), dim3(1024), 0, stream,
                     scores, boxes, sscore, sbox, state);
  hipLaunchKernelGGL(iou_rest, dim3(NW, 6, 2), dim3(256), 0, stream, sbox, M, state);
  hipLaunchKernelGGL(nms_finish, dim3(2), dim3(1024), 0, stream, M, sscore, keep, state,
                     sbox, (float*)d_out);
}